// Round 1
// 2170.240 us; speedup vs baseline: 1.1136x; 1.1136x over previous
//
#include <hip/hip_runtime.h>

#define BB 2
#define HH 128
#define WW 256
#define CC 768
#define NB 8
#define BS 96
#define WKEPT 65
#define NPTS (BB*HH*WKEPT)        // 16640 kept (b,h,w') points
#define NTOT ((size_t)BB*HH*WW*CC) // 50331648
#define TWOPI 6.283185307179586f

#define P1_TW (9*127*8)           // 9144 entries (cos + sin tables)
#define P7_TW (16*65*8)           // 8320 entries

// ---------------------------------------------------------------------------
// K0: precombine weights (unchanged).
// ---------------------------------------------------------------------------
__global__ __launch_bounds__(256) void k_weights(
    const float* __restrict__ w1, const float* __restrict__ w2,
    const float* __restrict__ b2,
    float* __restrict__ W1P, float* __restrict__ W1M,
    float* __restrict__ WKm, float* __restrict__ WNK, float* __restrict__ BEFF)
{
    const int n = blockIdx.x;
    const int tid = threadIdx.x;
    __shared__ float m_s[BS*BS];

    const float* w2a = w2 + (size_t)(0*NB + n)*BS*BS;
    const float* w2b = w2 + (size_t)(1*NB + n)*BS*BS;
    for (int idx = tid; idx < BS*BS; idx += 256)
        m_s[idx] = 0.5f*(w2a[idx] - w2b[idx]);

    const float* w1a = w1 + (size_t)(0*NB + n)*BS*BS;
    const float* w1b = w1 + (size_t)(1*NB + n)*BS*BS;
    for (int idx = tid; idx < BS*BS; idx += 256) {
        float t0 = w1a[idx], t1 = w1b[idx];
        W1P[n*BS*BS + idx] = 0.5f*(t0 + t1);
        W1M[n*BS*BS + idx] = 0.5f*(t0 - t1);
    }
    __syncthreads();

    for (int idx = tid; idx < BS*BS; idx += 256) {
        int i = idx / BS, o = idx - i*BS;
        float p_io = 0.5f*(w2a[idx] + w2b[idx]);
        float m_io = m_s[idx];
        float accK = 0.f, accN = 0.f;
        for (int j = 0; j < BS; ++j) {
            float p_ij = 0.5f*(w2a[i*BS + j] + w2b[i*BS + j]);
            float mjo  = m_s[j*BS + o];
            accK += p_ij * mjo;
            accN += m_s[i*BS + j] * mjo;
        }
        WKm[n*BS*BS + idx] = p_io + accK;
        WNK[n*BS*BS + idx] = p_io + m_io + accN;
    }
    if (tid < BS) {
        const float* b2a = b2 + (0*NB + n)*BS;
        const float* b2b = b2 + (1*NB + n)*BS;
        float acc = b2a[tid] + b2b[tid];
        for (int j = 0; j < BS; ++j) acc += b2a[j] * m_s[j*BS + tid];
        BEFF[n*BS + tid] = acc;
    }
}

// ---------------------------------------------------------------------------
// K-tw: twiddle tables in GLOBAL memory (wave-uniform reads -> s_load/L1 hit,
// zero LDS traffic in the hot DFT kernels).
//  p1 tables: [wg 0..8][w 1..127][j 0..7]  cos/sin(2*pi*w*(wg*8+j)/256)
//  p7 tables: [wg 0..15][wq 0..64][j 0..7] cos/sin(2*pi*(wg*8+j)*wq/256)
// ---------------------------------------------------------------------------
__global__ __launch_bounds__(256) void k_tw(
    float* __restrict__ c1t, float* __restrict__ s1t,
    float* __restrict__ c7t, float* __restrict__ s7t)
{
    int idx = blockIdx.x*256 + threadIdx.x;
    if (idx < P1_TW) {
        int j = idx & 7; int rest = idx >> 3;
        int w = rest % 127 + 1; int wg = rest / 127;
        int ai = (w * (wg*8 + j)) & 255;
        float sn, cs; sincosf(TWOPI * (float)ai / 256.0f, &sn, &cs);
        c1t[idx] = cs; s1t[idx] = sn;
    }
    if (idx < P7_TW) {
        int j = idx & 7; int rest = idx >> 3;
        int wq = rest % 65; int wg = rest / 65;
        int ai = ((wg*8 + j) * wq) & 255;
        float sn, cs; sincosf(TWOPI * (float)ai / 256.0f, &sn, &cs);
        c7t[idx] = cs; s7t[idx] = sn;
    }
}

// ---------------------------------------------------------------------------
// P1 (new): forward W-axis pruned DFT, real input, folded pairs (w, 256-w),
// 4 rows per block, twiddles from global (uniform -> scalar loads), no LDS.
// grid (27 = 3 ctiles * 9 wgroups, 64 rowgroups), 256 thr.
// ---------------------------------------------------------------------------
__global__ __launch_bounds__(256) void k_p1(
    const float* __restrict__ x, const float* __restrict__ c1t,
    const float* __restrict__ s1t, float2* __restrict__ out)
{
    const int tid = threadIdx.x;
    const int ct = blockIdx.x % 3;
    const int wg = blockIdx.x / 3;        // 0..8
    const int rg = blockIdx.y;            // 0..63, row = b*HH+h
    const int c  = ct*256 + tid;
    const int wpb = wg*8;
    const int row0 = rg*4;

    float re[4][8], im[4][8];
    const float* xr0 = x + (size_t)row0 * WW * CC + c;

    // edges: w=0 and w=128 (sin terms vanish; cos(pi*wp) = (-1)^wp)
    #pragma unroll
    for (int r = 0; r < 4; ++r) {
        const float* xr = xr0 + (size_t)r * WW * CC;
        float x0v   = xr[0];
        float x128v = xr[(size_t)128*CC];
        #pragma unroll
        for (int j = 0; j < 8; ++j) {
            re[r][j] = (((wpb + j) & 1) ? (x0v - x128v) : (x0v + x128v));
            im[r][j] = 0.f;
        }
    }

    const float4* cT = (const float4*)(c1t + (size_t)wg*127*8);
    const float4* sT = (const float4*)(s1t + (size_t)wg*127*8);
    for (int w = 1; w <= 127; ++w) {
        float4 c0 = cT[2*(w-1)], c1 = cT[2*(w-1)+1];
        float4 s0 = sT[2*(w-1)], s1 = sT[2*(w-1)+1];
        #pragma unroll
        for (int r = 0; r < 4; ++r) {
            const float* xr = xr0 + (size_t)r * WW * CC;
            float a = xr[(size_t)w*CC];
            float b = xr[(size_t)(256-w)*CC];
            float u = a + b, d = a - b;
            re[r][0] = fmaf(u, c0.x, re[r][0]);  im[r][0] = fmaf(-d, s0.x, im[r][0]);
            re[r][1] = fmaf(u, c0.y, re[r][1]);  im[r][1] = fmaf(-d, s0.y, im[r][1]);
            re[r][2] = fmaf(u, c0.z, re[r][2]);  im[r][2] = fmaf(-d, s0.z, im[r][2]);
            re[r][3] = fmaf(u, c0.w, re[r][3]);  im[r][3] = fmaf(-d, s0.w, im[r][3]);
            re[r][4] = fmaf(u, c1.x, re[r][4]);  im[r][4] = fmaf(-d, s1.x, im[r][4]);
            re[r][5] = fmaf(u, c1.y, re[r][5]);  im[r][5] = fmaf(-d, s1.y, im[r][5]);
            re[r][6] = fmaf(u, c1.z, re[r][6]);  im[r][6] = fmaf(-d, s1.z, im[r][6]);
            re[r][7] = fmaf(u, c1.w, re[r][7]);  im[r][7] = fmaf(-d, s1.w, im[r][7]);
        }
    }

    #pragma unroll
    for (int r = 0; r < 4; ++r) {
        #pragma unroll
        for (int j = 0; j < 8; ++j) {
            int wp = wpb + j;
            if (wp < WKEPT)
                out[(size_t)((row0 + r)*WKEPT + wp) * CC + c] = make_float2(re[r][j], im[r][j]);
        }
    }
}

// ---------------------------------------------------------------------------
// P1 fallback (previous verified version, LDS twiddles) — used only if the
// workspace lacks headroom for the global tables.
// ---------------------------------------------------------------------------
__global__ __launch_bounds__(256) void k_p1_fb(
    const float* __restrict__ x, float2* __restrict__ out)
{
    const int tid = threadIdx.x;
    const int ct = blockIdx.x % 3;
    const int wg = blockIdx.x / 3;
    const int h = blockIdx.y, b = blockIdx.z;
    const int c = ct*256 + tid;
    const int wpb = wg*8;

    __shared__ float2 tw[256][8];
    for (int idx = tid; idx < 2048; idx += 256) {
        int w = idx >> 3, j = idx & 7;
        int ai = (w * (wpb + j)) & 255;
        float sn, cs; sincosf(TWOPI * (float)ai / 256.0f, &sn, &cs);
        tw[w][j] = make_float2(cs, sn);
    }
    __syncthreads();

    float re[8] = {0,0,0,0,0,0,0,0}, im[8] = {0,0,0,0,0,0,0,0};
    const float* xrow = x + (size_t)(b*HH + h) * WW * CC + c;
    for (int w = 0; w < 256; ++w) {
        float xv = xrow[(size_t)w * CC];
        const float4* t4 = (const float4*)(&tw[w][0]);
        #pragma unroll
        for (int jj = 0; jj < 4; ++jj) {
            float4 q = t4[jj];
            re[2*jj]   += xv * q.x;  im[2*jj]   -= xv * q.y;
            re[2*jj+1] += xv * q.z;  im[2*jj+1] -= xv * q.w;
        }
    }
    #pragma unroll
    for (int j = 0; j < 8; ++j) {
        int wp = wpb + j;
        if (wp < WKEPT)
            out[(size_t)((b*HH + h)*WKEPT + wp) * CC + c] = make_float2(re[j], im[j]);
    }
}

// ---------------------------------------------------------------------------
// P2/P6: C-axis 768-pt FFT per line (unchanged).
// ---------------------------------------------------------------------------
#define LPB 4
__global__ __launch_bounds__(256) void k_cfft(
    const float2* __restrict__ in, float2* __restrict__ out)
{
    __shared__ float2 tw[CC];
    __shared__ float2 bufA[LPB*CC];
    __shared__ float2 bufB[LPB*CC];
    const int tid = threadIdx.x;
    const size_t line0 = (size_t)blockIdx.x * LPB;

    for (int t = tid; t < CC; t += 256) {
        float sn, cs; sincosf(TWOPI * (float)t / 768.0f, &sn, &cs);
        tw[t] = make_float2(cs, -sn);
    }
    for (int idx = tid; idx < LPB*CC; idx += 256) {
        int l = idx / CC, c = idx - l*CC;
        int m = c / 3, j = c - 3*m;
        bufA[l*CC + j*256 + m] = in[(line0 + l)*CC + c];
    }
    __syncthreads();

    float2* src = bufA;
    float2* dst = bufB;
    #pragma unroll
    for (int st = 0; st < 8; ++st) {
        const int s = 1 << st;
        const int h = 128 >> st;
        for (int item = tid; item < LPB*3*128; item += 256) {
            int sub = item >> 7;
            int t   = item & 127;
            int q = t & (s - 1);
            int p = t >> st;
            float2 a = src[sub*256 + q + s*p];
            float2 b = src[sub*256 + q + s*(p + h)];
            float2 w = tw[p * (3 << st)];
            float dx = a.x - b.x, dy = a.y - b.y;
            dst[sub*256 + q + s*(2*p)]     = make_float2(a.x + b.x, a.y + b.y);
            dst[sub*256 + q + s*(2*p + 1)] = make_float2(dx*w.x - dy*w.y, dx*w.y + dy*w.x);
        }
        __syncthreads();
        float2* tmp = src; src = dst; dst = tmp;
    }
    for (int idx = tid; idx < LPB*CC; idx += 256) {
        int l = idx / CC, cp = idx - l*CC;
        int r = cp & 255;
        float2 S0 = src[(l*3 + 0)*256 + r];
        float2 S1 = src[(l*3 + 1)*256 + r];
        float2 S2 = src[(l*3 + 2)*256 + r];
        float2 w1 = tw[cp];
        int i2 = 2*cp; if (i2 >= CC) i2 -= CC;
        float2 w2 = tw[i2];
        float fr = S0.x + w1.x*S1.x - w1.y*S1.y + w2.x*S2.x - w2.y*S2.y;
        float fi = S0.y + w1.x*S1.y + w1.y*S1.x + w2.x*S2.y + w2.y*S2.x;
        out[(line0 + l)*CC + cp] = make_float2(fr, fi);
    }
}

// ---------------------------------------------------------------------------
// P3: H-axis 128-pt DFT + B butterfly, complex -> a=Re+Im (unchanged).
// ---------------------------------------------------------------------------
#define CT3 16
__global__ __launch_bounds__(256) void k_hb_c2a(
    const float2* __restrict__ in, float* __restrict__ aout)
{
    const int tid = threadIdx.x;
    const int wp = blockIdx.y;
    const int c0 = blockIdx.x * CT3;
    __shared__ float2 us[HH][CT3];
    __shared__ float2 vs[HH][CT3];
    __shared__ float2 rt[HH];
    if (tid < HH) { float sn, cse; sincosf(TWOPI*(float)tid/128.f, &sn, &cse); rt[tid] = make_float2(cse, sn); }
    for (int idx = tid; idx < HH*CT3; idx += 256) {
        int h = idx / CT3, cl = idx - (idx / CT3)*CT3;
        float2 z0 = in[(size_t)((0*HH + h)*WKEPT + wp)*CC + c0 + cl];
        float2 z1 = in[(size_t)((1*HH + h)*WKEPT + wp)*CC + c0 + cl];
        us[h][cl] = make_float2(z0.x+z1.x, z0.y+z1.y);
        vs[h][cl] = make_float2(z0.x-z1.x, z0.y-z1.y);
    }
    __syncthreads();
    const int cl = tid & 15, hg = tid >> 4;
    float ur[8]={0,0,0,0,0,0,0,0}, ui[8]={0,0,0,0,0,0,0,0};
    float vr[8]={0,0,0,0,0,0,0,0}, vi[8]={0,0,0,0,0,0,0,0};
    for (int h = 0; h < HH; ++h) {
        float2 u = us[h][cl], v = vs[h][cl];
        #pragma unroll
        for (int k = 0; k < 8; ++k) {
            int hp = k*16 + hg;
            float2 t = rt[(h*hp) & 127];
            ur[k] += u.x*t.x + u.y*t.y;  ui[k] += u.y*t.x - u.x*t.y;
            vr[k] += v.x*t.x + v.y*t.y;  vi[k] += v.y*t.x - v.x*t.y;
        }
    }
    #pragma unroll
    for (int k = 0; k < 8; ++k) {
        int hp = k*16 + hg;
        aout[(size_t)((0*HH + hp)*WKEPT + wp)*CC + c0 + cl] = ur[k] + ui[k];
        aout[(size_t)((1*HH + hp)*WKEPT + wp)*CC + c0 + cl] = vr[k] + vi[k];
    }
}

// ---------------------------------------------------------------------------
// P5: H-axis 128-pt DFT + B butterfly, real -> complex (unchanged).
// ---------------------------------------------------------------------------
__global__ __launch_bounds__(256) void k_hb_s2c(
    const float* __restrict__ sreal, float2* __restrict__ out)
{
    const int tid = threadIdx.x;
    const int wp = blockIdx.y;
    const int c0 = blockIdx.x * CT3;
    __shared__ float us[HH][CT3];
    __shared__ float vs[HH][CT3];
    __shared__ float2 rt[HH];
    if (tid < HH) { float sn, cse; sincosf(TWOPI*(float)tid/128.f, &sn, &cse); rt[tid] = make_float2(cse, sn); }
    for (int idx = tid; idx < HH*CT3; idx += 256) {
        int h = idx / CT3, cl = idx - (idx / CT3)*CT3;
        float z0 = sreal[(size_t)((0*HH + h)*WKEPT + wp)*CC + c0 + cl];
        float z1 = sreal[(size_t)((1*HH + h)*WKEPT + wp)*CC + c0 + cl];
        us[h][cl] = z0 + z1;
        vs[h][cl] = z0 - z1;
    }
    __syncthreads();
    const int cl = tid & 15, hg = tid >> 4;
    float ur[8]={0,0,0,0,0,0,0,0}, ui[8]={0,0,0,0,0,0,0,0};
    float vr[8]={0,0,0,0,0,0,0,0}, vi[8]={0,0,0,0,0,0,0,0};
    for (int h = 0; h < HH; ++h) {
        float u = us[h][cl], v = vs[h][cl];
        #pragma unroll
        for (int k = 0; k < 8; ++k) {
            int hp = k*16 + hg;
            float2 t = rt[(h*hp) & 127];
            ur[k] += u*t.x;  ui[k] -= u*t.y;
            vr[k] += v*t.x;  vi[k] -= v*t.y;
        }
    }
    #pragma unroll
    for (int k = 0; k < 8; ++k) {
        int hp = k*16 + hg;
        out[(size_t)((0*HH + hp)*WKEPT + wp)*CC + c0 + cl] = make_float2(ur[k], ui[k]);
        out[(size_t)((1*HH + hp)*WKEPT + wp)*CC + c0 + cl] = make_float2(vr[k], vi[k]);
    }
}

// ---------------------------------------------------------------------------
// P4a: layer1 (unchanged).
// ---------------------------------------------------------------------------
__global__ __launch_bounds__(256) void k_mlp1(
    const float* __restrict__ a, const float* __restrict__ x,
    const float* __restrict__ W1P, const float* __restrict__ W1M,
    const float* __restrict__ b1,
    float* __restrict__ o1k, float* __restrict__ o1nk)
{
    const int tid = threadIdx.x;
    const int n = blockIdx.y;
    const int P0 = blockIdx.x * 64;
    __shared__ float at_s[BS*67];
    __shared__ float ant_s[BS*67];

    for (int idx = tid; idx < 64*BS; idx += 256) {
        int p = idx / BS, i = idx - p*BS;
        int P = P0 + p;
        at_s[i*67 + p] = a[(size_t)P*CC + n*BS + i];
        int b = P / (HH*WKEPT);
        int rem = P - b*(HH*WKEPT);
        int h = rem / WKEPT;
        int wq = rem - h*WKEPT;
        int hh2 = (HH - h) & (HH-1);
        int ww2 = (WW - wq) & (WW-1);
        ant_s[i*67 + p] = x[(size_t)((b*HH + hh2)*WW + ww2)*CC + n*BS + i];
    }
    __syncthreads();

    const int p = tid & 63, og = tid >> 6, ob = og*24;
    float ak[24], ank[24];
    #pragma unroll
    for (int j = 0; j < 24; ++j) { ak[j] = 0.f; ank[j] = 0.f; }
    const float* wpb = W1P + n*BS*BS;
    const float* wmb = W1M + n*BS*BS;
    for (int i = 0; i < BS; ++i) {
        float av = at_s[i*67 + p], anv = ant_s[i*67 + p];
        const float4* p4 = (const float4*)(wpb + i*BS + ob);
        const float4* m4 = (const float4*)(wmb + i*BS + ob);
        #pragma unroll
        for (int jj = 0; jj < 6; ++jj) {
            float4 qp = p4[jj], qm = m4[jj];
            ak [4*jj+0] += av*qp.x + anv*qm.x;  ank[4*jj+0] += anv*qp.x + av*qm.x;
            ak [4*jj+1] += av*qp.y + anv*qm.y;  ank[4*jj+1] += anv*qp.y + av*qm.y;
            ak [4*jj+2] += av*qp.z + anv*qm.z;  ank[4*jj+2] += anv*qp.z + av*qm.z;
            ak [4*jj+3] += av*qp.w + anv*qm.w;  ank[4*jj+3] += anv*qp.w + av*qm.w;
        }
    }
    __syncthreads();
    #pragma unroll
    for (int j = 0; j < 24; ++j) {
        int o = ob + j;
        at_s [p*97 + o] = fmaxf(ak[j]  + b1[(0*NB + n)*BS + o], 0.f);
        ant_s[p*97 + o] = fmaxf(ank[j] + b1[(1*NB + n)*BS + o], 0.f);
    }
    __syncthreads();
    for (int idx = tid; idx < 64*BS; idx += 256) {
        int p2 = idx / BS, o = idx - p2*BS;
        size_t g = (size_t)(P0 + p2)*CC + n*BS + o;
        o1k[g]  = at_s[p2*97 + o];
        o1nk[g] = ant_s[p2*97 + o];
    }
}

// ---------------------------------------------------------------------------
// P4b: collapsed layer2 + soft-threshold (unchanged).
// ---------------------------------------------------------------------------
__global__ __launch_bounds__(256) void k_mlp2(
    const float* __restrict__ o1k, const float* __restrict__ o1nk,
    const float* __restrict__ WKm, const float* __restrict__ WNK,
    const float* __restrict__ BEFF, float* __restrict__ sout)
{
    const int tid = threadIdx.x;
    const int n = blockIdx.y;
    const int P0 = blockIdx.x * 64;
    __shared__ float tk[BS*67];
    __shared__ float tn[BS*67];
    for (int idx = tid; idx < 64*BS; idx += 256) {
        int p = idx / BS, i = idx - p*BS;
        size_t g = (size_t)(P0 + p)*CC + n*BS + i;
        tk[i*67 + p] = o1k[g];
        tn[i*67 + p] = o1nk[g];
    }
    __syncthreads();
    const int p = tid & 63, og = tid >> 6, ob = og*24;
    float acc[24];
    #pragma unroll
    for (int j = 0; j < 24; ++j) acc[j] = 0.f;
    const float* wkb = WKm + n*BS*BS;
    const float* wnb = WNK + n*BS*BS;
    for (int i = 0; i < BS; ++i) {
        float vk = tk[i*67 + p], vn = tn[i*67 + p];
        const float4* k4 = (const float4*)(wkb + i*BS + ob);
        const float4* n4 = (const float4*)(wnb + i*BS + ob);
        #pragma unroll
        for (int jj = 0; jj < 6; ++jj) {
            float4 qk = k4[jj], qn = n4[jj];
            acc[4*jj+0] += vk*qk.x + vn*qn.x;
            acc[4*jj+1] += vk*qk.y + vn*qn.y;
            acc[4*jj+2] += vk*qk.z + vn*qn.z;
            acc[4*jj+3] += vk*qk.w + vn*qn.w;
        }
    }
    __syncthreads();
    #pragma unroll
    for (int j = 0; j < 24; ++j) {
        int o = ob + j;
        float v = acc[j] + BEFF[n*BS + o];
        float av = fabsf(v) - 0.01f;
        tk[p*97 + o] = (av > 0.f) ? copysignf(av, v) : 0.f;
    }
    __syncthreads();
    for (int idx = tid; idx < 64*BS; idx += 256) {
        int p2 = idx / BS, o = idx - p2*BS;
        sout[(size_t)(P0 + p2)*CC + n*BS + o] = tk[p2*97 + o];
    }
}

// ---------------------------------------------------------------------------
// P7 (new): inverse W expansion (65 -> 256) with output-pair symmetry
// (w, 256-w), 4 rows per block, global twiddles, no LDS.
//   out[w]     = sum_wq c*P + s*M,  P = vx+vy, M = vy-vx
//   out[256-w] = sum_wq c*P - s*M
//   out[128]   = sum_wq (-1)^wq * P   (wg==0 only)
// grid (48 = 3 ctiles * 16 wgroups, 64 rowgroups), 256 thr.
// ---------------------------------------------------------------------------
__global__ __launch_bounds__(256) void k_p7(
    const float2* __restrict__ A, const float* __restrict__ x,
    const float* __restrict__ c7t, const float* __restrict__ s7t,
    float* __restrict__ out)
{
    const int tid = threadIdx.x;
    const int ct = blockIdx.x % 3;
    const int wg = blockIdx.x / 3;        // 0..15
    const int rg = blockIdx.y;            // 0..63
    const int c  = ct*256 + tid;
    const int wpb = wg*8;
    const int row0 = rg*4;

    float accA[4][8], accB[4][8], acc128[4];
    #pragma unroll
    for (int r = 0; r < 4; ++r) {
        acc128[r] = 0.f;
        #pragma unroll
        for (int j = 0; j < 8; ++j) { accA[r][j] = 0.f; accB[r][j] = 0.f; }
    }

    const float2* A0 = A + (size_t)row0 * WKEPT * CC + c;
    const float4* cT = (const float4*)(c7t + (size_t)wg*65*8);
    const float4* sT = (const float4*)(s7t + (size_t)wg*65*8);
    for (int wq = 0; wq < 65; ++wq) {
        float4 c0 = cT[2*wq], c1 = cT[2*wq+1];
        float4 s0 = sT[2*wq], s1 = sT[2*wq+1];
        float sg = (wq & 1) ? -1.f : 1.f;
        #pragma unroll
        for (int r = 0; r < 4; ++r) {
            float2 v = A0[(size_t)(r*WKEPT + wq) * CC];
            float P = v.x + v.y;
            float M = v.y - v.x;
            float N = v.x - v.y;
            acc128[r] = fmaf(sg, P, acc128[r]);
            accA[r][0] = fmaf(P, c0.x, fmaf(M, s0.x, accA[r][0]));
            accB[r][0] = fmaf(P, c0.x, fmaf(N, s0.x, accB[r][0]));
            accA[r][1] = fmaf(P, c0.y, fmaf(M, s0.y, accA[r][1]));
            accB[r][1] = fmaf(P, c0.y, fmaf(N, s0.y, accB[r][1]));
            accA[r][2] = fmaf(P, c0.z, fmaf(M, s0.z, accA[r][2]));
            accB[r][2] = fmaf(P, c0.z, fmaf(N, s0.z, accB[r][2]));
            accA[r][3] = fmaf(P, c0.w, fmaf(M, s0.w, accA[r][3]));
            accB[r][3] = fmaf(P, c0.w, fmaf(N, s0.w, accB[r][3]));
            accA[r][4] = fmaf(P, c1.x, fmaf(M, s1.x, accA[r][4]));
            accB[r][4] = fmaf(P, c1.x, fmaf(N, s1.x, accB[r][4]));
            accA[r][5] = fmaf(P, c1.y, fmaf(M, s1.y, accA[r][5]));
            accB[r][5] = fmaf(P, c1.y, fmaf(N, s1.y, accB[r][5]));
            accA[r][6] = fmaf(P, c1.z, fmaf(M, s1.z, accA[r][6]));
            accB[r][6] = fmaf(P, c1.z, fmaf(N, s1.z, accB[r][6]));
            accA[r][7] = fmaf(P, c1.w, fmaf(M, s1.w, accA[r][7]));
            accB[r][7] = fmaf(P, c1.w, fmaf(N, s1.w, accB[r][7]));
        }
    }

    const float scale = 1.0f / 50331648.0f;
    #pragma unroll
    for (int r = 0; r < 4; ++r) {
        size_t base = (size_t)(row0 + r) * WW * CC + c;
        #pragma unroll
        for (int j = 0; j < 8; ++j) {
            int w = wpb + j;
            size_t g = base + (size_t)w*CC;
            out[g] = fmaf(accA[r][j], scale, x[g]);
            if (w != 0) {
                size_t g2 = base + (size_t)(256 - w)*CC;
                out[g2] = fmaf(accB[r][j], scale, x[g2]);
            }
        }
        if (wg == 0) {
            size_t g = base + (size_t)128*CC;
            out[g] = fmaf(acc128[r], scale, x[g]);
        }
    }
}

// ---------------------------------------------------------------------------
// P7 fallback (previous verified version).
// ---------------------------------------------------------------------------
__global__ __launch_bounds__(256) void k_p7_fb(
    const float2* __restrict__ A, const float* __restrict__ x,
    float* __restrict__ out)
{
    const int tid = threadIdx.x;
    const int ct = blockIdx.x % 3;
    const int wg = blockIdx.x / 3;
    const int h = blockIdx.y, b = blockIdx.z;
    const int c = ct*256 + tid;
    __shared__ float cm[WKEPT][8];
    __shared__ float cp[WKEPT][8];
    for (int idx = tid; idx < WKEPT*8; idx += 256) {
        int wq = idx >> 3, j = idx & 7;
        int w = wg*8 + j;
        int ai = (w * wq) & 255;
        float sn, cse; sincosf(TWOPI * (float)ai / 256.f, &sn, &cse);
        cm[wq][j] = cse - sn;
        cp[wq][j] = cse + sn;
    }
    __syncthreads();
    float acc[8] = {0,0,0,0,0,0,0,0};
    const float2* Ab = A + (size_t)((b*HH + h)*WKEPT)*CC + c;
    for (int wq = 0; wq < WKEPT; ++wq) {
        float2 v = Ab[(size_t)wq*CC];
        const float4* m4 = (const float4*)(&cm[wq][0]);
        const float4* p4 = (const float4*)(&cp[wq][0]);
        #pragma unroll
        for (int jj = 0; jj < 2; ++jj) {
            float4 qm = m4[jj], qp = p4[jj];
            acc[4*jj+0] += v.x*qm.x + v.y*qp.x;
            acc[4*jj+1] += v.x*qm.y + v.y*qp.y;
            acc[4*jj+2] += v.x*qm.z + v.y*qp.z;
            acc[4*jj+3] += v.x*qm.w + v.y*qp.w;
        }
    }
    const float scale = 1.0f / 50331648.0f;
    size_t base = (size_t)(b*HH + h)*WW*CC + c;
    #pragma unroll
    for (int j = 0; j < 8; ++j) {
        int w = wg*8 + j;
        size_t g = base + (size_t)w*CC;
        out[g] = fmaf(acc[j], scale, x[g]);
    }
}

// ---------------------------------------------------------------------------
// Launch. ws layout (floats):
//   [0 : 25,559,040)   complex buffer A (16640*768 float2)
//                      first half doubles as a_real, second half as s_real
//   [25,559,040 ...)   W1P, W1M, WK, WNK (each 73728), BEFF (768)
//   then c1t, s1t (9144 each), c7t, s7t (8320 each)   — twiddle tables
// d_out doubles as complex buffer B / o1 scratch.
// ---------------------------------------------------------------------------
extern "C" void kernel_launch(void* const* d_in, const int* in_sizes, int n_in,
                              void* d_out, int out_size, void* d_ws, size_t ws_size,
                              hipStream_t stream)
{
    (void)in_sizes; (void)n_in; (void)out_size;
    const float* x  = (const float*)d_in[0];
    const float* w1 = (const float*)d_in[1];
    const float* b1 = (const float*)d_in[2];
    const float* w2 = (const float*)d_in[3];
    const float* b2 = (const float*)d_in[4];

    float*  ws     = (float*)d_ws;
    float2* Abuf   = (float2*)d_ws;
    float*  a_real = ws;
    float*  s_real = ws + (size_t)NPTS*CC;
    float*  W1P    = ws + 2*(size_t)NPTS*CC;
    float*  W1M    = W1P + NB*BS*BS;
    float*  WKm    = W1M + NB*BS*BS;
    float*  WNK    = WKm + NB*BS*BS;
    float*  BEFF   = WNK + NB*BS*BS;
    float*  c1t    = BEFF + NB*BS;
    float*  s1t    = c1t + P1_TW;
    float*  c7t    = s1t + P1_TW;
    float*  s7t    = c7t + P7_TW;

    const size_t need_bytes =
        ((size_t)2*NPTS*CC + 4*(size_t)NB*BS*BS + NB*BS + 2*P1_TW + 2*P7_TW)
        * sizeof(float);
    const bool fast = (ws_size >= need_bytes);

    float2* Bc   = (float2*)d_out;
    float*  o1k  = (float*)d_out;
    float*  o1nk = (float*)d_out + (size_t)NPTS*CC;
    float*  outf = (float*)d_out;

    k_weights<<<dim3(NB), dim3(256), 0, stream>>>(w1, w2, b2, W1P, W1M, WKm, WNK, BEFF);
    if (fast) {
        k_tw<<<dim3(36), dim3(256), 0, stream>>>(c1t, s1t, c7t, s7t);
        k_p1<<<dim3(27, 64), dim3(256), 0, stream>>>(x, c1t, s1t, Abuf);
    } else {
        k_p1_fb<<<dim3(27, HH, BB), dim3(256), 0, stream>>>(x, Abuf);
    }
    k_cfft   <<<dim3(NPTS/LPB), dim3(256), 0, stream>>>(Abuf, Bc);
    k_hb_c2a <<<dim3(48, WKEPT), dim3(256), 0, stream>>>(Bc, a_real);
    k_mlp1   <<<dim3(260, NB), dim3(256), 0, stream>>>(a_real, x, W1P, W1M, b1, o1k, o1nk);
    k_mlp2   <<<dim3(260, NB), dim3(256), 0, stream>>>(o1k, o1nk, WKm, WNK, BEFF, s_real);
    k_hb_s2c <<<dim3(48, WKEPT), dim3(256), 0, stream>>>(s_real, Bc);
    k_cfft   <<<dim3(NPTS/LPB), dim3(256), 0, stream>>>(Bc, Abuf);
    if (fast) {
        k_p7<<<dim3(48, 64), dim3(256), 0, stream>>>(Abuf, x, c7t, s7t, outf);
    } else {
        k_p7_fb<<<dim3(96, HH, BB), dim3(256), 0, stream>>>(Abuf, x, outf);
    }
}

// Round 2
// 1838.709 us; speedup vs baseline: 1.3144x; 1.1803x over previous
//
#include <hip/hip_runtime.h>

#define BB 2
#define HH 128
#define WW 256
#define CC 768
#define NB 8
#define BS 96
#define WKEPT 65
#define NPTS (BB*HH*WKEPT)        // 16640 kept (b,h,w') points
#define NTOT ((size_t)BB*HH*WW*CC) // 50331648
#define TWOPI 6.283185307179586f

#define P1_TW (9*127*8)           // 9144 entries (cos + sin tables)
#define P7_TW (16*65*8)           // 8320 entries

// ---------------------------------------------------------------------------
// K0: precombine weights (unchanged).
// ---------------------------------------------------------------------------
__global__ __launch_bounds__(256) void k_weights(
    const float* __restrict__ w1, const float* __restrict__ w2,
    const float* __restrict__ b2,
    float* __restrict__ W1P, float* __restrict__ W1M,
    float* __restrict__ WKm, float* __restrict__ WNK, float* __restrict__ BEFF)
{
    const int n = blockIdx.x;
    const int tid = threadIdx.x;
    __shared__ float m_s[BS*BS];

    const float* w2a = w2 + (size_t)(0*NB + n)*BS*BS;
    const float* w2b = w2 + (size_t)(1*NB + n)*BS*BS;
    for (int idx = tid; idx < BS*BS; idx += 256)
        m_s[idx] = 0.5f*(w2a[idx] - w2b[idx]);

    const float* w1a = w1 + (size_t)(0*NB + n)*BS*BS;
    const float* w1b = w1 + (size_t)(1*NB + n)*BS*BS;
    for (int idx = tid; idx < BS*BS; idx += 256) {
        float t0 = w1a[idx], t1 = w1b[idx];
        W1P[n*BS*BS + idx] = 0.5f*(t0 + t1);
        W1M[n*BS*BS + idx] = 0.5f*(t0 - t1);
    }
    __syncthreads();

    for (int idx = tid; idx < BS*BS; idx += 256) {
        int i = idx / BS, o = idx - i*BS;
        float p_io = 0.5f*(w2a[idx] + w2b[idx]);
        float m_io = m_s[idx];
        float accK = 0.f, accN = 0.f;
        for (int j = 0; j < BS; ++j) {
            float p_ij = 0.5f*(w2a[i*BS + j] + w2b[i*BS + j]);
            float mjo  = m_s[j*BS + o];
            accK += p_ij * mjo;
            accN += m_s[i*BS + j] * mjo;
        }
        WKm[n*BS*BS + idx] = p_io + accK;
        WNK[n*BS*BS + idx] = p_io + m_io + accN;
    }
    if (tid < BS) {
        const float* b2a = b2 + (0*NB + n)*BS;
        const float* b2b = b2 + (1*NB + n)*BS;
        float acc = b2a[tid] + b2b[tid];
        for (int j = 0; j < BS; ++j) acc += b2a[j] * m_s[j*BS + tid];
        BEFF[n*BS + tid] = acc;
    }
}

// ---------------------------------------------------------------------------
// K-tw: twiddle tables in GLOBAL memory (unchanged).
// ---------------------------------------------------------------------------
__global__ __launch_bounds__(256) void k_tw(
    float* __restrict__ c1t, float* __restrict__ s1t,
    float* __restrict__ c7t, float* __restrict__ s7t)
{
    int idx = blockIdx.x*256 + threadIdx.x;
    if (idx < P1_TW) {
        int j = idx & 7; int rest = idx >> 3;
        int w = rest % 127 + 1; int wg = rest / 127;
        int ai = (w * (wg*8 + j)) & 255;
        float sn, cs; sincosf(TWOPI * (float)ai / 256.0f, &sn, &cs);
        c1t[idx] = cs; s1t[idx] = sn;
    }
    if (idx < P7_TW) {
        int j = idx & 7; int rest = idx >> 3;
        int wq = rest % 65; int wg = rest / 65;
        int ai = ((wg*8 + j) * wq) & 255;
        float sn, cs; sincosf(TWOPI * (float)ai / 256.0f, &sn, &cs);
        c7t[idx] = cs; s7t[idx] = sn;
    }
}

// ---------------------------------------------------------------------------
// P1: forward W-axis pruned DFT, folded pairs, global twiddles (unchanged).
// ---------------------------------------------------------------------------
__global__ __launch_bounds__(256) void k_p1(
    const float* __restrict__ x, const float* __restrict__ c1t,
    const float* __restrict__ s1t, float2* __restrict__ out)
{
    const int tid = threadIdx.x;
    const int ct = blockIdx.x % 3;
    const int wg = blockIdx.x / 3;        // 0..8
    const int rg = blockIdx.y;            // 0..63, row = b*HH+h
    const int c  = ct*256 + tid;
    const int wpb = wg*8;
    const int row0 = rg*4;

    float re[4][8], im[4][8];
    const float* xr0 = x + (size_t)row0 * WW * CC + c;

    #pragma unroll
    for (int r = 0; r < 4; ++r) {
        const float* xr = xr0 + (size_t)r * WW * CC;
        float x0v   = xr[0];
        float x128v = xr[(size_t)128*CC];
        #pragma unroll
        for (int j = 0; j < 8; ++j) {
            re[r][j] = (((wpb + j) & 1) ? (x0v - x128v) : (x0v + x128v));
            im[r][j] = 0.f;
        }
    }

    const float4* cT = (const float4*)(c1t + (size_t)wg*127*8);
    const float4* sT = (const float4*)(s1t + (size_t)wg*127*8);
    for (int w = 1; w <= 127; ++w) {
        float4 c0 = cT[2*(w-1)], c1 = cT[2*(w-1)+1];
        float4 s0 = sT[2*(w-1)], s1 = sT[2*(w-1)+1];
        #pragma unroll
        for (int r = 0; r < 4; ++r) {
            const float* xr = xr0 + (size_t)r * WW * CC;
            float a = xr[(size_t)w*CC];
            float b = xr[(size_t)(256-w)*CC];
            float u = a + b, d = a - b;
            re[r][0] = fmaf(u, c0.x, re[r][0]);  im[r][0] = fmaf(-d, s0.x, im[r][0]);
            re[r][1] = fmaf(u, c0.y, re[r][1]);  im[r][1] = fmaf(-d, s0.y, im[r][1]);
            re[r][2] = fmaf(u, c0.z, re[r][2]);  im[r][2] = fmaf(-d, s0.z, im[r][2]);
            re[r][3] = fmaf(u, c0.w, re[r][3]);  im[r][3] = fmaf(-d, s0.w, im[r][3]);
            re[r][4] = fmaf(u, c1.x, re[r][4]);  im[r][4] = fmaf(-d, s1.x, im[r][4]);
            re[r][5] = fmaf(u, c1.y, re[r][5]);  im[r][5] = fmaf(-d, s1.y, im[r][5]);
            re[r][6] = fmaf(u, c1.z, re[r][6]);  im[r][6] = fmaf(-d, s1.z, im[r][6]);
            re[r][7] = fmaf(u, c1.w, re[r][7]);  im[r][7] = fmaf(-d, s1.w, im[r][7]);
        }
    }

    #pragma unroll
    for (int r = 0; r < 4; ++r) {
        #pragma unroll
        for (int j = 0; j < 8; ++j) {
            int wp = wpb + j;
            if (wp < WKEPT)
                out[(size_t)((row0 + r)*WKEPT + wp) * CC + c] = make_float2(re[r][j], im[r][j]);
        }
    }
}

// ---------------------------------------------------------------------------
// P1 fallback (LDS twiddles) — only if ws lacks table headroom.
// ---------------------------------------------------------------------------
__global__ __launch_bounds__(256) void k_p1_fb(
    const float* __restrict__ x, float2* __restrict__ out)
{
    const int tid = threadIdx.x;
    const int ct = blockIdx.x % 3;
    const int wg = blockIdx.x / 3;
    const int h = blockIdx.y, b = blockIdx.z;
    const int c = ct*256 + tid;
    const int wpb = wg*8;

    __shared__ float2 tw[256][8];
    for (int idx = tid; idx < 2048; idx += 256) {
        int w = idx >> 3, j = idx & 7;
        int ai = (w * (wpb + j)) & 255;
        float sn, cs; sincosf(TWOPI * (float)ai / 256.0f, &sn, &cs);
        tw[w][j] = make_float2(cs, sn);
    }
    __syncthreads();

    float re[8] = {0,0,0,0,0,0,0,0}, im[8] = {0,0,0,0,0,0,0,0};
    const float* xrow = x + (size_t)(b*HH + h) * WW * CC + c;
    for (int w = 0; w < 256; ++w) {
        float xv = xrow[(size_t)w * CC];
        const float4* t4 = (const float4*)(&tw[w][0]);
        #pragma unroll
        for (int jj = 0; jj < 4; ++jj) {
            float4 q = t4[jj];
            re[2*jj]   += xv * q.x;  im[2*jj]   -= xv * q.y;
            re[2*jj+1] += xv * q.z;  im[2*jj+1] -= xv * q.w;
        }
    }
    #pragma unroll
    for (int j = 0; j < 8; ++j) {
        int wp = wpb + j;
        if (wp < WKEPT)
            out[(size_t)((b*HH + h)*WKEPT + wp) * CC + c] = make_float2(re[j], im[j]);
    }
}

// ---------------------------------------------------------------------------
// P2/P6: C-axis 768-pt FFT per line (unchanged).
// ---------------------------------------------------------------------------
#define LPB 4
__global__ __launch_bounds__(256) void k_cfft(
    const float2* __restrict__ in, float2* __restrict__ out)
{
    __shared__ float2 tw[CC];
    __shared__ float2 bufA[LPB*CC];
    __shared__ float2 bufB[LPB*CC];
    const int tid = threadIdx.x;
    const size_t line0 = (size_t)blockIdx.x * LPB;

    for (int t = tid; t < CC; t += 256) {
        float sn, cs; sincosf(TWOPI * (float)t / 768.0f, &sn, &cs);
        tw[t] = make_float2(cs, -sn);
    }
    for (int idx = tid; idx < LPB*CC; idx += 256) {
        int l = idx / CC, c = idx - l*CC;
        int m = c / 3, j = c - 3*m;
        bufA[l*CC + j*256 + m] = in[(line0 + l)*CC + c];
    }
    __syncthreads();

    float2* src = bufA;
    float2* dst = bufB;
    #pragma unroll
    for (int st = 0; st < 8; ++st) {
        const int s = 1 << st;
        const int h = 128 >> st;
        for (int item = tid; item < LPB*3*128; item += 256) {
            int sub = item >> 7;
            int t   = item & 127;
            int q = t & (s - 1);
            int p = t >> st;
            float2 a = src[sub*256 + q + s*p];
            float2 b = src[sub*256 + q + s*(p + h)];
            float2 w = tw[p * (3 << st)];
            float dx = a.x - b.x, dy = a.y - b.y;
            dst[sub*256 + q + s*(2*p)]     = make_float2(a.x + b.x, a.y + b.y);
            dst[sub*256 + q + s*(2*p + 1)] = make_float2(dx*w.x - dy*w.y, dx*w.y + dy*w.x);
        }
        __syncthreads();
        float2* tmp = src; src = dst; dst = tmp;
    }
    for (int idx = tid; idx < LPB*CC; idx += 256) {
        int l = idx / CC, cp = idx - l*CC;
        int r = cp & 255;
        float2 S0 = src[(l*3 + 0)*256 + r];
        float2 S1 = src[(l*3 + 1)*256 + r];
        float2 S2 = src[(l*3 + 2)*256 + r];
        float2 w1 = tw[cp];
        int i2 = 2*cp; if (i2 >= CC) i2 -= CC;
        float2 w2 = tw[i2];
        float fr = S0.x + w1.x*S1.x - w1.y*S1.y + w2.x*S2.x - w2.y*S2.y;
        float fi = S0.y + w1.x*S1.y + w1.y*S1.x + w2.x*S2.y + w2.y*S2.x;
        out[(line0 + l)*CC + cp] = make_float2(fr, fi);
    }
}

// ---------------------------------------------------------------------------
// P3: H-axis 128-pt DFT + B butterfly, complex -> a=Re+Im (unchanged).
// ---------------------------------------------------------------------------
#define CT3 16
__global__ __launch_bounds__(256) void k_hb_c2a(
    const float2* __restrict__ in, float* __restrict__ aout)
{
    const int tid = threadIdx.x;
    const int wp = blockIdx.y;
    const int c0 = blockIdx.x * CT3;
    __shared__ float2 us[HH][CT3];
    __shared__ float2 vs[HH][CT3];
    __shared__ float2 rt[HH];
    if (tid < HH) { float sn, cse; sincosf(TWOPI*(float)tid/128.f, &sn, &cse); rt[tid] = make_float2(cse, sn); }
    for (int idx = tid; idx < HH*CT3; idx += 256) {
        int h = idx / CT3, cl = idx - (idx / CT3)*CT3;
        float2 z0 = in[(size_t)((0*HH + h)*WKEPT + wp)*CC + c0 + cl];
        float2 z1 = in[(size_t)((1*HH + h)*WKEPT + wp)*CC + c0 + cl];
        us[h][cl] = make_float2(z0.x+z1.x, z0.y+z1.y);
        vs[h][cl] = make_float2(z0.x-z1.x, z0.y-z1.y);
    }
    __syncthreads();
    const int cl = tid & 15, hg = tid >> 4;
    float ur[8]={0,0,0,0,0,0,0,0}, ui[8]={0,0,0,0,0,0,0,0};
    float vr[8]={0,0,0,0,0,0,0,0}, vi[8]={0,0,0,0,0,0,0,0};
    for (int h = 0; h < HH; ++h) {
        float2 u = us[h][cl], v = vs[h][cl];
        #pragma unroll
        for (int k = 0; k < 8; ++k) {
            int hp = k*16 + hg;
            float2 t = rt[(h*hp) & 127];
            ur[k] += u.x*t.x + u.y*t.y;  ui[k] += u.y*t.x - u.x*t.y;
            vr[k] += v.x*t.x + v.y*t.y;  vi[k] += v.y*t.x - v.x*t.y;
        }
    }
    #pragma unroll
    for (int k = 0; k < 8; ++k) {
        int hp = k*16 + hg;
        aout[(size_t)((0*HH + hp)*WKEPT + wp)*CC + c0 + cl] = ur[k] + ui[k];
        aout[(size_t)((1*HH + hp)*WKEPT + wp)*CC + c0 + cl] = vr[k] + vi[k];
    }
}

// ---------------------------------------------------------------------------
// P5: H-axis 128-pt DFT + B butterfly, real -> complex (unchanged).
// ---------------------------------------------------------------------------
__global__ __launch_bounds__(256) void k_hb_s2c(
    const float* __restrict__ sreal, float2* __restrict__ out)
{
    const int tid = threadIdx.x;
    const int wp = blockIdx.y;
    const int c0 = blockIdx.x * CT3;
    __shared__ float us[HH][CT3];
    __shared__ float vs[HH][CT3];
    __shared__ float2 rt[HH];
    if (tid < HH) { float sn, cse; sincosf(TWOPI*(float)tid/128.f, &sn, &cse); rt[tid] = make_float2(cse, sn); }
    for (int idx = tid; idx < HH*CT3; idx += 256) {
        int h = idx / CT3, cl = idx - (idx / CT3)*CT3;
        float z0 = sreal[(size_t)((0*HH + h)*WKEPT + wp)*CC + c0 + cl];
        float z1 = sreal[(size_t)((1*HH + h)*WKEPT + wp)*CC + c0 + cl];
        us[h][cl] = z0 + z1;
        vs[h][cl] = z0 - z1;
    }
    __syncthreads();
    const int cl = tid & 15, hg = tid >> 4;
    float ur[8]={0,0,0,0,0,0,0,0}, ui[8]={0,0,0,0,0,0,0,0};
    float vr[8]={0,0,0,0,0,0,0,0}, vi[8]={0,0,0,0,0,0,0,0};
    for (int h = 0; h < HH; ++h) {
        float u = us[h][cl], v = vs[h][cl];
        #pragma unroll
        for (int k = 0; k < 8; ++k) {
            int hp = k*16 + hg;
            float2 t = rt[(h*hp) & 127];
            ur[k] += u*t.x;  ui[k] -= u*t.y;
            vr[k] += v*t.x;  vi[k] -= v*t.y;
        }
    }
    #pragma unroll
    for (int k = 0; k < 8; ++k) {
        int hp = k*16 + hg;
        out[(size_t)((0*HH + hp)*WKEPT + wp)*CC + c0 + cl] = make_float2(ur[k], ui[k]);
        out[(size_t)((1*HH + hp)*WKEPT + wp)*CC + c0 + cl] = make_float2(vr[k], vi[k]);
    }
}

// ---------------------------------------------------------------------------
// P4 (fused): layer1 + layer2 + soft-threshold in one kernel.
//   o1k = relu(a@W1P + an@W1M + b1[0]);  o1nk = relu(an@W1P + a@W1M + b1[1])
//   s   = st(o1k@WK + o1nk@WNK + BEFF)
// o1 never leaves the CU (registers -> swizzled LDS transpose -> layer2).
// Thread tile: 2 points x 12 outputs. 256 thr: og=tid&7 (12-out groups),
// pg=tid>>3 (2-pt groups). LDS transpose swizzle: col = (p + 2*row) & 63,
// rows padded to 68 (conflict-free b64 reads, ~2-4-way staging writes).
// grid (260, 8). LDS 52.2 KB -> 3 blocks/CU; launch_bounds(256,3) frees VGPRs.
// ---------------------------------------------------------------------------
__global__ __launch_bounds__(256, 3) void k_mlp(
    const float* __restrict__ a, const float* __restrict__ x,
    const float* __restrict__ W1P, const float* __restrict__ W1M,
    const float* __restrict__ b1,
    const float* __restrict__ WKm, const float* __restrict__ WNK,
    const float* __restrict__ BEFF, float* __restrict__ sout)
{
    const int tid = threadIdx.x;
    const int n = blockIdx.y;
    const int P0 = blockIdx.x * 64;
    __shared__ float As[96*68];   // 26.1 KB
    __shared__ float Bs[96*68];   // 26.1 KB

    // stage a / an transposed + swizzled: As[i][col(p,i)] = a[P0+p][i]
    for (int idx = tid; idx < 64*96; idx += 256) {
        int p = idx / 96, i = idx - p*96;
        int P = P0 + p;
        float av = a[(size_t)P*CC + n*BS + i];
        int b = P / (HH*WKEPT);
        int rem = P - b*(HH*WKEPT);
        int h = rem / WKEPT;
        int wq = rem - h*WKEPT;
        int hh2 = (HH - h) & (HH-1);
        int ww2 = (WW - wq) & (WW-1);
        float anv = x[(size_t)((b*HH + hh2)*WW + ww2)*CC + n*BS + i];
        int col = (p + 2*i) & 63;
        As[i*68 + col] = av;
        Bs[i*68 + col] = anv;
    }
    __syncthreads();

    const int og = tid & 7;        // 8 output groups x 12
    const int pg = tid >> 3;       // 32 point groups x 2
    const int ob = og * 12;
    const int p0 = pg * 2;

    float ak[2][12], ank[2][12];
    #pragma unroll
    for (int j = 0; j < 12; ++j) {
        ak[0][j] = 0.f; ak[1][j] = 0.f; ank[0][j] = 0.f; ank[1][j] = 0.f;
    }

    // ---- layer 1 ----
    {
        const float* wp = W1P + n*BS*BS + ob;
        const float* wm = W1M + n*BS*BS + ob;
        #pragma unroll 2
        for (int i = 0; i < 96; ++i) {
            int cix = (p0 + 2*i) & 63;
            float2 av = *(const float2*)&As[i*68 + cix];
            float2 bv = *(const float2*)&Bs[i*68 + cix];
            const float4* p4 = (const float4*)(wp + i*BS);
            const float4* m4 = (const float4*)(wm + i*BS);
            #pragma unroll
            for (int jj = 0; jj < 3; ++jj) {
                float4 qp = p4[jj], qm = m4[jj];
                int j0 = 4*jj;
                ak [0][j0+0] = fmaf(av.x, qp.x, fmaf(bv.x, qm.x, ak [0][j0+0]));
                ak [1][j0+0] = fmaf(av.y, qp.x, fmaf(bv.y, qm.x, ak [1][j0+0]));
                ank[0][j0+0] = fmaf(bv.x, qp.x, fmaf(av.x, qm.x, ank[0][j0+0]));
                ank[1][j0+0] = fmaf(bv.y, qp.x, fmaf(av.y, qm.x, ank[1][j0+0]));
                ak [0][j0+1] = fmaf(av.x, qp.y, fmaf(bv.x, qm.y, ak [0][j0+1]));
                ak [1][j0+1] = fmaf(av.y, qp.y, fmaf(bv.y, qm.y, ak [1][j0+1]));
                ank[0][j0+1] = fmaf(bv.x, qp.y, fmaf(av.x, qm.y, ank[0][j0+1]));
                ank[1][j0+1] = fmaf(bv.y, qp.y, fmaf(av.y, qm.y, ank[1][j0+1]));
                ak [0][j0+2] = fmaf(av.x, qp.z, fmaf(bv.x, qm.z, ak [0][j0+2]));
                ak [1][j0+2] = fmaf(av.y, qp.z, fmaf(bv.y, qm.z, ak [1][j0+2]));
                ank[0][j0+2] = fmaf(bv.x, qp.z, fmaf(av.x, qm.z, ank[0][j0+2]));
                ank[1][j0+2] = fmaf(bv.y, qp.z, fmaf(av.y, qm.z, ank[1][j0+2]));
                ak [0][j0+3] = fmaf(av.x, qp.w, fmaf(bv.x, qm.w, ak [0][j0+3]));
                ak [1][j0+3] = fmaf(av.y, qp.w, fmaf(bv.y, qm.w, ak [1][j0+3]));
                ank[0][j0+3] = fmaf(bv.x, qp.w, fmaf(av.x, qm.w, ank[0][j0+3]));
                ank[1][j0+3] = fmaf(bv.y, qp.w, fmaf(av.y, qm.w, ank[1][j0+3]));
            }
        }
    }

    // bias + relu, write o1 transposed back into As/Bs
    {
        const float* b1k = b1 + (0*NB + n)*BS + ob;
        const float* b1n = b1 + (1*NB + n)*BS + ob;
        float o1k[2][12], o1n[2][12];
        #pragma unroll
        for (int j = 0; j < 12; ++j) {
            float bk = b1k[j], bn = b1n[j];
            o1k[0][j] = fmaxf(ak [0][j] + bk, 0.f);
            o1k[1][j] = fmaxf(ak [1][j] + bk, 0.f);
            o1n[0][j] = fmaxf(ank[0][j] + bn, 0.f);
            o1n[1][j] = fmaxf(ank[1][j] + bn, 0.f);
        }
        __syncthreads();   // everyone done reading As/Bs
        #pragma unroll
        for (int j = 0; j < 12; ++j) {
            int o = ob + j;
            int col = (p0 + 2*o) & 63;
            *(float2*)&As[o*68 + col] = make_float2(o1k[0][j], o1k[1][j]);
            *(float2*)&Bs[o*68 + col] = make_float2(o1n[0][j], o1n[1][j]);
        }
        __syncthreads();
    }

    // ---- layer 2 (collapsed) ----
    float acc[2][12];
    #pragma unroll
    for (int j = 0; j < 12; ++j) { acc[0][j] = 0.f; acc[1][j] = 0.f; }
    {
        const float* wk = WKm + n*BS*BS + ob;
        const float* wn = WNK + n*BS*BS + ob;
        #pragma unroll 2
        for (int i = 0; i < 96; ++i) {
            int cix = (p0 + 2*i) & 63;
            float2 kv = *(const float2*)&As[i*68 + cix];
            float2 nv = *(const float2*)&Bs[i*68 + cix];
            const float4* k4 = (const float4*)(wk + i*BS);
            const float4* n4 = (const float4*)(wn + i*BS);
            #pragma unroll
            for (int jj = 0; jj < 3; ++jj) {
                float4 qk = k4[jj], qn = n4[jj];
                int j0 = 4*jj;
                acc[0][j0+0] = fmaf(kv.x, qk.x, fmaf(nv.x, qn.x, acc[0][j0+0]));
                acc[1][j0+0] = fmaf(kv.y, qk.x, fmaf(nv.y, qn.x, acc[1][j0+0]));
                acc[0][j0+1] = fmaf(kv.x, qk.y, fmaf(nv.x, qn.y, acc[0][j0+1]));
                acc[1][j0+1] = fmaf(kv.y, qk.y, fmaf(nv.y, qn.y, acc[1][j0+1]));
                acc[0][j0+2] = fmaf(kv.x, qk.z, fmaf(nv.x, qn.z, acc[0][j0+2]));
                acc[1][j0+2] = fmaf(kv.y, qk.z, fmaf(nv.y, qn.z, acc[1][j0+2]));
                acc[0][j0+3] = fmaf(kv.x, qk.w, fmaf(nv.x, qn.w, acc[0][j0+3]));
                acc[1][j0+3] = fmaf(kv.y, qk.w, fmaf(nv.y, qn.w, acc[1][j0+3]));
            }
        }
    }

    // soft-threshold + coalesced-ish float4 stores
    float r0[12], r1[12];
    #pragma unroll
    for (int j = 0; j < 12; ++j) {
        float be = BEFF[n*BS + ob + j];
        float v0 = acc[0][j] + be;
        float a0 = fabsf(v0) - 0.01f;
        r0[j] = (a0 > 0.f) ? copysignf(a0, v0) : 0.f;
        float v1 = acc[1][j] + be;
        float a1 = fabsf(v1) - 0.01f;
        r1[j] = (a1 > 0.f) ? copysignf(a1, v1) : 0.f;
    }
    {
        float* d0 = sout + (size_t)(P0 + p0    )*CC + n*BS + ob;
        float* d1 = sout + (size_t)(P0 + p0 + 1)*CC + n*BS + ob;
        ((float4*)d0)[0] = make_float4(r0[0], r0[1], r0[2],  r0[3]);
        ((float4*)d0)[1] = make_float4(r0[4], r0[5], r0[6],  r0[7]);
        ((float4*)d0)[2] = make_float4(r0[8], r0[9], r0[10], r0[11]);
        ((float4*)d1)[0] = make_float4(r1[0], r1[1], r1[2],  r1[3]);
        ((float4*)d1)[1] = make_float4(r1[4], r1[5], r1[6],  r1[7]);
        ((float4*)d1)[2] = make_float4(r1[8], r1[9], r1[10], r1[11]);
    }
}

// ---------------------------------------------------------------------------
// P7: inverse W expansion with output-pair symmetry (unchanged).
// ---------------------------------------------------------------------------
__global__ __launch_bounds__(256) void k_p7(
    const float2* __restrict__ A, const float* __restrict__ x,
    const float* __restrict__ c7t, const float* __restrict__ s7t,
    float* __restrict__ out)
{
    const int tid = threadIdx.x;
    const int ct = blockIdx.x % 3;
    const int wg = blockIdx.x / 3;        // 0..15
    const int rg = blockIdx.y;            // 0..63
    const int c  = ct*256 + tid;
    const int wpb = wg*8;
    const int row0 = rg*4;

    float accA[4][8], accB[4][8], acc128[4];
    #pragma unroll
    for (int r = 0; r < 4; ++r) {
        acc128[r] = 0.f;
        #pragma unroll
        for (int j = 0; j < 8; ++j) { accA[r][j] = 0.f; accB[r][j] = 0.f; }
    }

    const float2* A0 = A + (size_t)row0 * WKEPT * CC + c;
    const float4* cT = (const float4*)(c7t + (size_t)wg*65*8);
    const float4* sT = (const float4*)(s7t + (size_t)wg*65*8);
    for (int wq = 0; wq < 65; ++wq) {
        float4 c0 = cT[2*wq], c1 = cT[2*wq+1];
        float4 s0 = sT[2*wq], s1 = sT[2*wq+1];
        float sg = (wq & 1) ? -1.f : 1.f;
        #pragma unroll
        for (int r = 0; r < 4; ++r) {
            float2 v = A0[(size_t)(r*WKEPT + wq) * CC];
            float P = v.x + v.y;
            float M = v.y - v.x;
            float N = v.x - v.y;
            acc128[r] = fmaf(sg, P, acc128[r]);
            accA[r][0] = fmaf(P, c0.x, fmaf(M, s0.x, accA[r][0]));
            accB[r][0] = fmaf(P, c0.x, fmaf(N, s0.x, accB[r][0]));
            accA[r][1] = fmaf(P, c0.y, fmaf(M, s0.y, accA[r][1]));
            accB[r][1] = fmaf(P, c0.y, fmaf(N, s0.y, accB[r][1]));
            accA[r][2] = fmaf(P, c0.z, fmaf(M, s0.z, accA[r][2]));
            accB[r][2] = fmaf(P, c0.z, fmaf(N, s0.z, accB[r][2]));
            accA[r][3] = fmaf(P, c0.w, fmaf(M, s0.w, accA[r][3]));
            accB[r][3] = fmaf(P, c0.w, fmaf(N, s0.w, accB[r][3]));
            accA[r][4] = fmaf(P, c1.x, fmaf(M, s1.x, accA[r][4]));
            accB[r][4] = fmaf(P, c1.x, fmaf(N, s1.x, accB[r][4]));
            accA[r][5] = fmaf(P, c1.y, fmaf(M, s1.y, accA[r][5]));
            accB[r][5] = fmaf(P, c1.y, fmaf(N, s1.y, accB[r][5]));
            accA[r][6] = fmaf(P, c1.z, fmaf(M, s1.z, accA[r][6]));
            accB[r][6] = fmaf(P, c1.z, fmaf(N, s1.z, accB[r][6]));
            accA[r][7] = fmaf(P, c1.w, fmaf(M, s1.w, accA[r][7]));
            accB[r][7] = fmaf(P, c1.w, fmaf(N, s1.w, accB[r][7]));
        }
    }

    const float scale = 1.0f / 50331648.0f;
    #pragma unroll
    for (int r = 0; r < 4; ++r) {
        size_t base = (size_t)(row0 + r) * WW * CC + c;
        #pragma unroll
        for (int j = 0; j < 8; ++j) {
            int w = wpb + j;
            size_t g = base + (size_t)w*CC;
            out[g] = fmaf(accA[r][j], scale, x[g]);
            if (w != 0) {
                size_t g2 = base + (size_t)(256 - w)*CC;
                out[g2] = fmaf(accB[r][j], scale, x[g2]);
            }
        }
        if (wg == 0) {
            size_t g = base + (size_t)128*CC;
            out[g] = fmaf(acc128[r], scale, x[g]);
        }
    }
}

// ---------------------------------------------------------------------------
// P7 fallback (unchanged).
// ---------------------------------------------------------------------------
__global__ __launch_bounds__(256) void k_p7_fb(
    const float2* __restrict__ A, const float* __restrict__ x,
    float* __restrict__ out)
{
    const int tid = threadIdx.x;
    const int ct = blockIdx.x % 3;
    const int wg = blockIdx.x / 3;
    const int h = blockIdx.y, b = blockIdx.z;
    const int c = ct*256 + tid;
    __shared__ float cm[WKEPT][8];
    __shared__ float cp[WKEPT][8];
    for (int idx = tid; idx < WKEPT*8; idx += 256) {
        int wq = idx >> 3, j = idx & 7;
        int w = wg*8 + j;
        int ai = (w * wq) & 255;
        float sn, cse; sincosf(TWOPI * (float)ai / 256.f, &sn, &cse);
        cm[wq][j] = cse - sn;
        cp[wq][j] = cse + sn;
    }
    __syncthreads();
    float acc[8] = {0,0,0,0,0,0,0,0};
    const float2* Ab = A + (size_t)((b*HH + h)*WKEPT)*CC + c;
    for (int wq = 0; wq < WKEPT; ++wq) {
        float2 v = Ab[(size_t)wq*CC];
        const float4* m4 = (const float4*)(&cm[wq][0]);
        const float4* p4 = (const float4*)(&cp[wq][0]);
        #pragma unroll
        for (int jj = 0; jj < 2; ++jj) {
            float4 qm = m4[jj], qp = p4[jj];
            acc[4*jj+0] += v.x*qm.x + v.y*qp.x;
            acc[4*jj+1] += v.x*qm.y + v.y*qp.y;
            acc[4*jj+2] += v.x*qm.z + v.y*qp.z;
            acc[4*jj+3] += v.x*qm.w + v.y*qp.w;
        }
    }
    const float scale = 1.0f / 50331648.0f;
    size_t base = (size_t)(b*HH + h)*WW*CC + c;
    #pragma unroll
    for (int j = 0; j < 8; ++j) {
        int w = wg*8 + j;
        size_t g = base + (size_t)w*CC;
        out[g] = fmaf(acc[j], scale, x[g]);
    }
}

// ---------------------------------------------------------------------------
// Launch. ws layout (floats):
//   [0 : 25,559,040)   complex buffer A (16640*768 float2)
//                      first half doubles as a_real, second half as s_real
//   [25,559,040 ...)   W1P, W1M, WK, WNK (each 73728), BEFF (768)
//   then c1t, s1t (9144 each), c7t, s7t (8320 each)   — twiddle tables
// d_out doubles as complex buffer B.
// ---------------------------------------------------------------------------
extern "C" void kernel_launch(void* const* d_in, const int* in_sizes, int n_in,
                              void* d_out, int out_size, void* d_ws, size_t ws_size,
                              hipStream_t stream)
{
    (void)in_sizes; (void)n_in; (void)out_size;
    const float* x  = (const float*)d_in[0];
    const float* w1 = (const float*)d_in[1];
    const float* b1 = (const float*)d_in[2];
    const float* w2 = (const float*)d_in[3];
    const float* b2 = (const float*)d_in[4];

    float*  ws     = (float*)d_ws;
    float2* Abuf   = (float2*)d_ws;
    float*  a_real = ws;
    float*  s_real = ws + (size_t)NPTS*CC;
    float*  W1P    = ws + 2*(size_t)NPTS*CC;
    float*  W1M    = W1P + NB*BS*BS;
    float*  WKm    = W1M + NB*BS*BS;
    float*  WNK    = WKm + NB*BS*BS;
    float*  BEFF   = WNK + NB*BS*BS;
    float*  c1t    = BEFF + NB*BS;
    float*  s1t    = c1t + P1_TW;
    float*  c7t    = s1t + P1_TW;
    float*  s7t    = c7t + P7_TW;

    const size_t need_bytes =
        ((size_t)2*NPTS*CC + 4*(size_t)NB*BS*BS + NB*BS + 2*P1_TW + 2*P7_TW)
        * sizeof(float);
    const bool fast = (ws_size >= need_bytes);

    float2* Bc   = (float2*)d_out;
    float*  outf = (float*)d_out;

    k_weights<<<dim3(NB), dim3(256), 0, stream>>>(w1, w2, b2, W1P, W1M, WKm, WNK, BEFF);
    if (fast) {
        k_tw<<<dim3(36), dim3(256), 0, stream>>>(c1t, s1t, c7t, s7t);
        k_p1<<<dim3(27, 64), dim3(256), 0, stream>>>(x, c1t, s1t, Abuf);
    } else {
        k_p1_fb<<<dim3(27, HH, BB), dim3(256), 0, stream>>>(x, Abuf);
    }
    k_cfft   <<<dim3(NPTS/LPB), dim3(256), 0, stream>>>(Abuf, Bc);
    k_hb_c2a <<<dim3(48, WKEPT), dim3(256), 0, stream>>>(Bc, a_real);
    k_mlp    <<<dim3(260, NB), dim3(256), 0, stream>>>(a_real, x, W1P, W1M, b1,
                                                       WKm, WNK, BEFF, s_real);
    k_hb_s2c <<<dim3(48, WKEPT), dim3(256), 0, stream>>>(s_real, Bc);
    k_cfft   <<<dim3(NPTS/LPB), dim3(256), 0, stream>>>(Bc, Abuf);
    if (fast) {
        k_p7<<<dim3(48, 64), dim3(256), 0, stream>>>(Abuf, x, c7t, s7t, outf);
    } else {
        k_p7_fb<<<dim3(96, HH, BB), dim3(256), 0, stream>>>(Abuf, x, outf);
    }
}

// Round 4
// 1810.652 us; speedup vs baseline: 1.3348x; 1.0155x over previous
//
#include <hip/hip_runtime.h>

#define BB 2
#define HH 128
#define WW 256
#define CC 768
#define NB 8
#define BS 96
#define WKEPT 65
#define NPTS (BB*HH*WKEPT)        // 16640 kept (b,h,w') points
#define NTOT ((size_t)BB*HH*WW*CC) // 50331648
#define TWOPI 6.283185307179586f

#define P1_TW (9*127*8)           // 9144 entries (cos + sin tables)
#define P7_TW (16*65*8)           // 8320 entries

// ---------------------------------------------------------------------------
// K0: precombine weights (unchanged).
// ---------------------------------------------------------------------------
__global__ __launch_bounds__(256) void k_weights(
    const float* __restrict__ w1, const float* __restrict__ w2,
    const float* __restrict__ b2,
    float* __restrict__ W1P, float* __restrict__ W1M,
    float* __restrict__ WKm, float* __restrict__ WNK, float* __restrict__ BEFF)
{
    const int n = blockIdx.x;
    const int tid = threadIdx.x;
    __shared__ float m_s[BS*BS];

    const float* w2a = w2 + (size_t)(0*NB + n)*BS*BS;
    const float* w2b = w2 + (size_t)(1*NB + n)*BS*BS;
    for (int idx = tid; idx < BS*BS; idx += 256)
        m_s[idx] = 0.5f*(w2a[idx] - w2b[idx]);

    const float* w1a = w1 + (size_t)(0*NB + n)*BS*BS;
    const float* w1b = w1 + (size_t)(1*NB + n)*BS*BS;
    for (int idx = tid; idx < BS*BS; idx += 256) {
        float t0 = w1a[idx], t1 = w1b[idx];
        W1P[n*BS*BS + idx] = 0.5f*(t0 + t1);
        W1M[n*BS*BS + idx] = 0.5f*(t0 - t1);
    }
    __syncthreads();

    for (int idx = tid; idx < BS*BS; idx += 256) {
        int i = idx / BS, o = idx - i*BS;
        float p_io = 0.5f*(w2a[idx] + w2b[idx]);
        float m_io = m_s[idx];
        float accK = 0.f, accN = 0.f;
        for (int j = 0; j < BS; ++j) {
            float p_ij = 0.5f*(w2a[i*BS + j] + w2b[i*BS + j]);
            float mjo  = m_s[j*BS + o];
            accK += p_ij * mjo;
            accN += m_s[i*BS + j] * mjo;
        }
        WKm[n*BS*BS + idx] = p_io + accK;
        WNK[n*BS*BS + idx] = p_io + m_io + accN;
    }
    if (tid < BS) {
        const float* b2a = b2 + (0*NB + n)*BS;
        const float* b2b = b2 + (1*NB + n)*BS;
        float acc = b2a[tid] + b2b[tid];
        for (int j = 0; j < BS; ++j) acc += b2a[j] * m_s[j*BS + tid];
        BEFF[n*BS + tid] = acc;
    }
}

// ---------------------------------------------------------------------------
// K-tw: twiddle tables in GLOBAL memory (unchanged).
// ---------------------------------------------------------------------------
__global__ __launch_bounds__(256) void k_tw(
    float* __restrict__ c1t, float* __restrict__ s1t,
    float* __restrict__ c7t, float* __restrict__ s7t)
{
    int idx = blockIdx.x*256 + threadIdx.x;
    if (idx < P1_TW) {
        int j = idx & 7; int rest = idx >> 3;
        int w = rest % 127 + 1; int wg = rest / 127;
        int ai = (w * (wg*8 + j)) & 255;
        float sn, cs; sincosf(TWOPI * (float)ai / 256.0f, &sn, &cs);
        c1t[idx] = cs; s1t[idx] = sn;
    }
    if (idx < P7_TW) {
        int j = idx & 7; int rest = idx >> 3;
        int wq = rest % 65; int wg = rest / 65;
        int ai = ((wg*8 + j) * wq) & 255;
        float sn, cs; sincosf(TWOPI * (float)ai / 256.0f, &sn, &cs);
        c7t[idx] = cs; s7t[idx] = sn;
    }
}

// ---------------------------------------------------------------------------
// P1: forward W-axis pruned DFT, folded pairs, global twiddles (unchanged).
// ---------------------------------------------------------------------------
__global__ __launch_bounds__(256) void k_p1(
    const float* __restrict__ x, const float* __restrict__ c1t,
    const float* __restrict__ s1t, float2* __restrict__ out)
{
    const int tid = threadIdx.x;
    const int ct = blockIdx.x % 3;
    const int wg = blockIdx.x / 3;        // 0..8
    const int rg = blockIdx.y;            // 0..63, row = b*HH+h
    const int c  = ct*256 + tid;
    const int wpb = wg*8;
    const int row0 = rg*4;

    float re[4][8], im[4][8];
    const float* xr0 = x + (size_t)row0 * WW * CC + c;

    #pragma unroll
    for (int r = 0; r < 4; ++r) {
        const float* xr = xr0 + (size_t)r * WW * CC;
        float x0v   = xr[0];
        float x128v = xr[(size_t)128*CC];
        #pragma unroll
        for (int j = 0; j < 8; ++j) {
            re[r][j] = (((wpb + j) & 1) ? (x0v - x128v) : (x0v + x128v));
            im[r][j] = 0.f;
        }
    }

    const float4* cT = (const float4*)(c1t + (size_t)wg*127*8);
    const float4* sT = (const float4*)(s1t + (size_t)wg*127*8);
    for (int w = 1; w <= 127; ++w) {
        float4 c0 = cT[2*(w-1)], c1 = cT[2*(w-1)+1];
        float4 s0 = sT[2*(w-1)], s1 = sT[2*(w-1)+1];
        #pragma unroll
        for (int r = 0; r < 4; ++r) {
            const float* xr = xr0 + (size_t)r * WW * CC;
            float a = xr[(size_t)w*CC];
            float b = xr[(size_t)(256-w)*CC];
            float u = a + b, d = a - b;
            re[r][0] = fmaf(u, c0.x, re[r][0]);  im[r][0] = fmaf(-d, s0.x, im[r][0]);
            re[r][1] = fmaf(u, c0.y, re[r][1]);  im[r][1] = fmaf(-d, s0.y, im[r][1]);
            re[r][2] = fmaf(u, c0.z, re[r][2]);  im[r][2] = fmaf(-d, s0.z, im[r][2]);
            re[r][3] = fmaf(u, c0.w, re[r][3]);  im[r][3] = fmaf(-d, s0.w, im[r][3]);
            re[r][4] = fmaf(u, c1.x, re[r][4]);  im[r][4] = fmaf(-d, s1.x, im[r][4]);
            re[r][5] = fmaf(u, c1.y, re[r][5]);  im[r][5] = fmaf(-d, s1.y, im[r][5]);
            re[r][6] = fmaf(u, c1.z, re[r][6]);  im[r][6] = fmaf(-d, s1.z, im[r][6]);
            re[r][7] = fmaf(u, c1.w, re[r][7]);  im[r][7] = fmaf(-d, s1.w, im[r][7]);
        }
    }

    #pragma unroll
    for (int r = 0; r < 4; ++r) {
        #pragma unroll
        for (int j = 0; j < 8; ++j) {
            int wp = wpb + j;
            if (wp < WKEPT)
                out[(size_t)((row0 + r)*WKEPT + wp) * CC + c] = make_float2(re[r][j], im[r][j]);
        }
    }
}

// ---------------------------------------------------------------------------
// P1 fallback (LDS twiddles) — only if ws lacks table headroom.
// ---------------------------------------------------------------------------
__global__ __launch_bounds__(256) void k_p1_fb(
    const float* __restrict__ x, float2* __restrict__ out)
{
    const int tid = threadIdx.x;
    const int ct = blockIdx.x % 3;
    const int wg = blockIdx.x / 3;
    const int h = blockIdx.y, b = blockIdx.z;
    const int c = ct*256 + tid;
    const int wpb = wg*8;

    __shared__ float2 tw[256][8];
    for (int idx = tid; idx < 2048; idx += 256) {
        int w = idx >> 3, j = idx & 7;
        int ai = (w * (wpb + j)) & 255;
        float sn, cs; sincosf(TWOPI * (float)ai / 256.0f, &sn, &cs);
        tw[w][j] = make_float2(cs, sn);
    }
    __syncthreads();

    float re[8] = {0,0,0,0,0,0,0,0}, im[8] = {0,0,0,0,0,0,0,0};
    const float* xrow = x + (size_t)(b*HH + h) * WW * CC + c;
    for (int w = 0; w < 256; ++w) {
        float xv = xrow[(size_t)w * CC];
        const float4* t4 = (const float4*)(&tw[w][0]);
        #pragma unroll
        for (int jj = 0; jj < 4; ++jj) {
            float4 q = t4[jj];
            re[2*jj]   += xv * q.x;  im[2*jj]   -= xv * q.y;
            re[2*jj+1] += xv * q.z;  im[2*jj+1] -= xv * q.w;
        }
    }
    #pragma unroll
    for (int j = 0; j < 8; ++j) {
        int wp = wpb + j;
        if (wp < WKEPT)
            out[(size_t)((b*HH + h)*WKEPT + wp) * CC + c] = make_float2(re[j], im[j]);
    }
}

// ---------------------------------------------------------------------------
// P2/P6: C-axis 768-pt FFT per line (unchanged).
// ---------------------------------------------------------------------------
#define LPB 4
__global__ __launch_bounds__(256) void k_cfft(
    const float2* __restrict__ in, float2* __restrict__ out)
{
    __shared__ float2 tw[CC];
    __shared__ float2 bufA[LPB*CC];
    __shared__ float2 bufB[LPB*CC];
    const int tid = threadIdx.x;
    const size_t line0 = (size_t)blockIdx.x * LPB;

    for (int t = tid; t < CC; t += 256) {
        float sn, cs; sincosf(TWOPI * (float)t / 768.0f, &sn, &cs);
        tw[t] = make_float2(cs, -sn);
    }
    for (int idx = tid; idx < LPB*CC; idx += 256) {
        int l = idx / CC, c = idx - l*CC;
        int m = c / 3, j = c - 3*m;
        bufA[l*CC + j*256 + m] = in[(line0 + l)*CC + c];
    }
    __syncthreads();

    float2* src = bufA;
    float2* dst = bufB;
    #pragma unroll
    for (int st = 0; st < 8; ++st) {
        const int s = 1 << st;
        const int h = 128 >> st;
        for (int item = tid; item < LPB*3*128; item += 256) {
            int sub = item >> 7;
            int t   = item & 127;
            int q = t & (s - 1);
            int p = t >> st;
            float2 a = src[sub*256 + q + s*p];
            float2 b = src[sub*256 + q + s*(p + h)];
            float2 w = tw[p * (3 << st)];
            float dx = a.x - b.x, dy = a.y - b.y;
            dst[sub*256 + q + s*(2*p)]     = make_float2(a.x + b.x, a.y + b.y);
            dst[sub*256 + q + s*(2*p + 1)] = make_float2(dx*w.x - dy*w.y, dx*w.y + dy*w.x);
        }
        __syncthreads();
        float2* tmp = src; src = dst; dst = tmp;
    }
    for (int idx = tid; idx < LPB*CC; idx += 256) {
        int l = idx / CC, cp = idx - l*CC;
        int r = cp & 255;
        float2 S0 = src[(l*3 + 0)*256 + r];
        float2 S1 = src[(l*3 + 1)*256 + r];
        float2 S2 = src[(l*3 + 2)*256 + r];
        float2 w1 = tw[cp];
        int i2 = 2*cp; if (i2 >= CC) i2 -= CC;
        float2 w2 = tw[i2];
        float fr = S0.x + w1.x*S1.x - w1.y*S1.y + w2.x*S2.x - w2.y*S2.y;
        float fi = S0.y + w1.x*S1.y + w1.y*S1.x + w2.x*S2.y + w2.y*S2.x;
        out[(line0 + l)*CC + cp] = make_float2(fr, fi);
    }
}

// ---------------------------------------------------------------------------
// P3: H-axis 128-pt DFT + B butterfly, complex -> a=Re+Im (unchanged).
// ---------------------------------------------------------------------------
#define CT3 16
__global__ __launch_bounds__(256) void k_hb_c2a(
    const float2* __restrict__ in, float* __restrict__ aout)
{
    const int tid = threadIdx.x;
    const int wp = blockIdx.y;
    const int c0 = blockIdx.x * CT3;
    __shared__ float2 us[HH][CT3];
    __shared__ float2 vs[HH][CT3];
    __shared__ float2 rt[HH];
    if (tid < HH) { float sn, cse; sincosf(TWOPI*(float)tid/128.f, &sn, &cse); rt[tid] = make_float2(cse, sn); }
    for (int idx = tid; idx < HH*CT3; idx += 256) {
        int h = idx / CT3, cl = idx - (idx / CT3)*CT3;
        float2 z0 = in[(size_t)((0*HH + h)*WKEPT + wp)*CC + c0 + cl];
        float2 z1 = in[(size_t)((1*HH + h)*WKEPT + wp)*CC + c0 + cl];
        us[h][cl] = make_float2(z0.x+z1.x, z0.y+z1.y);
        vs[h][cl] = make_float2(z0.x-z1.x, z0.y-z1.y);
    }
    __syncthreads();
    const int cl = tid & 15, hg = tid >> 4;
    float ur[8]={0,0,0,0,0,0,0,0}, ui[8]={0,0,0,0,0,0,0,0};
    float vr[8]={0,0,0,0,0,0,0,0}, vi[8]={0,0,0,0,0,0,0,0};
    for (int h = 0; h < HH; ++h) {
        float2 u = us[h][cl], v = vs[h][cl];
        #pragma unroll
        for (int k = 0; k < 8; ++k) {
            int hp = k*16 + hg;
            float2 t = rt[(h*hp) & 127];
            ur[k] += u.x*t.x + u.y*t.y;  ui[k] += u.y*t.x - u.x*t.y;
            vr[k] += v.x*t.x + v.y*t.y;  vi[k] += v.y*t.x - v.x*t.y;
        }
    }
    #pragma unroll
    for (int k = 0; k < 8; ++k) {
        int hp = k*16 + hg;
        aout[(size_t)((0*HH + hp)*WKEPT + wp)*CC + c0 + cl] = ur[k] + ui[k];
        aout[(size_t)((1*HH + hp)*WKEPT + wp)*CC + c0 + cl] = vr[k] + vi[k];
    }
}

// ---------------------------------------------------------------------------
// P5: H-axis 128-pt DFT + B butterfly, real -> complex (unchanged).
// ---------------------------------------------------------------------------
__global__ __launch_bounds__(256) void k_hb_s2c(
    const float* __restrict__ sreal, float2* __restrict__ out)
{
    const int tid = threadIdx.x;
    const int wp = blockIdx.y;
    const int c0 = blockIdx.x * CT3;
    __shared__ float us[HH][CT3];
    __shared__ float vs[HH][CT3];
    __shared__ float2 rt[HH];
    if (tid < HH) { float sn, cse; sincosf(TWOPI*(float)tid/128.f, &sn, &cse); rt[tid] = make_float2(cse, sn); }
    for (int idx = tid; idx < HH*CT3; idx += 256) {
        int h = idx / CT3, cl = idx - (idx / CT3)*CT3;
        float z0 = sreal[(size_t)((0*HH + h)*WKEPT + wp)*CC + c0 + cl];
        float z1 = sreal[(size_t)((1*HH + h)*WKEPT + wp)*CC + c0 + cl];
        us[h][cl] = z0 + z1;
        vs[h][cl] = z0 - z1;
    }
    __syncthreads();
    const int cl = tid & 15, hg = tid >> 4;
    float ur[8]={0,0,0,0,0,0,0,0}, ui[8]={0,0,0,0,0,0,0,0};
    float vr[8]={0,0,0,0,0,0,0,0}, vi[8]={0,0,0,0,0,0,0,0};
    for (int h = 0; h < HH; ++h) {
        float u = us[h][cl], v = vs[h][cl];
        #pragma unroll
        for (int k = 0; k < 8; ++k) {
            int hp = k*16 + hg;
            float2 t = rt[(h*hp) & 127];
            ur[k] += u*t.x;  ui[k] -= u*t.y;
            vr[k] += v*t.x;  vi[k] -= v*t.y;
        }
    }
    #pragma unroll
    for (int k = 0; k < 8; ++k) {
        int hp = k*16 + hg;
        out[(size_t)((0*HH + hp)*WKEPT + wp)*CC + c0 + cl] = make_float2(ur[k], ui[k]);
        out[(size_t)((1*HH + hp)*WKEPT + wp)*CC + c0 + cl] = make_float2(vr[k], vi[k]);
    }
}

// ---------------------------------------------------------------------------
// P4 (fused, v2): layer1 + layer2 + soft-threshold.
// Re-tiled so WEIGHTS ARE WAVE-UNIFORM -> scalar (s_load) path:
//   lane (0..63)  = point p          (64 points per block)
//   wave (0..3)   = 24-output slice  (ob = wave*24, forced uniform via
//                                     readfirstlane)
// Per i-step a wave reads 2 conflict-free ds_read_b32 (activations,
// stride-1 across lanes) + 48 scalar weight floats (s_load_dwordx8/16,
// constant cache — no VMEM-vector traffic, no VGPR cost).
// LDS: As/Bs [96][67] (pad 67: stage stride-67 = free, reads stride-1).
// o1 round-trips through As/Bs (transpose in LDS); result staged through
// As ([64][97]) for coalesced stores. grid (260, 8), 256 thr.
// ---------------------------------------------------------------------------
__global__ __launch_bounds__(256, 3) void k_mlp(
    const float* __restrict__ a, const float* __restrict__ x,
    const float* __restrict__ W1P, const float* __restrict__ W1M,
    const float* __restrict__ b1,
    const float* __restrict__ WKm, const float* __restrict__ WNK,
    const float* __restrict__ BEFF, float* __restrict__ sout)
{
    const int tid = threadIdx.x;
    const int n = blockIdx.y;
    const int P0 = blockIdx.x * 64;
    __shared__ float As[96*67];   // 25.7 KB
    __shared__ float Bs[96*67];   // 25.7 KB

    // stage a / an transposed: As[i][p] = a[P0+p][i], Bs[i][p] = an
    for (int idx = tid; idx < 64*96; idx += 256) {
        int p = idx / 96, i = idx - p*96;
        int P = P0 + p;
        float av = a[(size_t)P*CC + n*BS + i];
        int b = P / (HH*WKEPT);
        int rem = P - b*(HH*WKEPT);
        int h = rem / WKEPT;
        int wq = rem - h*WKEPT;
        int hh2 = (HH - h) & (HH-1);
        int ww2 = (WW - wq) & (WW-1);
        float anv = x[(size_t)((b*HH + hh2)*WW + ww2)*CC + n*BS + i];
        As[i*67 + p] = av;
        Bs[i*67 + p] = anv;
    }
    __syncthreads();

    const int lane = tid & 63;
    const int wv = __builtin_amdgcn_readfirstlane(tid >> 6);  // 0..3, uniform
    const int ob = wv * 24;

    float ak[24], ank[24];
    #pragma unroll
    for (int j = 0; j < 24; ++j) { ak[j] = 0.f; ank[j] = 0.f; }

    // ---- layer 1 ----
    {
        const float* wp = W1P + n*BS*BS + ob;
        const float* wm = W1M + n*BS*BS + ob;
        #pragma unroll 2
        for (int i = 0; i < 96; ++i) {
            float av = As[i*67 + lane];
            float bv = Bs[i*67 + lane];
            const float* wpr = wp + i*BS;
            const float* wmr = wm + i*BS;
            #pragma unroll
            for (int j = 0; j < 24; ++j) {
                float qp = wpr[j];
                float qm = wmr[j];
                ak [j] = fmaf(av, qp, fmaf(bv, qm, ak [j]));
                ank[j] = fmaf(bv, qp, fmaf(av, qm, ank[j]));
            }
        }
    }

    // bias + relu (uniform bias via scalar loads), transpose o1 into As/Bs
    {
        const float* b1k = b1 + (0*NB + n)*BS + ob;
        const float* b1n = b1 + (1*NB + n)*BS + ob;
        float o1kv[24], o1nv[24];
        #pragma unroll
        for (int j = 0; j < 24; ++j) {
            o1kv[j] = fmaxf(ak [j] + b1k[j], 0.f);
            o1nv[j] = fmaxf(ank[j] + b1n[j], 0.f);
        }
        __syncthreads();   // everyone done reading As/Bs
        #pragma unroll
        for (int j = 0; j < 24; ++j) {
            As[(ob + j)*67 + lane] = o1kv[j];
            Bs[(ob + j)*67 + lane] = o1nv[j];
        }
        __syncthreads();
    }

    // ---- layer 2 (collapsed) ----
    float acc[24];
    #pragma unroll
    for (int j = 0; j < 24; ++j) acc[j] = 0.f;
    {
        const float* wk = WKm + n*BS*BS + ob;
        const float* wn = WNK + n*BS*BS + ob;
        #pragma unroll 2
        for (int i = 0; i < 96; ++i) {
            float kv = As[i*67 + lane];
            float nv = Bs[i*67 + lane];
            const float* wkr = wk + i*BS;
            const float* wnr = wn + i*BS;
            #pragma unroll
            for (int j = 0; j < 24; ++j) {
                acc[j] = fmaf(kv, wkr[j], fmaf(nv, wnr[j], acc[j]));
            }
        }
    }

    // soft-threshold, stage through LDS for coalesced stores
    {
        const float* be = BEFF + n*BS + ob;
        float r[24];
        #pragma unroll
        for (int j = 0; j < 24; ++j) {
            float v = acc[j] + be[j];
            float av2 = fabsf(v) - 0.01f;
            r[j] = (av2 > 0.f) ? copysignf(av2, v) : 0.f;
        }
        __syncthreads();   // done reading As/Bs for layer 2
        #pragma unroll
        for (int j = 0; j < 24; ++j)
            As[lane*97 + ob + j] = r[j];   // 64*97 = 6208 <= 6432, fits in As
        __syncthreads();
    }
    for (int idx = tid; idx < 64*96; idx += 256) {
        int p2 = idx / 96, o = idx - p2*96;
        sout[(size_t)(P0 + p2)*CC + n*BS + o] = As[p2*97 + o];
    }
}

// ---------------------------------------------------------------------------
// P7: inverse W expansion with output-pair symmetry (unchanged).
// ---------------------------------------------------------------------------
__global__ __launch_bounds__(256) void k_p7(
    const float2* __restrict__ A, const float* __restrict__ x,
    const float* __restrict__ c7t, const float* __restrict__ s7t,
    float* __restrict__ out)
{
    const int tid = threadIdx.x;
    const int ct = blockIdx.x % 3;
    const int wg = blockIdx.x / 3;        // 0..15
    const int rg = blockIdx.y;            // 0..63
    const int c  = ct*256 + tid;
    const int wpb = wg*8;
    const int row0 = rg*4;

    float accA[4][8], accB[4][8], acc128[4];
    #pragma unroll
    for (int r = 0; r < 4; ++r) {
        acc128[r] = 0.f;
        #pragma unroll
        for (int j = 0; j < 8; ++j) { accA[r][j] = 0.f; accB[r][j] = 0.f; }
    }

    const float2* A0 = A + (size_t)row0 * WKEPT * CC + c;
    const float4* cT = (const float4*)(c7t + (size_t)wg*65*8);
    const float4* sT = (const float4*)(s7t + (size_t)wg*65*8);
    for (int wq = 0; wq < 65; ++wq) {
        float4 c0 = cT[2*wq], c1 = cT[2*wq+1];
        float4 s0 = sT[2*wq], s1 = sT[2*wq+1];
        float sg = (wq & 1) ? -1.f : 1.f;
        #pragma unroll
        for (int r = 0; r < 4; ++r) {
            float2 v = A0[(size_t)(r*WKEPT + wq) * CC];
            float P = v.x + v.y;
            float M = v.y - v.x;
            float N = v.x - v.y;
            acc128[r] = fmaf(sg, P, acc128[r]);
            accA[r][0] = fmaf(P, c0.x, fmaf(M, s0.x, accA[r][0]));
            accB[r][0] = fmaf(P, c0.x, fmaf(N, s0.x, accB[r][0]));
            accA[r][1] = fmaf(P, c0.y, fmaf(M, s0.y, accA[r][1]));
            accB[r][1] = fmaf(P, c0.y, fmaf(N, s0.y, accB[r][1]));
            accA[r][2] = fmaf(P, c0.z, fmaf(M, s0.z, accA[r][2]));
            accB[r][2] = fmaf(P, c0.z, fmaf(N, s0.z, accB[r][2]));
            accA[r][3] = fmaf(P, c0.w, fmaf(M, s0.w, accA[r][3]));
            accB[r][3] = fmaf(P, c0.w, fmaf(N, s0.w, accB[r][3]));
            accA[r][4] = fmaf(P, c1.x, fmaf(M, s1.x, accA[r][4]));
            accB[r][4] = fmaf(P, c1.x, fmaf(N, s1.x, accB[r][4]));
            accA[r][5] = fmaf(P, c1.y, fmaf(M, s1.y, accA[r][5]));
            accB[r][5] = fmaf(P, c1.y, fmaf(N, s1.y, accB[r][5]));
            accA[r][6] = fmaf(P, c1.z, fmaf(M, s1.z, accA[r][6]));
            accB[r][6] = fmaf(P, c1.z, fmaf(N, s1.z, accB[r][6]));
            accA[r][7] = fmaf(P, c1.w, fmaf(M, s1.w, accA[r][7]));
            accB[r][7] = fmaf(P, c1.w, fmaf(N, s1.w, accB[r][7]));
        }
    }

    const float scale = 1.0f / 50331648.0f;
    #pragma unroll
    for (int r = 0; r < 4; ++r) {
        size_t base = (size_t)(row0 + r) * WW * CC + c;
        #pragma unroll
        for (int j = 0; j < 8; ++j) {
            int w = wpb + j;
            size_t g = base + (size_t)w*CC;
            out[g] = fmaf(accA[r][j], scale, x[g]);
            if (w != 0) {
                size_t g2 = base + (size_t)(256 - w)*CC;
                out[g2] = fmaf(accB[r][j], scale, x[g2]);
            }
        }
        if (wg == 0) {
            size_t g = base + (size_t)128*CC;
            out[g] = fmaf(acc128[r], scale, x[g]);
        }
    }
}

// ---------------------------------------------------------------------------
// P7 fallback (unchanged).
// ---------------------------------------------------------------------------
__global__ __launch_bounds__(256) void k_p7_fb(
    const float2* __restrict__ A, const float* __restrict__ x,
    float* __restrict__ out)
{
    const int tid = threadIdx.x;
    const int ct = blockIdx.x % 3;
    const int wg = blockIdx.x / 3;
    const int h = blockIdx.y, b = blockIdx.z;
    const int c = ct*256 + tid;
    __shared__ float cm[WKEPT][8];
    __shared__ float cp[WKEPT][8];
    for (int idx = tid; idx < WKEPT*8; idx += 256) {
        int wq = idx >> 3, j = idx & 7;
        int w = wg*8 + j;
        int ai = (w * wq) & 255;
        float sn, cse; sincosf(TWOPI * (float)ai / 256.f, &sn, &cse);
        cm[wq][j] = cse - sn;
        cp[wq][j] = cse + sn;
    }
    __syncthreads();
    float acc[8] = {0,0,0,0,0,0,0,0};
    const float2* Ab = A + (size_t)((b*HH + h)*WKEPT)*CC + c;
    for (int wq = 0; wq < WKEPT; ++wq) {
        float2 v = Ab[(size_t)wq*CC];
        const float4* m4 = (const float4*)(&cm[wq][0]);
        const float4* p4 = (const float4*)(&cp[wq][0]);
        #pragma unroll
        for (int jj = 0; jj < 2; ++jj) {
            float4 qm = m4[jj], qp = p4[jj];
            acc[4*jj+0] += v.x*qm.x + v.y*qp.x;
            acc[4*jj+1] += v.x*qm.y + v.y*qp.y;
            acc[4*jj+2] += v.x*qm.z + v.y*qp.z;
            acc[4*jj+3] += v.x*qm.w + v.y*qp.w;
        }
    }
    const float scale = 1.0f / 50331648.0f;
    size_t base = (size_t)(b*HH + h)*WW*CC + c;
    #pragma unroll
    for (int j = 0; j < 8; ++j) {
        int w = wg*8 + j;
        size_t g = base + (size_t)w*CC;
        out[g] = fmaf(acc[j], scale, x[g]);
    }
}

// ---------------------------------------------------------------------------
// Launch. ws layout (floats):
//   [0 : 25,559,040)   complex buffer A (16640*768 float2)
//                      first half doubles as a_real, second half as s_real
//   [25,559,040 ...)   W1P, W1M, WK, WNK (each 73728), BEFF (768)
//   then c1t, s1t (9144 each), c7t, s7t (8320 each)   — twiddle tables
// d_out doubles as complex buffer B.
// ---------------------------------------------------------------------------
extern "C" void kernel_launch(void* const* d_in, const int* in_sizes, int n_in,
                              void* d_out, int out_size, void* d_ws, size_t ws_size,
                              hipStream_t stream)
{
    (void)in_sizes; (void)n_in; (void)out_size;
    const float* x  = (const float*)d_in[0];
    const float* w1 = (const float*)d_in[1];
    const float* b1 = (const float*)d_in[2];
    const float* w2 = (const float*)d_in[3];
    const float* b2 = (const float*)d_in[4];

    float*  ws     = (float*)d_ws;
    float2* Abuf   = (float2*)d_ws;
    float*  a_real = ws;
    float*  s_real = ws + (size_t)NPTS*CC;
    float*  W1P    = ws + 2*(size_t)NPTS*CC;
    float*  W1M    = W1P + NB*BS*BS;
    float*  WKm    = W1M + NB*BS*BS;
    float*  WNK    = WKm + NB*BS*BS;
    float*  BEFF   = WNK + NB*BS*BS;
    float*  c1t    = BEFF + NB*BS;
    float*  s1t    = c1t + P1_TW;
    float*  c7t    = s1t + P1_TW;
    float*  s7t    = c7t + P7_TW;

    const size_t need_bytes =
        ((size_t)2*NPTS*CC + 4*(size_t)NB*BS*BS + NB*BS + 2*P1_TW + 2*P7_TW)
        * sizeof(float);
    const bool fast = (ws_size >= need_bytes);

    float2* Bc   = (float2*)d_out;
    float*  outf = (float*)d_out;

    k_weights<<<dim3(NB), dim3(256), 0, stream>>>(w1, w2, b2, W1P, W1M, WKm, WNK, BEFF);
    if (fast) {
        k_tw<<<dim3(36), dim3(256), 0, stream>>>(c1t, s1t, c7t, s7t);
        k_p1<<<dim3(27, 64), dim3(256), 0, stream>>>(x, c1t, s1t, Abuf);
    } else {
        k_p1_fb<<<dim3(27, HH, BB), dim3(256), 0, stream>>>(x, Abuf);
    }
    k_cfft   <<<dim3(NPTS/LPB), dim3(256), 0, stream>>>(Abuf, Bc);
    k_hb_c2a <<<dim3(48, WKEPT), dim3(256), 0, stream>>>(Bc, a_real);
    k_mlp    <<<dim3(260, NB), dim3(256), 0, stream>>>(a_real, x, W1P, W1M, b1,
                                                       WKm, WNK, BEFF, s_real);
    k_hb_s2c <<<dim3(48, WKEPT), dim3(256), 0, stream>>>(s_real, Bc);
    k_cfft   <<<dim3(NPTS/LPB), dim3(256), 0, stream>>>(Bc, Abuf);
    if (fast) {
        k_p7<<<dim3(48, 64), dim3(256), 0, stream>>>(Abuf, x, c7t, s7t, outf);
    } else {
        k_p7_fb<<<dim3(96, HH, BB), dim3(256), 0, stream>>>(Abuf, x, outf);
    }
}

// Round 5
// 1416.102 us; speedup vs baseline: 1.7067x; 1.2786x over previous
//
#include <hip/hip_runtime.h>

#define BB 2
#define HH 128
#define WW 256
#define CC 768
#define NB 8
#define BS 96
#define WKEPT 65
#define NPTS (BB*HH*WKEPT)        // 16640 kept (b,h,w') points
#define NTOT ((size_t)BB*HH*WW*CC) // 50331648
#define TWOPI 6.283185307179586f

#define P1_TW (9*127*8)           // 9144 entries (cos + sin tables)
#define P7_TW (16*65*8)           // 8320 entries

// ---------------------------------------------------------------------------
// K0: precombine weights (unchanged).
// ---------------------------------------------------------------------------
__global__ __launch_bounds__(256) void k_weights(
    const float* __restrict__ w1, const float* __restrict__ w2,
    const float* __restrict__ b2,
    float* __restrict__ W1P, float* __restrict__ W1M,
    float* __restrict__ WKm, float* __restrict__ WNK, float* __restrict__ BEFF)
{
    const int n = blockIdx.x;
    const int tid = threadIdx.x;
    __shared__ float m_s[BS*BS];

    const float* w2a = w2 + (size_t)(0*NB + n)*BS*BS;
    const float* w2b = w2 + (size_t)(1*NB + n)*BS*BS;
    for (int idx = tid; idx < BS*BS; idx += 256)
        m_s[idx] = 0.5f*(w2a[idx] - w2b[idx]);

    const float* w1a = w1 + (size_t)(0*NB + n)*BS*BS;
    const float* w1b = w1 + (size_t)(1*NB + n)*BS*BS;
    for (int idx = tid; idx < BS*BS; idx += 256) {
        float t0 = w1a[idx], t1 = w1b[idx];
        W1P[n*BS*BS + idx] = 0.5f*(t0 + t1);
        W1M[n*BS*BS + idx] = 0.5f*(t0 - t1);
    }
    __syncthreads();

    for (int idx = tid; idx < BS*BS; idx += 256) {
        int i = idx / BS, o = idx - i*BS;
        float p_io = 0.5f*(w2a[idx] + w2b[idx]);
        float m_io = m_s[idx];
        float accK = 0.f, accN = 0.f;
        for (int j = 0; j < BS; ++j) {
            float p_ij = 0.5f*(w2a[i*BS + j] + w2b[i*BS + j]);
            float mjo  = m_s[j*BS + o];
            accK += p_ij * mjo;
            accN += m_s[i*BS + j] * mjo;
        }
        WKm[n*BS*BS + idx] = p_io + accK;
        WNK[n*BS*BS + idx] = p_io + m_io + accN;
    }
    if (tid < BS) {
        const float* b2a = b2 + (0*NB + n)*BS;
        const float* b2b = b2 + (1*NB + n)*BS;
        float acc = b2a[tid] + b2b[tid];
        for (int j = 0; j < BS; ++j) acc += b2a[j] * m_s[j*BS + tid];
        BEFF[n*BS + tid] = acc;
    }
}

// ---------------------------------------------------------------------------
// K-tw: twiddle tables in GLOBAL memory (unchanged).
// ---------------------------------------------------------------------------
__global__ __launch_bounds__(256) void k_tw(
    float* __restrict__ c1t, float* __restrict__ s1t,
    float* __restrict__ c7t, float* __restrict__ s7t)
{
    int idx = blockIdx.x*256 + threadIdx.x;
    if (idx < P1_TW) {
        int j = idx & 7; int rest = idx >> 3;
        int w = rest % 127 + 1; int wg = rest / 127;
        int ai = (w * (wg*8 + j)) & 255;
        float sn, cs; sincosf(TWOPI * (float)ai / 256.0f, &sn, &cs);
        c1t[idx] = cs; s1t[idx] = sn;
    }
    if (idx < P7_TW) {
        int j = idx & 7; int rest = idx >> 3;
        int wq = rest % 65; int wg = rest / 65;
        int ai = ((wg*8 + j) * wq) & 255;
        float sn, cs; sincosf(TWOPI * (float)ai / 256.0f, &sn, &cs);
        c7t[idx] = cs; s7t[idx] = sn;
    }
}

// ---------------------------------------------------------------------------
// P1: forward W-axis pruned DFT, folded pairs, global twiddles (unchanged).
// ---------------------------------------------------------------------------
__global__ __launch_bounds__(256) void k_p1(
    const float* __restrict__ x, const float* __restrict__ c1t,
    const float* __restrict__ s1t, float2* __restrict__ out)
{
    const int tid = threadIdx.x;
    const int ct = blockIdx.x % 3;
    const int wg = blockIdx.x / 3;        // 0..8
    const int rg = blockIdx.y;            // 0..63, row = b*HH+h
    const int c  = ct*256 + tid;
    const int wpb = wg*8;
    const int row0 = rg*4;

    float re[4][8], im[4][8];
    const float* xr0 = x + (size_t)row0 * WW * CC + c;

    #pragma unroll
    for (int r = 0; r < 4; ++r) {
        const float* xr = xr0 + (size_t)r * WW * CC;
        float x0v   = xr[0];
        float x128v = xr[(size_t)128*CC];
        #pragma unroll
        for (int j = 0; j < 8; ++j) {
            re[r][j] = (((wpb + j) & 1) ? (x0v - x128v) : (x0v + x128v));
            im[r][j] = 0.f;
        }
    }

    const float4* cT = (const float4*)(c1t + (size_t)wg*127*8);
    const float4* sT = (const float4*)(s1t + (size_t)wg*127*8);
    for (int w = 1; w <= 127; ++w) {
        float4 c0 = cT[2*(w-1)], c1 = cT[2*(w-1)+1];
        float4 s0 = sT[2*(w-1)], s1 = sT[2*(w-1)+1];
        #pragma unroll
        for (int r = 0; r < 4; ++r) {
            const float* xr = xr0 + (size_t)r * WW * CC;
            float a = xr[(size_t)w*CC];
            float b = xr[(size_t)(256-w)*CC];
            float u = a + b, d = a - b;
            re[r][0] = fmaf(u, c0.x, re[r][0]);  im[r][0] = fmaf(-d, s0.x, im[r][0]);
            re[r][1] = fmaf(u, c0.y, re[r][1]);  im[r][1] = fmaf(-d, s0.y, im[r][1]);
            re[r][2] = fmaf(u, c0.z, re[r][2]);  im[r][2] = fmaf(-d, s0.z, im[r][2]);
            re[r][3] = fmaf(u, c0.w, re[r][3]);  im[r][3] = fmaf(-d, s0.w, im[r][3]);
            re[r][4] = fmaf(u, c1.x, re[r][4]);  im[r][4] = fmaf(-d, s1.x, im[r][4]);
            re[r][5] = fmaf(u, c1.y, re[r][5]);  im[r][5] = fmaf(-d, s1.y, im[r][5]);
            re[r][6] = fmaf(u, c1.z, re[r][6]);  im[r][6] = fmaf(-d, s1.z, im[r][6]);
            re[r][7] = fmaf(u, c1.w, re[r][7]);  im[r][7] = fmaf(-d, s1.w, im[r][7]);
        }
    }

    #pragma unroll
    for (int r = 0; r < 4; ++r) {
        #pragma unroll
        for (int j = 0; j < 8; ++j) {
            int wp = wpb + j;
            if (wp < WKEPT)
                out[(size_t)((row0 + r)*WKEPT + wp) * CC + c] = make_float2(re[r][j], im[r][j]);
        }
    }
}

// ---------------------------------------------------------------------------
// P1 fallback (LDS twiddles) — only if ws lacks table headroom.
// ---------------------------------------------------------------------------
__global__ __launch_bounds__(256) void k_p1_fb(
    const float* __restrict__ x, float2* __restrict__ out)
{
    const int tid = threadIdx.x;
    const int ct = blockIdx.x % 3;
    const int wg = blockIdx.x / 3;
    const int h = blockIdx.y, b = blockIdx.z;
    const int c = ct*256 + tid;
    const int wpb = wg*8;

    __shared__ float2 tw[256][8];
    for (int idx = tid; idx < 2048; idx += 256) {
        int w = idx >> 3, j = idx & 7;
        int ai = (w * (wpb + j)) & 255;
        float sn, cs; sincosf(TWOPI * (float)ai / 256.0f, &sn, &cs);
        tw[w][j] = make_float2(cs, sn);
    }
    __syncthreads();

    float re[8] = {0,0,0,0,0,0,0,0}, im[8] = {0,0,0,0,0,0,0,0};
    const float* xrow = x + (size_t)(b*HH + h) * WW * CC + c;
    for (int w = 0; w < 256; ++w) {
        float xv = xrow[(size_t)w * CC];
        const float4* t4 = (const float4*)(&tw[w][0]);
        #pragma unroll
        for (int jj = 0; jj < 4; ++jj) {
            float4 q = t4[jj];
            re[2*jj]   += xv * q.x;  im[2*jj]   -= xv * q.y;
            re[2*jj+1] += xv * q.z;  im[2*jj+1] -= xv * q.w;
        }
    }
    #pragma unroll
    for (int j = 0; j < 8; ++j) {
        int wp = wpb + j;
        if (wp < WKEPT)
            out[(size_t)((b*HH + h)*WKEPT + wp) * CC + c] = make_float2(re[j], im[j]);
    }
}

// ---------------------------------------------------------------------------
// P2/P6: C-axis 768-pt FFT per line (unchanged).
// ---------------------------------------------------------------------------
#define LPB 4
__global__ __launch_bounds__(256) void k_cfft(
    const float2* __restrict__ in, float2* __restrict__ out)
{
    __shared__ float2 tw[CC];
    __shared__ float2 bufA[LPB*CC];
    __shared__ float2 bufB[LPB*CC];
    const int tid = threadIdx.x;
    const size_t line0 = (size_t)blockIdx.x * LPB;

    for (int t = tid; t < CC; t += 256) {
        float sn, cs; sincosf(TWOPI * (float)t / 768.0f, &sn, &cs);
        tw[t] = make_float2(cs, -sn);
    }
    for (int idx = tid; idx < LPB*CC; idx += 256) {
        int l = idx / CC, c = idx - l*CC;
        int m = c / 3, j = c - 3*m;
        bufA[l*CC + j*256 + m] = in[(line0 + l)*CC + c];
    }
    __syncthreads();

    float2* src = bufA;
    float2* dst = bufB;
    #pragma unroll
    for (int st = 0; st < 8; ++st) {
        const int s = 1 << st;
        const int h = 128 >> st;
        for (int item = tid; item < LPB*3*128; item += 256) {
            int sub = item >> 7;
            int t   = item & 127;
            int q = t & (s - 1);
            int p = t >> st;
            float2 a = src[sub*256 + q + s*p];
            float2 b = src[sub*256 + q + s*(p + h)];
            float2 w = tw[p * (3 << st)];
            float dx = a.x - b.x, dy = a.y - b.y;
            dst[sub*256 + q + s*(2*p)]     = make_float2(a.x + b.x, a.y + b.y);
            dst[sub*256 + q + s*(2*p + 1)] = make_float2(dx*w.x - dy*w.y, dx*w.y + dy*w.x);
        }
        __syncthreads();
        float2* tmp = src; src = dst; dst = tmp;
    }
    for (int idx = tid; idx < LPB*CC; idx += 256) {
        int l = idx / CC, cp = idx - l*CC;
        int r = cp & 255;
        float2 S0 = src[(l*3 + 0)*256 + r];
        float2 S1 = src[(l*3 + 1)*256 + r];
        float2 S2 = src[(l*3 + 2)*256 + r];
        float2 w1 = tw[cp];
        int i2 = 2*cp; if (i2 >= CC) i2 -= CC;
        float2 w2 = tw[i2];
        float fr = S0.x + w1.x*S1.x - w1.y*S1.y + w2.x*S2.x - w2.y*S2.y;
        float fi = S0.y + w1.x*S1.y + w1.y*S1.x + w2.x*S2.y + w2.y*S2.x;
        out[(line0 + l)*CC + cp] = make_float2(fr, fi);
    }
}

// ---------------------------------------------------------------------------
// P3 (new): H-axis via 128-pt radix-2 Stockham FFT (was O(128^2) direct DFT).
// Per block: 8 channels x (u,v) = 16 complex lines of 128.
//   u = z0+z1, v = z0-z1 (B-butterfly at load);  FFT along h;
//   a[b=0][hp] = Re(U)+Im(U), a[b=1][hp] = Re(V)+Im(V).
// 7 stages, tw[p<<st] = e^{-2pi i p/(128>>st)}. Natural-order output in bufB.
// LDS 33 KB -> 4 blocks/CU. grid (96, 65), 256 thr.
// ---------------------------------------------------------------------------
__global__ __launch_bounds__(256) void k_hb_c2a(
    const float2* __restrict__ in, float* __restrict__ aout)
{
    const int tid = threadIdx.x;
    const int wp = blockIdx.y;
    const int c0 = blockIdx.x * 8;
    __shared__ float2 tw[128];        // e^{-2pi i t/128}
    __shared__ float2 bufA[16*128];   // 16 KB
    __shared__ float2 bufB[16*128];   // 16 KB

    if (tid < 128) {
        float sn, cs; sincosf(TWOPI*(float)tid/128.f, &sn, &cs);
        tw[tid] = make_float2(cs, -sn);
    }
    // stage + B-butterfly: line 2*cl+0 = u, 2*cl+1 = v
    for (int idx = tid; idx < 1024; idx += 256) {
        int cl = idx & 7, h = idx >> 3;
        float2 z0 = in[(size_t)((0*HH + h)*WKEPT + wp)*CC + c0 + cl];
        float2 z1 = in[(size_t)((1*HH + h)*WKEPT + wp)*CC + c0 + cl];
        bufA[(2*cl+0)*128 + h] = make_float2(z0.x+z1.x, z0.y+z1.y);
        bufA[(2*cl+1)*128 + h] = make_float2(z0.x-z1.x, z0.y-z1.y);
    }
    __syncthreads();

    float2* src = bufA;
    float2* dst = bufB;
    const int t  = tid & 63;
    const int l0 = tid >> 6;
    #pragma unroll
    for (int st = 0; st < 7; ++st) {
        const int s = 1 << st;
        const int q = t & (s - 1);
        const int p = t >> st;
        const float2 w = tw[p << st];
        #pragma unroll
        for (int k = 0; k < 4; ++k) {
            int base = (l0 + 4*k) * 128;
            float2 a = src[base + q + s*p];
            float2 b = src[base + q + s*p + 64];
            float dx = a.x - b.x, dy = a.y - b.y;
            dst[base + q + 2*s*p]     = make_float2(a.x + b.x, a.y + b.y);
            dst[base + q + 2*s*p + s] = make_float2(dx*w.x - dy*w.y, dx*w.y + dy*w.x);
        }
        __syncthreads();
        float2* tmp = src; src = dst; dst = tmp;
    }
    // 7 swaps -> result in src (== bufB)
    for (int idx = tid; idx < 2048; idx += 256) {
        int cl = idx & 7;
        int hp = (idx >> 3) & 127;
        int uv = idx >> 10;
        float2 z = src[(2*cl + uv)*128 + hp];
        aout[(size_t)((uv*HH + hp)*WKEPT + wp)*CC + c0 + cl] = z.x + z.y;
    }
}

// ---------------------------------------------------------------------------
// P5 (new): H-axis FFT on REAL s via complex packing z = u + i*v.
// Per block: 16 channels, one packed line each. After FFT (Z in bufB):
//   U[k] = 0.5*(Z[k] + conj(Z[(128-k)%128]))
//   V[k] = -0.5i*(Z[k] - conj(Z[(128-k)%128]))
//     U = 0.5*(A.x+Zm.x, A.y-Zm.y);  V = 0.5*(A.y+Zm.y, Zm.x-A.x)
// out[b=0] = U, out[b=1] = V. LDS 33 KB. grid (48, 65), 256 thr.
// ---------------------------------------------------------------------------
__global__ __launch_bounds__(256) void k_hb_s2c(
    const float* __restrict__ sreal, float2* __restrict__ out)
{
    const int tid = threadIdx.x;
    const int wp = blockIdx.y;
    const int c0 = blockIdx.x * 16;
    __shared__ float2 tw[128];
    __shared__ float2 bufA[16*128];
    __shared__ float2 bufB[16*128];

    if (tid < 128) {
        float sn, cs; sincosf(TWOPI*(float)tid/128.f, &sn, &cs);
        tw[tid] = make_float2(cs, -sn);
    }
    for (int idx = tid; idx < 2048; idx += 256) {
        int cl = idx & 15, h = idx >> 4;
        float s0 = sreal[(size_t)((0*HH + h)*WKEPT + wp)*CC + c0 + cl];
        float s1 = sreal[(size_t)((1*HH + h)*WKEPT + wp)*CC + c0 + cl];
        bufA[cl*128 + h] = make_float2(s0 + s1, s0 - s1);   // z = u + i v
    }
    __syncthreads();

    float2* src = bufA;
    float2* dst = bufB;
    const int t  = tid & 63;
    const int l0 = tid >> 6;
    #pragma unroll
    for (int st = 0; st < 7; ++st) {
        const int s = 1 << st;
        const int q = t & (s - 1);
        const int p = t >> st;
        const float2 w = tw[p << st];
        #pragma unroll
        for (int k = 0; k < 4; ++k) {
            int base = (l0 + 4*k) * 128;
            float2 a = src[base + q + s*p];
            float2 b = src[base + q + s*p + 64];
            float dx = a.x - b.x, dy = a.y - b.y;
            dst[base + q + 2*s*p]     = make_float2(a.x + b.x, a.y + b.y);
            dst[base + q + 2*s*p + s] = make_float2(dx*w.x - dy*w.y, dx*w.y + dy*w.x);
        }
        __syncthreads();
        float2* tmp = src; src = dst; dst = tmp;
    }
    // result in src (== bufB); unpack U/V and write both B-rows
    for (int idx = tid; idx < 2048; idx += 256) {
        int cl = idx & 15;
        int hp = idx >> 4;
        float2 A  = src[cl*128 + hp];
        float2 Zm = src[cl*128 + ((128 - hp) & 127)];
        float2 U = make_float2(0.5f*(A.x + Zm.x), 0.5f*(A.y - Zm.y));
        float2 V = make_float2(0.5f*(A.y + Zm.y), 0.5f*(Zm.x - A.x));
        out[(size_t)((0*HH + hp)*WKEPT + wp)*CC + c0 + cl] = U;
        out[(size_t)((1*HH + hp)*WKEPT + wp)*CC + c0 + cl] = V;
    }
}

// ---------------------------------------------------------------------------
// P4 (fused): layer1 + layer2 + soft-threshold, wave-uniform scalar weights
// (unchanged from verified round-4 version).
// ---------------------------------------------------------------------------
__global__ __launch_bounds__(256, 3) void k_mlp(
    const float* __restrict__ a, const float* __restrict__ x,
    const float* __restrict__ W1P, const float* __restrict__ W1M,
    const float* __restrict__ b1,
    const float* __restrict__ WKm, const float* __restrict__ WNK,
    const float* __restrict__ BEFF, float* __restrict__ sout)
{
    const int tid = threadIdx.x;
    const int n = blockIdx.y;
    const int P0 = blockIdx.x * 64;
    __shared__ float As[96*67];   // 25.7 KB
    __shared__ float Bs[96*67];   // 25.7 KB

    for (int idx = tid; idx < 64*96; idx += 256) {
        int p = idx / 96, i = idx - p*96;
        int P = P0 + p;
        float av = a[(size_t)P*CC + n*BS + i];
        int b = P / (HH*WKEPT);
        int rem = P - b*(HH*WKEPT);
        int h = rem / WKEPT;
        int wq = rem - h*WKEPT;
        int hh2 = (HH - h) & (HH-1);
        int ww2 = (WW - wq) & (WW-1);
        float anv = x[(size_t)((b*HH + hh2)*WW + ww2)*CC + n*BS + i];
        As[i*67 + p] = av;
        Bs[i*67 + p] = anv;
    }
    __syncthreads();

    const int lane = tid & 63;
    const int wv = __builtin_amdgcn_readfirstlane(tid >> 6);  // 0..3, uniform
    const int ob = wv * 24;

    float ak[24], ank[24];
    #pragma unroll
    for (int j = 0; j < 24; ++j) { ak[j] = 0.f; ank[j] = 0.f; }

    {
        const float* wp = W1P + n*BS*BS + ob;
        const float* wm = W1M + n*BS*BS + ob;
        #pragma unroll 2
        for (int i = 0; i < 96; ++i) {
            float av = As[i*67 + lane];
            float bv = Bs[i*67 + lane];
            const float* wpr = wp + i*BS;
            const float* wmr = wm + i*BS;
            #pragma unroll
            for (int j = 0; j < 24; ++j) {
                float qp = wpr[j];
                float qm = wmr[j];
                ak [j] = fmaf(av, qp, fmaf(bv, qm, ak [j]));
                ank[j] = fmaf(bv, qp, fmaf(av, qm, ank[j]));
            }
        }
    }

    {
        const float* b1k = b1 + (0*NB + n)*BS + ob;
        const float* b1n = b1 + (1*NB + n)*BS + ob;
        float o1kv[24], o1nv[24];
        #pragma unroll
        for (int j = 0; j < 24; ++j) {
            o1kv[j] = fmaxf(ak [j] + b1k[j], 0.f);
            o1nv[j] = fmaxf(ank[j] + b1n[j], 0.f);
        }
        __syncthreads();
        #pragma unroll
        for (int j = 0; j < 24; ++j) {
            As[(ob + j)*67 + lane] = o1kv[j];
            Bs[(ob + j)*67 + lane] = o1nv[j];
        }
        __syncthreads();
    }

    float acc[24];
    #pragma unroll
    for (int j = 0; j < 24; ++j) acc[j] = 0.f;
    {
        const float* wk = WKm + n*BS*BS + ob;
        const float* wn = WNK + n*BS*BS + ob;
        #pragma unroll 2
        for (int i = 0; i < 96; ++i) {
            float kv = As[i*67 + lane];
            float nv = Bs[i*67 + lane];
            const float* wkr = wk + i*BS;
            const float* wnr = wn + i*BS;
            #pragma unroll
            for (int j = 0; j < 24; ++j) {
                acc[j] = fmaf(kv, wkr[j], fmaf(nv, wnr[j], acc[j]));
            }
        }
    }

    {
        const float* be = BEFF + n*BS + ob;
        float r[24];
        #pragma unroll
        for (int j = 0; j < 24; ++j) {
            float v = acc[j] + be[j];
            float av2 = fabsf(v) - 0.01f;
            r[j] = (av2 > 0.f) ? copysignf(av2, v) : 0.f;
        }
        __syncthreads();
        #pragma unroll
        for (int j = 0; j < 24; ++j)
            As[lane*97 + ob + j] = r[j];
        __syncthreads();
    }
    for (int idx = tid; idx < 64*96; idx += 256) {
        int p2 = idx / 96, o = idx - p2*96;
        sout[(size_t)(P0 + p2)*CC + n*BS + o] = As[p2*97 + o];
    }
}

// ---------------------------------------------------------------------------
// P7: inverse W expansion with output-pair symmetry (unchanged).
// ---------------------------------------------------------------------------
__global__ __launch_bounds__(256) void k_p7(
    const float2* __restrict__ A, const float* __restrict__ x,
    const float* __restrict__ c7t, const float* __restrict__ s7t,
    float* __restrict__ out)
{
    const int tid = threadIdx.x;
    const int ct = blockIdx.x % 3;
    const int wg = blockIdx.x / 3;        // 0..15
    const int rg = blockIdx.y;            // 0..63
    const int c  = ct*256 + tid;
    const int wpb = wg*8;
    const int row0 = rg*4;

    float accA[4][8], accB[4][8], acc128[4];
    #pragma unroll
    for (int r = 0; r < 4; ++r) {
        acc128[r] = 0.f;
        #pragma unroll
        for (int j = 0; j < 8; ++j) { accA[r][j] = 0.f; accB[r][j] = 0.f; }
    }

    const float2* A0 = A + (size_t)row0 * WKEPT * CC + c;
    const float4* cT = (const float4*)(c7t + (size_t)wg*65*8);
    const float4* sT = (const float4*)(s7t + (size_t)wg*65*8);
    for (int wq = 0; wq < 65; ++wq) {
        float4 c0 = cT[2*wq], c1 = cT[2*wq+1];
        float4 s0 = sT[2*wq], s1 = sT[2*wq+1];
        float sg = (wq & 1) ? -1.f : 1.f;
        #pragma unroll
        for (int r = 0; r < 4; ++r) {
            float2 v = A0[(size_t)(r*WKEPT + wq) * CC];
            float P = v.x + v.y;
            float M = v.y - v.x;
            float N = v.x - v.y;
            acc128[r] = fmaf(sg, P, acc128[r]);
            accA[r][0] = fmaf(P, c0.x, fmaf(M, s0.x, accA[r][0]));
            accB[r][0] = fmaf(P, c0.x, fmaf(N, s0.x, accB[r][0]));
            accA[r][1] = fmaf(P, c0.y, fmaf(M, s0.y, accA[r][1]));
            accB[r][1] = fmaf(P, c0.y, fmaf(N, s0.y, accB[r][1]));
            accA[r][2] = fmaf(P, c0.z, fmaf(M, s0.z, accA[r][2]));
            accB[r][2] = fmaf(P, c0.z, fmaf(N, s0.z, accB[r][2]));
            accA[r][3] = fmaf(P, c0.w, fmaf(M, s0.w, accA[r][3]));
            accB[r][3] = fmaf(P, c0.w, fmaf(N, s0.w, accB[r][3]));
            accA[r][4] = fmaf(P, c1.x, fmaf(M, s1.x, accA[r][4]));
            accB[r][4] = fmaf(P, c1.x, fmaf(N, s1.x, accB[r][4]));
            accA[r][5] = fmaf(P, c1.y, fmaf(M, s1.y, accA[r][5]));
            accB[r][5] = fmaf(P, c1.y, fmaf(N, s1.y, accB[r][5]));
            accA[r][6] = fmaf(P, c1.z, fmaf(M, s1.z, accA[r][6]));
            accB[r][6] = fmaf(P, c1.z, fmaf(N, s1.z, accB[r][6]));
            accA[r][7] = fmaf(P, c1.w, fmaf(M, s1.w, accA[r][7]));
            accB[r][7] = fmaf(P, c1.w, fmaf(N, s1.w, accB[r][7]));
        }
    }

    const float scale = 1.0f / 50331648.0f;
    #pragma unroll
    for (int r = 0; r < 4; ++r) {
        size_t base = (size_t)(row0 + r) * WW * CC + c;
        #pragma unroll
        for (int j = 0; j < 8; ++j) {
            int w = wpb + j;
            size_t g = base + (size_t)w*CC;
            out[g] = fmaf(accA[r][j], scale, x[g]);
            if (w != 0) {
                size_t g2 = base + (size_t)(256 - w)*CC;
                out[g2] = fmaf(accB[r][j], scale, x[g2]);
            }
        }
        if (wg == 0) {
            size_t g = base + (size_t)128*CC;
            out[g] = fmaf(acc128[r], scale, x[g]);
        }
    }
}

// ---------------------------------------------------------------------------
// P7 fallback (unchanged).
// ---------------------------------------------------------------------------
__global__ __launch_bounds__(256) void k_p7_fb(
    const float2* __restrict__ A, const float* __restrict__ x,
    float* __restrict__ out)
{
    const int tid = threadIdx.x;
    const int ct = blockIdx.x % 3;
    const int wg = blockIdx.x / 3;
    const int h = blockIdx.y, b = blockIdx.z;
    const int c = ct*256 + tid;
    __shared__ float cm[WKEPT][8];
    __shared__ float cp[WKEPT][8];
    for (int idx = tid; idx < WKEPT*8; idx += 256) {
        int wq = idx >> 3, j = idx & 7;
        int w = wg*8 + j;
        int ai = (w * wq) & 255;
        float sn, cse; sincosf(TWOPI * (float)ai / 256.f, &sn, &cse);
        cm[wq][j] = cse - sn;
        cp[wq][j] = cse + sn;
    }
    __syncthreads();
    float acc[8] = {0,0,0,0,0,0,0,0};
    const float2* Ab = A + (size_t)((b*HH + h)*WKEPT)*CC + c;
    for (int wq = 0; wq < WKEPT; ++wq) {
        float2 v = Ab[(size_t)wq*CC];
        const float4* m4 = (const float4*)(&cm[wq][0]);
        const float4* p4 = (const float4*)(&cp[wq][0]);
        #pragma unroll
        for (int jj = 0; jj < 2; ++jj) {
            float4 qm = m4[jj], qp = p4[jj];
            acc[4*jj+0] += v.x*qm.x + v.y*qp.x;
            acc[4*jj+1] += v.x*qm.y + v.y*qp.y;
            acc[4*jj+2] += v.x*qm.z + v.y*qp.z;
            acc[4*jj+3] += v.x*qm.w + v.y*qp.w;
        }
    }
    const float scale = 1.0f / 50331648.0f;
    size_t base = (size_t)(b*HH + h)*WW*CC + c;
    #pragma unroll
    for (int j = 0; j < 8; ++j) {
        int w = wg*8 + j;
        size_t g = base + (size_t)w*CC;
        out[g] = fmaf(acc[j], scale, x[g]);
    }
}

// ---------------------------------------------------------------------------
// Launch. ws layout (floats):
//   [0 : 25,559,040)   complex buffer A (16640*768 float2)
//                      first half doubles as a_real, second half as s_real
//   [25,559,040 ...)   W1P, W1M, WK, WNK (each 73728), BEFF (768)
//   then c1t, s1t (9144 each), c7t, s7t (8320 each)   — twiddle tables
// d_out doubles as complex buffer B.
// ---------------------------------------------------------------------------
extern "C" void kernel_launch(void* const* d_in, const int* in_sizes, int n_in,
                              void* d_out, int out_size, void* d_ws, size_t ws_size,
                              hipStream_t stream)
{
    (void)in_sizes; (void)n_in; (void)out_size;
    const float* x  = (const float*)d_in[0];
    const float* w1 = (const float*)d_in[1];
    const float* b1 = (const float*)d_in[2];
    const float* w2 = (const float*)d_in[3];
    const float* b2 = (const float*)d_in[4];

    float*  ws     = (float*)d_ws;
    float2* Abuf   = (float2*)d_ws;
    float*  a_real = ws;
    float*  s_real = ws + (size_t)NPTS*CC;
    float*  W1P    = ws + 2*(size_t)NPTS*CC;
    float*  W1M    = W1P + NB*BS*BS;
    float*  WKm    = W1M + NB*BS*BS;
    float*  WNK    = WKm + NB*BS*BS;
    float*  BEFF   = WNK + NB*BS*BS;
    float*  c1t    = BEFF + NB*BS;
    float*  s1t    = c1t + P1_TW;
    float*  c7t    = s1t + P1_TW;
    float*  s7t    = c7t + P7_TW;

    const size_t need_bytes =
        ((size_t)2*NPTS*CC + 4*(size_t)NB*BS*BS + NB*BS + 2*P1_TW + 2*P7_TW)
        * sizeof(float);
    const bool fast = (ws_size >= need_bytes);

    float2* Bc   = (float2*)d_out;
    float*  outf = (float*)d_out;

    k_weights<<<dim3(NB), dim3(256), 0, stream>>>(w1, w2, b2, W1P, W1M, WKm, WNK, BEFF);
    if (fast) {
        k_tw<<<dim3(36), dim3(256), 0, stream>>>(c1t, s1t, c7t, s7t);
        k_p1<<<dim3(27, 64), dim3(256), 0, stream>>>(x, c1t, s1t, Abuf);
    } else {
        k_p1_fb<<<dim3(27, HH, BB), dim3(256), 0, stream>>>(x, Abuf);
    }
    k_cfft   <<<dim3(NPTS/LPB), dim3(256), 0, stream>>>(Abuf, Bc);
    k_hb_c2a <<<dim3(96, WKEPT), dim3(256), 0, stream>>>(Bc, a_real);
    k_mlp    <<<dim3(260, NB), dim3(256), 0, stream>>>(a_real, x, W1P, W1M, b1,
                                                       WKm, WNK, BEFF, s_real);
    k_hb_s2c <<<dim3(48, WKEPT), dim3(256), 0, stream>>>(s_real, Bc);
    k_cfft   <<<dim3(NPTS/LPB), dim3(256), 0, stream>>>(Bc, Abuf);
    if (fast) {
        k_p7<<<dim3(48, 64), dim3(256), 0, stream>>>(Abuf, x, c7t, s7t, outf);
    } else {
        k_p7_fb<<<dim3(96, HH, BB), dim3(256), 0, stream>>>(Abuf, x, outf);
    }
}

// Round 6
// 1342.546 us; speedup vs baseline: 1.8002x; 1.0548x over previous
//
#include <hip/hip_runtime.h>

#define BB 2
#define HH 128
#define WW 256
#define CC 768
#define NB 8
#define BS 96
#define WKEPT 65
#define NPTS (BB*HH*WKEPT)        // 16640 kept (b,h,w') points
#define NTOT ((size_t)BB*HH*WW*CC) // 50331648
#define TWOPI 6.283185307179586f

#define P1_TW (9*127*8)           // 9144 entries (cos + sin tables)
#define P7_TW (16*65*8)           // 8320 entries

__device__ __forceinline__ unsigned short f2bf(float f) {
    unsigned int u = __float_as_uint(f);
    u += 0x7fffu + ((u >> 16) & 1u);      // round-to-nearest-even
    return (unsigned short)(u >> 16);
}
__device__ __forceinline__ float bf2f(unsigned short s) {
    return __uint_as_float((unsigned int)s << 16);
}

// ---------------------------------------------------------------------------
// K0: precombine layer-2 weights only.
//   WK  = p + p@m ; WNK = p + m + m@m   (p=(w2a+w2b)/2, m=(w2a-w2b)/2)
//   WKP = (WK+WNK)/2 ; WKM = (WK-WNK)/2   (for the p2/m2 form)
//   BEFF= b2[0]+b2[1]+b2[0]@m
// Layer-1 now uses raw w1 directly (U/V trick) — no W1P/W1M.
// ---------------------------------------------------------------------------
__global__ __launch_bounds__(256) void k_weights(
    const float* __restrict__ w2, const float* __restrict__ b2,
    float* __restrict__ WKP, float* __restrict__ WKM, float* __restrict__ BEFF)
{
    const int n = blockIdx.x;
    const int tid = threadIdx.x;
    __shared__ float m_s[BS*BS];

    const float* w2a = w2 + (size_t)(0*NB + n)*BS*BS;
    const float* w2b = w2 + (size_t)(1*NB + n)*BS*BS;
    for (int idx = tid; idx < BS*BS; idx += 256)
        m_s[idx] = 0.5f*(w2a[idx] - w2b[idx]);
    __syncthreads();

    for (int idx = tid; idx < BS*BS; idx += 256) {
        int i = idx / BS, o = idx - i*BS;
        float p_io = 0.5f*(w2a[idx] + w2b[idx]);
        float m_io = m_s[idx];
        float accK = 0.f, accN = 0.f;
        for (int j = 0; j < BS; ++j) {
            float p_ij = 0.5f*(w2a[i*BS + j] + w2b[i*BS + j]);
            float mjo  = m_s[j*BS + o];
            accK += p_ij * mjo;
            accN += m_s[i*BS + j] * mjo;
        }
        float valK = p_io + accK;
        float valN = p_io + m_io + accN;
        WKP[n*BS*BS + idx] = 0.5f*(valK + valN);
        WKM[n*BS*BS + idx] = 0.5f*(valK - valN);
    }
    if (tid < BS) {
        const float* b2a = b2 + (0*NB + n)*BS;
        const float* b2b = b2 + (1*NB + n)*BS;
        float acc = b2a[tid] + b2b[tid];
        for (int j = 0; j < BS; ++j) acc += b2a[j] * m_s[j*BS + tid];
        BEFF[n*BS + tid] = acc;
    }
}

// ---------------------------------------------------------------------------
// K-tw: twiddle tables in GLOBAL memory (unchanged).
// ---------------------------------------------------------------------------
__global__ __launch_bounds__(256) void k_tw(
    float* __restrict__ c1t, float* __restrict__ s1t,
    float* __restrict__ c7t, float* __restrict__ s7t)
{
    int idx = blockIdx.x*256 + threadIdx.x;
    if (idx < P1_TW) {
        int j = idx & 7; int rest = idx >> 3;
        int w = rest % 127 + 1; int wg = rest / 127;
        int ai = (w * (wg*8 + j)) & 255;
        float sn, cs; sincosf(TWOPI * (float)ai / 256.0f, &sn, &cs);
        c1t[idx] = cs; s1t[idx] = sn;
    }
    if (idx < P7_TW) {
        int j = idx & 7; int rest = idx >> 3;
        int wq = rest % 65; int wg = rest / 65;
        int ai = ((wg*8 + j) * wq) & 255;
        float sn, cs; sincosf(TWOPI * (float)ai / 256.0f, &sn, &cs);
        c7t[idx] = cs; s7t[idx] = sn;
    }
}

// ---------------------------------------------------------------------------
// P1: forward W-axis pruned DFT, folded pairs, global twiddles (unchanged).
// ---------------------------------------------------------------------------
__global__ __launch_bounds__(256) void k_p1(
    const float* __restrict__ x, const float* __restrict__ c1t,
    const float* __restrict__ s1t, float2* __restrict__ out)
{
    const int tid = threadIdx.x;
    const int ct = blockIdx.x % 3;
    const int wg = blockIdx.x / 3;        // 0..8
    const int rg = blockIdx.y;            // 0..63, row = b*HH+h
    const int c  = ct*256 + tid;
    const int wpb = wg*8;
    const int row0 = rg*4;

    float re[4][8], im[4][8];
    const float* xr0 = x + (size_t)row0 * WW * CC + c;

    #pragma unroll
    for (int r = 0; r < 4; ++r) {
        const float* xr = xr0 + (size_t)r * WW * CC;
        float x0v   = xr[0];
        float x128v = xr[(size_t)128*CC];
        #pragma unroll
        for (int j = 0; j < 8; ++j) {
            re[r][j] = (((wpb + j) & 1) ? (x0v - x128v) : (x0v + x128v));
            im[r][j] = 0.f;
        }
    }

    const float4* cT = (const float4*)(c1t + (size_t)wg*127*8);
    const float4* sT = (const float4*)(s1t + (size_t)wg*127*8);
    for (int w = 1; w <= 127; ++w) {
        float4 c0 = cT[2*(w-1)], c1 = cT[2*(w-1)+1];
        float4 s0 = sT[2*(w-1)], s1 = sT[2*(w-1)+1];
        #pragma unroll
        for (int r = 0; r < 4; ++r) {
            const float* xr = xr0 + (size_t)r * WW * CC;
            float a = xr[(size_t)w*CC];
            float b = xr[(size_t)(256-w)*CC];
            float u = a + b, d = a - b;
            re[r][0] = fmaf(u, c0.x, re[r][0]);  im[r][0] = fmaf(-d, s0.x, im[r][0]);
            re[r][1] = fmaf(u, c0.y, re[r][1]);  im[r][1] = fmaf(-d, s0.y, im[r][1]);
            re[r][2] = fmaf(u, c0.z, re[r][2]);  im[r][2] = fmaf(-d, s0.z, im[r][2]);
            re[r][3] = fmaf(u, c0.w, re[r][3]);  im[r][3] = fmaf(-d, s0.w, im[r][3]);
            re[r][4] = fmaf(u, c1.x, re[r][4]);  im[r][4] = fmaf(-d, s1.x, im[r][4]);
            re[r][5] = fmaf(u, c1.y, re[r][5]);  im[r][5] = fmaf(-d, s1.y, im[r][5]);
            re[r][6] = fmaf(u, c1.z, re[r][6]);  im[r][6] = fmaf(-d, s1.z, im[r][6]);
            re[r][7] = fmaf(u, c1.w, re[r][7]);  im[r][7] = fmaf(-d, s1.w, im[r][7]);
        }
    }

    #pragma unroll
    for (int r = 0; r < 4; ++r) {
        #pragma unroll
        for (int j = 0; j < 8; ++j) {
            int wp = wpb + j;
            if (wp < WKEPT)
                out[(size_t)((row0 + r)*WKEPT + wp) * CC + c] = make_float2(re[r][j], im[r][j]);
        }
    }
}

// ---------------------------------------------------------------------------
// P1 fallback (LDS twiddles) — only if ws lacks table headroom.
// ---------------------------------------------------------------------------
__global__ __launch_bounds__(256) void k_p1_fb(
    const float* __restrict__ x, float2* __restrict__ out)
{
    const int tid = threadIdx.x;
    const int ct = blockIdx.x % 3;
    const int wg = blockIdx.x / 3;
    const int h = blockIdx.y, b = blockIdx.z;
    const int c = ct*256 + tid;
    const int wpb = wg*8;

    __shared__ float2 tw[256][8];
    for (int idx = tid; idx < 2048; idx += 256) {
        int w = idx >> 3, j = idx & 7;
        int ai = (w * (wpb + j)) & 255;
        float sn, cs; sincosf(TWOPI * (float)ai / 256.0f, &sn, &cs);
        tw[w][j] = make_float2(cs, sn);
    }
    __syncthreads();

    float re[8] = {0,0,0,0,0,0,0,0}, im[8] = {0,0,0,0,0,0,0,0};
    const float* xrow = x + (size_t)(b*HH + h) * WW * CC + c;
    for (int w = 0; w < 256; ++w) {
        float xv = xrow[(size_t)w * CC];
        const float4* t4 = (const float4*)(&tw[w][0]);
        #pragma unroll
        for (int jj = 0; jj < 4; ++jj) {
            float4 q = t4[jj];
            re[2*jj]   += xv * q.x;  im[2*jj]   -= xv * q.y;
            re[2*jj+1] += xv * q.z;  im[2*jj+1] -= xv * q.w;
        }
    }
    #pragma unroll
    for (int j = 0; j < 8; ++j) {
        int wp = wpb + j;
        if (wp < WKEPT)
            out[(size_t)((b*HH + h)*WKEPT + wp) * CC + c] = make_float2(re[j], im[j]);
    }
}

// ---------------------------------------------------------------------------
// P2/P6: C-axis 768-pt FFT per line (unchanged).
// ---------------------------------------------------------------------------
#define LPB 4
__global__ __launch_bounds__(256) void k_cfft(
    const float2* __restrict__ in, float2* __restrict__ out)
{
    __shared__ float2 tw[CC];
    __shared__ float2 bufA[LPB*CC];
    __shared__ float2 bufB[LPB*CC];
    const int tid = threadIdx.x;
    const size_t line0 = (size_t)blockIdx.x * LPB;

    for (int t = tid; t < CC; t += 256) {
        float sn, cs; sincosf(TWOPI * (float)t / 768.0f, &sn, &cs);
        tw[t] = make_float2(cs, -sn);
    }
    for (int idx = tid; idx < LPB*CC; idx += 256) {
        int l = idx / CC, c = idx - l*CC;
        int m = c / 3, j = c - 3*m;
        bufA[l*CC + j*256 + m] = in[(line0 + l)*CC + c];
    }
    __syncthreads();

    float2* src = bufA;
    float2* dst = bufB;
    #pragma unroll
    for (int st = 0; st < 8; ++st) {
        const int s = 1 << st;
        const int h = 128 >> st;
        for (int item = tid; item < LPB*3*128; item += 256) {
            int sub = item >> 7;
            int t   = item & 127;
            int q = t & (s - 1);
            int p = t >> st;
            float2 a = src[sub*256 + q + s*p];
            float2 b = src[sub*256 + q + s*(p + h)];
            float2 w = tw[p * (3 << st)];
            float dx = a.x - b.x, dy = a.y - b.y;
            dst[sub*256 + q + s*(2*p)]     = make_float2(a.x + b.x, a.y + b.y);
            dst[sub*256 + q + s*(2*p + 1)] = make_float2(dx*w.x - dy*w.y, dx*w.y + dy*w.x);
        }
        __syncthreads();
        float2* tmp = src; src = dst; dst = tmp;
    }
    for (int idx = tid; idx < LPB*CC; idx += 256) {
        int l = idx / CC, cp = idx - l*CC;
        int r = cp & 255;
        float2 S0 = src[(l*3 + 0)*256 + r];
        float2 S1 = src[(l*3 + 1)*256 + r];
        float2 S2 = src[(l*3 + 2)*256 + r];
        float2 w1 = tw[cp];
        int i2 = 2*cp; if (i2 >= CC) i2 -= CC;
        float2 w2 = tw[i2];
        float fr = S0.x + w1.x*S1.x - w1.y*S1.y + w2.x*S2.x - w2.y*S2.y;
        float fi = S0.y + w1.x*S1.y + w1.y*S1.x + w2.x*S2.y + w2.y*S2.x;
        out[(line0 + l)*CC + cp] = make_float2(fr, fi);
    }
}

// ---------------------------------------------------------------------------
// P3: H-axis via 128-pt radix-2 Stockham FFT (unchanged from round 5).
// ---------------------------------------------------------------------------
__global__ __launch_bounds__(256) void k_hb_c2a(
    const float2* __restrict__ in, float* __restrict__ aout)
{
    const int tid = threadIdx.x;
    const int wp = blockIdx.y;
    const int c0 = blockIdx.x * 8;
    __shared__ float2 tw[128];        // e^{-2pi i t/128}
    __shared__ float2 bufA[16*128];   // 16 KB
    __shared__ float2 bufB[16*128];   // 16 KB

    if (tid < 128) {
        float sn, cs; sincosf(TWOPI*(float)tid/128.f, &sn, &cs);
        tw[tid] = make_float2(cs, -sn);
    }
    for (int idx = tid; idx < 1024; idx += 256) {
        int cl = idx & 7, h = idx >> 3;
        float2 z0 = in[(size_t)((0*HH + h)*WKEPT + wp)*CC + c0 + cl];
        float2 z1 = in[(size_t)((1*HH + h)*WKEPT + wp)*CC + c0 + cl];
        bufA[(2*cl+0)*128 + h] = make_float2(z0.x+z1.x, z0.y+z1.y);
        bufA[(2*cl+1)*128 + h] = make_float2(z0.x-z1.x, z0.y-z1.y);
    }
    __syncthreads();

    float2* src = bufA;
    float2* dst = bufB;
    const int t  = tid & 63;
    const int l0 = tid >> 6;
    #pragma unroll
    for (int st = 0; st < 7; ++st) {
        const int s = 1 << st;
        const int q = t & (s - 1);
        const int p = t >> st;
        const float2 w = tw[p << st];
        #pragma unroll
        for (int k = 0; k < 4; ++k) {
            int base = (l0 + 4*k) * 128;
            float2 a = src[base + q + s*p];
            float2 b = src[base + q + s*p + 64];
            float dx = a.x - b.x, dy = a.y - b.y;
            dst[base + q + 2*s*p]     = make_float2(a.x + b.x, a.y + b.y);
            dst[base + q + 2*s*p + s] = make_float2(dx*w.x - dy*w.y, dx*w.y + dy*w.x);
        }
        __syncthreads();
        float2* tmp = src; src = dst; dst = tmp;
    }
    for (int idx = tid; idx < 2048; idx += 256) {
        int cl = idx & 7;
        int hp = (idx >> 3) & 127;
        int uv = idx >> 10;
        float2 z = src[(2*cl + uv)*128 + hp];
        aout[(size_t)((uv*HH + hp)*WKEPT + wp)*CC + c0 + cl] = z.x + z.y;
    }
}

// ---------------------------------------------------------------------------
// P5: H-axis FFT on REAL s via complex packing (unchanged from round 5).
// ---------------------------------------------------------------------------
__global__ __launch_bounds__(256) void k_hb_s2c(
    const float* __restrict__ sreal, float2* __restrict__ out)
{
    const int tid = threadIdx.x;
    const int wp = blockIdx.y;
    const int c0 = blockIdx.x * 16;
    __shared__ float2 tw[128];
    __shared__ float2 bufA[16*128];
    __shared__ float2 bufB[16*128];

    if (tid < 128) {
        float sn, cs; sincosf(TWOPI*(float)tid/128.f, &sn, &cs);
        tw[tid] = make_float2(cs, -sn);
    }
    for (int idx = tid; idx < 2048; idx += 256) {
        int cl = idx & 15, h = idx >> 4;
        float s0 = sreal[(size_t)((0*HH + h)*WKEPT + wp)*CC + c0 + cl];
        float s1 = sreal[(size_t)((1*HH + h)*WKEPT + wp)*CC + c0 + cl];
        bufA[cl*128 + h] = make_float2(s0 + s1, s0 - s1);   // z = u + i v
    }
    __syncthreads();

    float2* src = bufA;
    float2* dst = bufB;
    const int t  = tid & 63;
    const int l0 = tid >> 6;
    #pragma unroll
    for (int st = 0; st < 7; ++st) {
        const int s = 1 << st;
        const int q = t & (s - 1);
        const int p = t >> st;
        const float2 w = tw[p << st];
        #pragma unroll
        for (int k = 0; k < 4; ++k) {
            int base = (l0 + 4*k) * 128;
            float2 a = src[base + q + s*p];
            float2 b = src[base + q + s*p + 64];
            float dx = a.x - b.x, dy = a.y - b.y;
            dst[base + q + 2*s*p]     = make_float2(a.x + b.x, a.y + b.y);
            dst[base + q + 2*s*p + s] = make_float2(dx*w.x - dy*w.y, dx*w.y + dy*w.x);
        }
        __syncthreads();
        float2* tmp = src; src = dst; dst = tmp;
    }
    for (int idx = tid; idx < 2048; idx += 256) {
        int cl = idx & 15;
        int hp = idx >> 4;
        float2 A  = src[cl*128 + hp];
        float2 Zm = src[cl*128 + ((128 - hp) & 127)];
        float2 U = make_float2(0.5f*(A.x + Zm.x), 0.5f*(A.y - Zm.y));
        float2 V = make_float2(0.5f*(A.y + Zm.y), 0.5f*(Zm.x - A.x));
        out[(size_t)((0*HH + hp)*WKEPT + wp)*CC + c0 + cl] = U;
        out[(size_t)((1*HH + hp)*WKEPT + wp)*CC + c0 + cl] = V;
    }
}

// ---------------------------------------------------------------------------
// P4 (fused, v3): U/V-form layer1 + p2/m2-form layer2 + soft-threshold.
//   U=(a+an)/2, V=(a-an)/2 staged in LDS as BF16 ->
//     t1 = U@w1[0], t2 = V@w1[1];  o1k = relu(t1+t2+b1k), o1nk = relu(t1-t2+b1n)
//   p2=o1k+o1nk, m2=o1k-o1nk (bf16 restage) -> s = p2@WKP + m2@WKM + BEFF
// Halves layer-1 FMAs; bf16 staging halves LDS (25.1 KB) -> 6 blocks/CU,
// 24 waves (75% occupancy) to hide the scalar weight-load latency.
// Weights stay wave-uniform (lane=point, wave=24-output slice) -> s_load path.
// grid (260, 8), 256 thr.
// ---------------------------------------------------------------------------
__global__ __launch_bounds__(256, 6) void k_mlp(
    const float* __restrict__ a, const float* __restrict__ x,
    const float* __restrict__ w1, const float* __restrict__ b1,
    const float* __restrict__ WKP, const float* __restrict__ WKM,
    const float* __restrict__ BEFF, float* __restrict__ sout)
{
    const int tid = threadIdx.x;
    const int n = blockIdx.y;
    const int P0 = blockIdx.x * 64;
    __shared__ unsigned short SH[2*96*67];     // 25.1 KB total
    unsigned short* As = SH;                   // U, later p2  (bf16)
    unsigned short* Bs = SH + 96*67;           // V, later m2  (bf16)

    // stage U/V transposed: As[i][p] = bf16(0.5*(a+an)), Bs = bf16(0.5*(a-an))
    for (int idx = tid; idx < 64*96; idx += 256) {
        int p = idx / 96, i = idx - p*96;
        int P = P0 + p;
        float av = a[(size_t)P*CC + n*BS + i];
        int b = P / (HH*WKEPT);
        int rem = P - b*(HH*WKEPT);
        int h = rem / WKEPT;
        int wq = rem - h*WKEPT;
        int hh2 = (HH - h) & (HH-1);
        int ww2 = (WW - wq) & (WW-1);
        float anv = x[(size_t)((b*HH + hh2)*WW + ww2)*CC + n*BS + i];
        As[i*67 + p] = f2bf(0.5f*(av + anv));
        Bs[i*67 + p] = f2bf(0.5f*(av - anv));
    }
    __syncthreads();

    const int lane = tid & 63;
    const int wv = __builtin_amdgcn_readfirstlane(tid >> 6);  // 0..3, uniform
    const int ob = wv * 24;

    // ---- layer 1: t1 = U@w1[0], t2 = V@w1[1] ----
    float t1[24], t2[24];
    #pragma unroll
    for (int j = 0; j < 24; ++j) { t1[j] = 0.f; t2[j] = 0.f; }
    {
        const float* w10 = w1 + (size_t)(0*NB + n)*BS*BS + ob;
        const float* w11 = w1 + (size_t)(1*NB + n)*BS*BS + ob;
        #pragma unroll 2
        for (int i = 0; i < 96; ++i) {
            float Uv = bf2f(As[i*67 + lane]);
            float Vv = bf2f(Bs[i*67 + lane]);
            const float* r0 = w10 + i*BS;
            const float* r1 = w11 + i*BS;
            #pragma unroll
            for (int j = 0; j < 24; ++j) {
                t1[j] = fmaf(Uv, r0[j], t1[j]);
                t2[j] = fmaf(Vv, r1[j], t2[j]);
            }
        }
    }

    // bias + relu -> p2/m2, restage (bf16)
    {
        const float* b1k = b1 + (0*NB + n)*BS + ob;
        const float* b1n = b1 + (1*NB + n)*BS + ob;
        float p2v[24], m2v[24];
        #pragma unroll
        for (int j = 0; j < 24; ++j) {
            float ok = fmaxf(t1[j] + t2[j] + b1k[j], 0.f);
            float on = fmaxf(t1[j] - t2[j] + b1n[j], 0.f);
            p2v[j] = ok + on;
            m2v[j] = ok - on;
        }
        __syncthreads();   // everyone done reading U/V
        #pragma unroll
        for (int j = 0; j < 24; ++j) {
            As[(ob + j)*67 + lane] = f2bf(p2v[j]);
            Bs[(ob + j)*67 + lane] = f2bf(m2v[j]);
        }
        __syncthreads();
    }

    // ---- layer 2: s = p2@WKP + m2@WKM + BEFF ----
    float acc[24];
    #pragma unroll
    for (int j = 0; j < 24; ++j) acc[j] = 0.f;
    {
        const float* wkp = WKP + n*BS*BS + ob;
        const float* wkm = WKM + n*BS*BS + ob;
        #pragma unroll 2
        for (int i = 0; i < 96; ++i) {
            float pv = bf2f(As[i*67 + lane]);
            float mv = bf2f(Bs[i*67 + lane]);
            const float* rk = wkp + i*BS;
            const float* rm = wkm + i*BS;
            #pragma unroll
            for (int j = 0; j < 24; ++j) {
                acc[j] = fmaf(pv, rk[j], fmaf(mv, rm[j], acc[j]));
            }
        }
    }

    // soft-threshold, stage as fp32 through SH (reinterpreted) for coalesced stores
    {
        const float* be = BEFF + n*BS + ob;
        float r[24];
        #pragma unroll
        for (int j = 0; j < 24; ++j) {
            float v = acc[j] + be[j];
            float av2 = fabsf(v) - 0.01f;
            r[j] = (av2 > 0.f) ? copysignf(av2, v) : 0.f;
        }
        __syncthreads();   // done reading p2/m2
        float* Fs = (float*)SH;            // need 64*97 = 6208 floats <= 6432
        #pragma unroll
        for (int j = 0; j < 24; ++j)
            Fs[lane*97 + ob + j] = r[j];
        __syncthreads();
        for (int idx = tid; idx < 64*96; idx += 256) {
            int p2i = idx / 96, o = idx - p2i*96;
            sout[(size_t)(P0 + p2i)*CC + n*BS + o] = Fs[p2i*97 + o];
        }
    }
}

// ---------------------------------------------------------------------------
// P7: inverse W expansion with output-pair symmetry (unchanged).
// ---------------------------------------------------------------------------
__global__ __launch_bounds__(256) void k_p7(
    const float2* __restrict__ A, const float* __restrict__ x,
    const float* __restrict__ c7t, const float* __restrict__ s7t,
    float* __restrict__ out)
{
    const int tid = threadIdx.x;
    const int ct = blockIdx.x % 3;
    const int wg = blockIdx.x / 3;        // 0..15
    const int rg = blockIdx.y;            // 0..63
    const int c  = ct*256 + tid;
    const int wpb = wg*8;
    const int row0 = rg*4;

    float accA[4][8], accB[4][8], acc128[4];
    #pragma unroll
    for (int r = 0; r < 4; ++r) {
        acc128[r] = 0.f;
        #pragma unroll
        for (int j = 0; j < 8; ++j) { accA[r][j] = 0.f; accB[r][j] = 0.f; }
    }

    const float2* A0 = A + (size_t)row0 * WKEPT * CC + c;
    const float4* cT = (const float4*)(c7t + (size_t)wg*65*8);
    const float4* sT = (const float4*)(s7t + (size_t)wg*65*8);
    for (int wq = 0; wq < 65; ++wq) {
        float4 c0 = cT[2*wq], c1 = cT[2*wq+1];
        float4 s0 = sT[2*wq], s1 = sT[2*wq+1];
        float sg = (wq & 1) ? -1.f : 1.f;
        #pragma unroll
        for (int r = 0; r < 4; ++r) {
            float2 v = A0[(size_t)(r*WKEPT + wq) * CC];
            float P = v.x + v.y;
            float M = v.y - v.x;
            float N = v.x - v.y;
            acc128[r] = fmaf(sg, P, acc128[r]);
            accA[r][0] = fmaf(P, c0.x, fmaf(M, s0.x, accA[r][0]));
            accB[r][0] = fmaf(P, c0.x, fmaf(N, s0.x, accB[r][0]));
            accA[r][1] = fmaf(P, c0.y, fmaf(M, s0.y, accA[r][1]));
            accB[r][1] = fmaf(P, c0.y, fmaf(N, s0.y, accB[r][1]));
            accA[r][2] = fmaf(P, c0.z, fmaf(M, s0.z, accA[r][2]));
            accB[r][2] = fmaf(P, c0.z, fmaf(N, s0.z, accB[r][2]));
            accA[r][3] = fmaf(P, c0.w, fmaf(M, s0.w, accA[r][3]));
            accB[r][3] = fmaf(P, c0.w, fmaf(N, s0.w, accB[r][3]));
            accA[r][4] = fmaf(P, c1.x, fmaf(M, s1.x, accA[r][4]));
            accB[r][4] = fmaf(P, c1.x, fmaf(N, s1.x, accB[r][4]));
            accA[r][5] = fmaf(P, c1.y, fmaf(M, s1.y, accA[r][5]));
            accB[r][5] = fmaf(P, c1.y, fmaf(N, s1.y, accB[r][5]));
            accA[r][6] = fmaf(P, c1.z, fmaf(M, s1.z, accA[r][6]));
            accB[r][6] = fmaf(P, c1.z, fmaf(N, s1.z, accB[r][6]));
            accA[r][7] = fmaf(P, c1.w, fmaf(M, s1.w, accA[r][7]));
            accB[r][7] = fmaf(P, c1.w, fmaf(N, s1.w, accB[r][7]));
        }
    }

    const float scale = 1.0f / 50331648.0f;
    #pragma unroll
    for (int r = 0; r < 4; ++r) {
        size_t base = (size_t)(row0 + r) * WW * CC + c;
        #pragma unroll
        for (int j = 0; j < 8; ++j) {
            int w = wpb + j;
            size_t g = base + (size_t)w*CC;
            out[g] = fmaf(accA[r][j], scale, x[g]);
            if (w != 0) {
                size_t g2 = base + (size_t)(256 - w)*CC;
                out[g2] = fmaf(accB[r][j], scale, x[g2]);
            }
        }
        if (wg == 0) {
            size_t g = base + (size_t)128*CC;
            out[g] = fmaf(acc128[r], scale, x[g]);
        }
    }
}

// ---------------------------------------------------------------------------
// P7 fallback (unchanged).
// ---------------------------------------------------------------------------
__global__ __launch_bounds__(256) void k_p7_fb(
    const float2* __restrict__ A, const float* __restrict__ x,
    float* __restrict__ out)
{
    const int tid = threadIdx.x;
    const int ct = blockIdx.x % 3;
    const int wg = blockIdx.x / 3;
    const int h = blockIdx.y, b = blockIdx.z;
    const int c = ct*256 + tid;
    __shared__ float cm[WKEPT][8];
    __shared__ float cp[WKEPT][8];
    for (int idx = tid; idx < WKEPT*8; idx += 256) {
        int wq = idx >> 3, j = idx & 7;
        int w = wg*8 + j;
        int ai = (w * wq) & 255;
        float sn, cse; sincosf(TWOPI * (float)ai / 256.f, &sn, &cse);
        cm[wq][j] = cse - sn;
        cp[wq][j] = cse + sn;
    }
    __syncthreads();
    float acc[8] = {0,0,0,0,0,0,0,0};
    const float2* Ab = A + (size_t)((b*HH + h)*WKEPT)*CC + c;
    for (int wq = 0; wq < WKEPT; ++wq) {
        float2 v = Ab[(size_t)wq*CC];
        const float4* m4 = (const float4*)(&cm[wq][0]);
        const float4* p4 = (const float4*)(&cp[wq][0]);
        #pragma unroll
        for (int jj = 0; jj < 2; ++jj) {
            float4 qm = m4[jj], qp = p4[jj];
            acc[4*jj+0] += v.x*qm.x + v.y*qp.x;
            acc[4*jj+1] += v.x*qm.y + v.y*qp.y;
            acc[4*jj+2] += v.x*qm.z + v.y*qp.z;
            acc[4*jj+3] += v.x*qm.w + v.y*qp.w;
        }
    }
    const float scale = 1.0f / 50331648.0f;
    size_t base = (size_t)(b*HH + h)*WW*CC + c;
    #pragma unroll
    for (int j = 0; j < 8; ++j) {
        int w = wg*8 + j;
        size_t g = base + (size_t)w*CC;
        out[g] = fmaf(acc[j], scale, x[g]);
    }
}

// ---------------------------------------------------------------------------
// Launch. ws layout (floats):
//   [0 : 25,559,040)   complex buffer A (16640*768 float2)
//                      first half doubles as a_real, second half as s_real
//   [25,559,040 ...)   W1P(unused), W1M(unused), WKP, WKM (each 73728),
//                      BEFF (768), then c1t/s1t/c7t/s7t twiddle tables
// d_out doubles as complex buffer B.
// ---------------------------------------------------------------------------
extern "C" void kernel_launch(void* const* d_in, const int* in_sizes, int n_in,
                              void* d_out, int out_size, void* d_ws, size_t ws_size,
                              hipStream_t stream)
{
    (void)in_sizes; (void)n_in; (void)out_size;
    const float* x  = (const float*)d_in[0];
    const float* w1 = (const float*)d_in[1];
    const float* b1 = (const float*)d_in[2];
    const float* w2 = (const float*)d_in[3];
    const float* b2 = (const float*)d_in[4];

    float*  ws     = (float*)d_ws;
    float2* Abuf   = (float2*)d_ws;
    float*  a_real = ws;
    float*  s_real = ws + (size_t)NPTS*CC;
    float*  W1P    = ws + 2*(size_t)NPTS*CC;   // unused (layout keeps offsets)
    float*  W1M    = W1P + NB*BS*BS;           // unused
    float*  WKP    = W1M + NB*BS*BS;
    float*  WKM    = WKP + NB*BS*BS;
    float*  BEFF   = WKM + NB*BS*BS;
    float*  c1t    = BEFF + NB*BS;
    float*  s1t    = c1t + P1_TW;
    float*  c7t    = s1t + P1_TW;
    float*  s7t    = c7t + P7_TW;

    const size_t need_bytes =
        ((size_t)2*NPTS*CC + 4*(size_t)NB*BS*BS + NB*BS + 2*P1_TW + 2*P7_TW)
        * sizeof(float);
    const bool fast = (ws_size >= need_bytes);

    float2* Bc   = (float2*)d_out;
    float*  outf = (float*)d_out;

    k_weights<<<dim3(NB), dim3(256), 0, stream>>>(w2, b2, WKP, WKM, BEFF);
    if (fast) {
        k_tw<<<dim3(36), dim3(256), 0, stream>>>(c1t, s1t, c7t, s7t);
        k_p1<<<dim3(27, 64), dim3(256), 0, stream>>>(x, c1t, s1t, Abuf);
    } else {
        k_p1_fb<<<dim3(27, HH, BB), dim3(256), 0, stream>>>(x, Abuf);
    }
    k_cfft   <<<dim3(NPTS/LPB), dim3(256), 0, stream>>>(Abuf, Bc);
    k_hb_c2a <<<dim3(96, WKEPT), dim3(256), 0, stream>>>(Bc, a_real);
    k_mlp    <<<dim3(260, NB), dim3(256), 0, stream>>>(a_real, x, w1, b1,
                                                       WKP, WKM, BEFF, s_real);
    k_hb_s2c <<<dim3(48, WKEPT), dim3(256), 0, stream>>>(s_real, Bc);
    k_cfft   <<<dim3(NPTS/LPB), dim3(256), 0, stream>>>(Bc, Abuf);
    if (fast) {
        k_p7<<<dim3(48, 64), dim3(256), 0, stream>>>(Abuf, x, c7t, s7t, outf);
    } else {
        k_p7_fb<<<dim3(96, HH, BB), dim3(256), 0, stream>>>(Abuf, x, outf);
    }
}

// Round 7
// 1187.374 us; speedup vs baseline: 2.0354x; 1.1307x over previous
//
#include <hip/hip_runtime.h>

#define BB 2
#define HH 128
#define WW 256
#define CC 768
#define NB 8
#define BS 96
#define WKEPT 65
#define NPTS (BB*HH*WKEPT)        // 16640 kept (b,h,w') points
#define NTOT ((size_t)BB*HH*WW*CC) // 50331648
#define TWOPI 6.283185307179586f

#define P1_TW (9*127*8)           // 9144 entries (legacy layout, unused)
#define P7_TW (16*65*8)           // 8320 entries

__device__ __forceinline__ unsigned short f2bf(float f) {
    unsigned int u = __float_as_uint(f);
    u += 0x7fffu + ((u >> 16) & 1u);      // round-to-nearest-even
    return (unsigned short)(u >> 16);
}
__device__ __forceinline__ float bf2f(unsigned short s) {
    return __uint_as_float((unsigned int)s << 16);
}

// ---------------------------------------------------------------------------
// K0: precombine layer-2 weights (unchanged from round 6).
// ---------------------------------------------------------------------------
__global__ __launch_bounds__(256) void k_weights(
    const float* __restrict__ w2, const float* __restrict__ b2,
    float* __restrict__ WKP, float* __restrict__ WKM, float* __restrict__ BEFF)
{
    const int n = blockIdx.x;
    const int tid = threadIdx.x;
    __shared__ float m_s[BS*BS];

    const float* w2a = w2 + (size_t)(0*NB + n)*BS*BS;
    const float* w2b = w2 + (size_t)(1*NB + n)*BS*BS;
    for (int idx = tid; idx < BS*BS; idx += 256)
        m_s[idx] = 0.5f*(w2a[idx] - w2b[idx]);
    __syncthreads();

    for (int idx = tid; idx < BS*BS; idx += 256) {
        int i = idx / BS, o = idx - i*BS;
        float p_io = 0.5f*(w2a[idx] + w2b[idx]);
        float m_io = m_s[idx];
        float accK = 0.f, accN = 0.f;
        for (int j = 0; j < BS; ++j) {
            float p_ij = 0.5f*(w2a[i*BS + j] + w2b[i*BS + j]);
            float mjo  = m_s[j*BS + o];
            accK += p_ij * mjo;
            accN += m_s[i*BS + j] * mjo;
        }
        float valK = p_io + accK;
        float valN = p_io + m_io + accN;
        WKP[n*BS*BS + idx] = 0.5f*(valK + valN);
        WKM[n*BS*BS + idx] = 0.5f*(valK - valN);
    }
    if (tid < BS) {
        const float* b2a = b2 + (0*NB + n)*BS;
        const float* b2b = b2 + (1*NB + n)*BS;
        float acc = b2a[tid] + b2b[tid];
        for (int j = 0; j < BS; ++j) acc += b2a[j] * m_s[j*BS + tid];
        BEFF[n*BS + tid] = acc;
    }
}

// ---------------------------------------------------------------------------
// K-tw: p7 twiddle tables in GLOBAL memory (p1 tables no longer used).
// ---------------------------------------------------------------------------
__global__ __launch_bounds__(256) void k_tw(
    float* __restrict__ c7t, float* __restrict__ s7t)
{
    int idx = blockIdx.x*256 + threadIdx.x;
    if (idx < P7_TW) {
        int j = idx & 7; int rest = idx >> 3;
        int wq = rest % 65; int wg = rest / 65;
        int ai = ((wg*8 + j) * wq) & 255;
        float sn, cs; sincosf(TWOPI * (float)ai / 256.0f, &sn, &cs);
        c7t[idx] = cs; s7t[idx] = sn;
    }
}

// ---------------------------------------------------------------------------
// P1 (v3): forward W-axis via 256-pt Stockham FFT, channel-pair packing.
// Block: 16 channels = 8 packed complex lines (z = x[c] + i x[c+1]) for one
// row (b*HH+h). x read EXACTLY ONCE (was 9x re-read, 790 MB FETCH).
// 8 radix-2 stages (same recurrence as verified k_cfft 256-pt sub-FFT:
// tw256[p<<st] == cfft tw768[p*(3<<st)], b-offset s*h = 128).
// Unpack U/V by conjugate symmetry (same formulas as verified k_hb_s2c),
// write only wp < 65. LDS 34.8 KB -> 4 blocks/CU. grid (48, 256), 256 thr.
// ---------------------------------------------------------------------------
__global__ __launch_bounds__(256) void k_p1(
    const float* __restrict__ x, float2* __restrict__ out)
{
    const int tid = threadIdx.x;
    const int row = blockIdx.y;           // 0..255 = b*HH+h
    const int c0 = blockIdx.x * 16;
    __shared__ float2 tw[256];
    __shared__ float2 bufA[8*256];        // 16 KB
    __shared__ float2 bufB[8*256];        // 16 KB

    {
        float sn, cs; sincosf(TWOPI*(float)tid/256.f, &sn, &cs);
        tw[tid] = make_float2(cs, -sn);
    }
    // load + pack: bufA[l*256 + w] = (x[row][w][c0+2l], x[row][w][c0+2l+1])
    const float* xr = x + (size_t)row * WW * CC + c0;
    for (int idx = tid; idx < 2048; idx += 256) {
        int l = idx & 7, w = idx >> 3;
        const float2 v = *(const float2*)(xr + (size_t)w*CC + 2*l);
        bufA[l*256 + w] = v;
    }
    __syncthreads();

    float2* src = bufA;
    float2* dst = bufB;
    const int t  = tid & 127;             // butterfly index 0..127
    const int l0 = tid >> 7;              // 0..1
    #pragma unroll
    for (int st = 0; st < 8; ++st) {
        const int s = 1 << st;
        const int q = t & (s - 1);
        const int p = t >> st;
        const float2 w = tw[p << st];
        #pragma unroll
        for (int k = 0; k < 4; ++k) {
            int base = (l0 + 2*k) * 256;  // lines 0..7
            float2 a = src[base + q + s*p];
            float2 b = src[base + q + s*p + 128];
            float dx = a.x - b.x, dy = a.y - b.y;
            dst[base + q + 2*s*p]     = make_float2(a.x + b.x, a.y + b.y);
            dst[base + q + 2*s*p + s] = make_float2(dx*w.x - dy*w.y, dx*w.y + dy*w.x);
        }
        __syncthreads();
        float2* tmp = src; src = dst; dst = tmp;
    }
    // 8 swaps -> result back in bufA (== src). Unpack channel pair, write wp<65.
    for (int idx = tid; idx < 8*WKEPT; idx += 256) {
        int l = idx & 7, wp = idx >> 3;
        float2 Z  = src[l*256 + wp];
        float2 Zm = src[l*256 + ((256 - wp) & 255)];
        float2 U = make_float2(0.5f*(Z.x + Zm.x), 0.5f*(Z.y - Zm.y));
        float2 V = make_float2(0.5f*(Z.y + Zm.y), 0.5f*(Zm.x - Z.x));
        size_t g = (size_t)(row*WKEPT + wp)*CC + c0 + 2*l;
        out[g]     = U;
        out[g + 1] = V;
    }
}

// ---------------------------------------------------------------------------
// P2/P6: C-axis 768-pt FFT per line (unchanged).
// ---------------------------------------------------------------------------
#define LPB 4
__global__ __launch_bounds__(256) void k_cfft(
    const float2* __restrict__ in, float2* __restrict__ out)
{
    __shared__ float2 tw[CC];
    __shared__ float2 bufA[LPB*CC];
    __shared__ float2 bufB[LPB*CC];
    const int tid = threadIdx.x;
    const size_t line0 = (size_t)blockIdx.x * LPB;

    for (int t = tid; t < CC; t += 256) {
        float sn, cs; sincosf(TWOPI * (float)t / 768.0f, &sn, &cs);
        tw[t] = make_float2(cs, -sn);
    }
    for (int idx = tid; idx < LPB*CC; idx += 256) {
        int l = idx / CC, c = idx - l*CC;
        int m = c / 3, j = c - 3*m;
        bufA[l*CC + j*256 + m] = in[(line0 + l)*CC + c];
    }
    __syncthreads();

    float2* src = bufA;
    float2* dst = bufB;
    #pragma unroll
    for (int st = 0; st < 8; ++st) {
        const int s = 1 << st;
        const int h = 128 >> st;
        for (int item = tid; item < LPB*3*128; item += 256) {
            int sub = item >> 7;
            int t   = item & 127;
            int q = t & (s - 1);
            int p = t >> st;
            float2 a = src[sub*256 + q + s*p];
            float2 b = src[sub*256 + q + s*(p + h)];
            float2 w = tw[p * (3 << st)];
            float dx = a.x - b.x, dy = a.y - b.y;
            dst[sub*256 + q + s*(2*p)]     = make_float2(a.x + b.x, a.y + b.y);
            dst[sub*256 + q + s*(2*p + 1)] = make_float2(dx*w.x - dy*w.y, dx*w.y + dy*w.x);
        }
        __syncthreads();
        float2* tmp = src; src = dst; dst = tmp;
    }
    for (int idx = tid; idx < LPB*CC; idx += 256) {
        int l = idx / CC, cp = idx - l*CC;
        int r = cp & 255;
        float2 S0 = src[(l*3 + 0)*256 + r];
        float2 S1 = src[(l*3 + 1)*256 + r];
        float2 S2 = src[(l*3 + 2)*256 + r];
        float2 w1 = tw[cp];
        int i2 = 2*cp; if (i2 >= CC) i2 -= CC;
        float2 w2 = tw[i2];
        float fr = S0.x + w1.x*S1.x - w1.y*S1.y + w2.x*S2.x - w2.y*S2.y;
        float fi = S0.y + w1.x*S1.y + w1.y*S1.x + w2.x*S2.y + w2.y*S2.x;
        out[(line0 + l)*CC + cp] = make_float2(fr, fi);
    }
}

// ---------------------------------------------------------------------------
// P3: H-axis via 128-pt radix-2 Stockham FFT (unchanged from round 5).
// ---------------------------------------------------------------------------
__global__ __launch_bounds__(256) void k_hb_c2a(
    const float2* __restrict__ in, float* __restrict__ aout)
{
    const int tid = threadIdx.x;
    const int wp = blockIdx.y;
    const int c0 = blockIdx.x * 8;
    __shared__ float2 tw[128];        // e^{-2pi i t/128}
    __shared__ float2 bufA[16*128];   // 16 KB
    __shared__ float2 bufB[16*128];   // 16 KB

    if (tid < 128) {
        float sn, cs; sincosf(TWOPI*(float)tid/128.f, &sn, &cs);
        tw[tid] = make_float2(cs, -sn);
    }
    for (int idx = tid; idx < 1024; idx += 256) {
        int cl = idx & 7, h = idx >> 3;
        float2 z0 = in[(size_t)((0*HH + h)*WKEPT + wp)*CC + c0 + cl];
        float2 z1 = in[(size_t)((1*HH + h)*WKEPT + wp)*CC + c0 + cl];
        bufA[(2*cl+0)*128 + h] = make_float2(z0.x+z1.x, z0.y+z1.y);
        bufA[(2*cl+1)*128 + h] = make_float2(z0.x-z1.x, z0.y-z1.y);
    }
    __syncthreads();

    float2* src = bufA;
    float2* dst = bufB;
    const int t  = tid & 63;
    const int l0 = tid >> 6;
    #pragma unroll
    for (int st = 0; st < 7; ++st) {
        const int s = 1 << st;
        const int q = t & (s - 1);
        const int p = t >> st;
        const float2 w = tw[p << st];
        #pragma unroll
        for (int k = 0; k < 4; ++k) {
            int base = (l0 + 4*k) * 128;
            float2 a = src[base + q + s*p];
            float2 b = src[base + q + s*p + 64];
            float dx = a.x - b.x, dy = a.y - b.y;
            dst[base + q + 2*s*p]     = make_float2(a.x + b.x, a.y + b.y);
            dst[base + q + 2*s*p + s] = make_float2(dx*w.x - dy*w.y, dx*w.y + dy*w.x);
        }
        __syncthreads();
        float2* tmp = src; src = dst; dst = tmp;
    }
    for (int idx = tid; idx < 2048; idx += 256) {
        int cl = idx & 7;
        int hp = (idx >> 3) & 127;
        int uv = idx >> 10;
        float2 z = src[(2*cl + uv)*128 + hp];
        aout[(size_t)((uv*HH + hp)*WKEPT + wp)*CC + c0 + cl] = z.x + z.y;
    }
}

// ---------------------------------------------------------------------------
// P5: H-axis FFT on REAL s via complex packing (unchanged from round 5).
// ---------------------------------------------------------------------------
__global__ __launch_bounds__(256) void k_hb_s2c(
    const float* __restrict__ sreal, float2* __restrict__ out)
{
    const int tid = threadIdx.x;
    const int wp = blockIdx.y;
    const int c0 = blockIdx.x * 16;
    __shared__ float2 tw[128];
    __shared__ float2 bufA[16*128];
    __shared__ float2 bufB[16*128];

    if (tid < 128) {
        float sn, cs; sincosf(TWOPI*(float)tid/128.f, &sn, &cs);
        tw[tid] = make_float2(cs, -sn);
    }
    for (int idx = tid; idx < 2048; idx += 256) {
        int cl = idx & 15, h = idx >> 4;
        float s0 = sreal[(size_t)((0*HH + h)*WKEPT + wp)*CC + c0 + cl];
        float s1 = sreal[(size_t)((1*HH + h)*WKEPT + wp)*CC + c0 + cl];
        bufA[cl*128 + h] = make_float2(s0 + s1, s0 - s1);   // z = u + i v
    }
    __syncthreads();

    float2* src = bufA;
    float2* dst = bufB;
    const int t  = tid & 63;
    const int l0 = tid >> 6;
    #pragma unroll
    for (int st = 0; st < 7; ++st) {
        const int s = 1 << st;
        const int q = t & (s - 1);
        const int p = t >> st;
        const float2 w = tw[p << st];
        #pragma unroll
        for (int k = 0; k < 4; ++k) {
            int base = (l0 + 4*k) * 128;
            float2 a = src[base + q + s*p];
            float2 b = src[base + q + s*p + 64];
            float dx = a.x - b.x, dy = a.y - b.y;
            dst[base + q + 2*s*p]     = make_float2(a.x + b.x, a.y + b.y);
            dst[base + q + 2*s*p + s] = make_float2(dx*w.x - dy*w.y, dx*w.y + dy*w.x);
        }
        __syncthreads();
        float2* tmp = src; src = dst; dst = tmp;
    }
    for (int idx = tid; idx < 2048; idx += 256) {
        int cl = idx & 15;
        int hp = idx >> 4;
        float2 A  = src[cl*128 + hp];
        float2 Zm = src[cl*128 + ((128 - hp) & 127)];
        float2 U = make_float2(0.5f*(A.x + Zm.x), 0.5f*(A.y - Zm.y));
        float2 V = make_float2(0.5f*(A.y + Zm.y), 0.5f*(Zm.x - A.x));
        out[(size_t)((0*HH + hp)*WKEPT + wp)*CC + c0 + cl] = U;
        out[(size_t)((1*HH + hp)*WKEPT + wp)*CC + c0 + cl] = V;
    }
}

// ---------------------------------------------------------------------------
// P4 (fused, v3): U/V-form layer1 + p2/m2-form layer2 + soft-threshold
// (unchanged from round 6 — bf16 staging, wave-uniform scalar weights).
// ---------------------------------------------------------------------------
__global__ __launch_bounds__(256, 6) void k_mlp(
    const float* __restrict__ a, const float* __restrict__ x,
    const float* __restrict__ w1, const float* __restrict__ b1,
    const float* __restrict__ WKP, const float* __restrict__ WKM,
    const float* __restrict__ BEFF, float* __restrict__ sout)
{
    const int tid = threadIdx.x;
    const int n = blockIdx.y;
    const int P0 = blockIdx.x * 64;
    __shared__ unsigned short SH[2*96*67];     // 25.1 KB total
    unsigned short* As = SH;                   // U, later p2  (bf16)
    unsigned short* Bs = SH + 96*67;           // V, later m2  (bf16)

    for (int idx = tid; idx < 64*96; idx += 256) {
        int p = idx / 96, i = idx - p*96;
        int P = P0 + p;
        float av = a[(size_t)P*CC + n*BS + i];
        int b = P / (HH*WKEPT);
        int rem = P - b*(HH*WKEPT);
        int h = rem / WKEPT;
        int wq = rem - h*WKEPT;
        int hh2 = (HH - h) & (HH-1);
        int ww2 = (WW - wq) & (WW-1);
        float anv = x[(size_t)((b*HH + hh2)*WW + ww2)*CC + n*BS + i];
        As[i*67 + p] = f2bf(0.5f*(av + anv));
        Bs[i*67 + p] = f2bf(0.5f*(av - anv));
    }
    __syncthreads();

    const int lane = tid & 63;
    const int wv = __builtin_amdgcn_readfirstlane(tid >> 6);  // 0..3, uniform
    const int ob = wv * 24;

    float t1[24], t2[24];
    #pragma unroll
    for (int j = 0; j < 24; ++j) { t1[j] = 0.f; t2[j] = 0.f; }
    {
        const float* w10 = w1 + (size_t)(0*NB + n)*BS*BS + ob;
        const float* w11 = w1 + (size_t)(1*NB + n)*BS*BS + ob;
        #pragma unroll 2
        for (int i = 0; i < 96; ++i) {
            float Uv = bf2f(As[i*67 + lane]);
            float Vv = bf2f(Bs[i*67 + lane]);
            const float* r0 = w10 + i*BS;
            const float* r1 = w11 + i*BS;
            #pragma unroll
            for (int j = 0; j < 24; ++j) {
                t1[j] = fmaf(Uv, r0[j], t1[j]);
                t2[j] = fmaf(Vv, r1[j], t2[j]);
            }
        }
    }

    {
        const float* b1k = b1 + (0*NB + n)*BS + ob;
        const float* b1n = b1 + (1*NB + n)*BS + ob;
        float p2v[24], m2v[24];
        #pragma unroll
        for (int j = 0; j < 24; ++j) {
            float ok = fmaxf(t1[j] + t2[j] + b1k[j], 0.f);
            float on = fmaxf(t1[j] - t2[j] + b1n[j], 0.f);
            p2v[j] = ok + on;
            m2v[j] = ok - on;
        }
        __syncthreads();
        #pragma unroll
        for (int j = 0; j < 24; ++j) {
            As[(ob + j)*67 + lane] = f2bf(p2v[j]);
            Bs[(ob + j)*67 + lane] = f2bf(m2v[j]);
        }
        __syncthreads();
    }

    float acc[24];
    #pragma unroll
    for (int j = 0; j < 24; ++j) acc[j] = 0.f;
    {
        const float* wkp = WKP + n*BS*BS + ob;
        const float* wkm = WKM + n*BS*BS + ob;
        #pragma unroll 2
        for (int i = 0; i < 96; ++i) {
            float pv = bf2f(As[i*67 + lane]);
            float mv = bf2f(Bs[i*67 + lane]);
            const float* rk = wkp + i*BS;
            const float* rm = wkm + i*BS;
            #pragma unroll
            for (int j = 0; j < 24; ++j) {
                acc[j] = fmaf(pv, rk[j], fmaf(mv, rm[j], acc[j]));
            }
        }
    }

    {
        const float* be = BEFF + n*BS + ob;
        float r[24];
        #pragma unroll
        for (int j = 0; j < 24; ++j) {
            float v = acc[j] + be[j];
            float av2 = fabsf(v) - 0.01f;
            r[j] = (av2 > 0.f) ? copysignf(av2, v) : 0.f;
        }
        __syncthreads();
        float* Fs = (float*)SH;            // 64*97 = 6208 floats <= 6432
        #pragma unroll
        for (int j = 0; j < 24; ++j)
            Fs[lane*97 + ob + j] = r[j];
        __syncthreads();
        for (int idx = tid; idx < 64*96; idx += 256) {
            int p2i = idx / 96, o = idx - p2i*96;
            sout[(size_t)(P0 + p2i)*CC + n*BS + o] = Fs[p2i*97 + o];
        }
    }
}

// ---------------------------------------------------------------------------
// P7: inverse W expansion with output-pair symmetry (unchanged).
// ---------------------------------------------------------------------------
__global__ __launch_bounds__(256) void k_p7(
    const float2* __restrict__ A, const float* __restrict__ x,
    const float* __restrict__ c7t, const float* __restrict__ s7t,
    float* __restrict__ out)
{
    const int tid = threadIdx.x;
    const int ct = blockIdx.x % 3;
    const int wg = blockIdx.x / 3;        // 0..15
    const int rg = blockIdx.y;            // 0..63
    const int c  = ct*256 + tid;
    const int wpb = wg*8;
    const int row0 = rg*4;

    float accA[4][8], accB[4][8], acc128[4];
    #pragma unroll
    for (int r = 0; r < 4; ++r) {
        acc128[r] = 0.f;
        #pragma unroll
        for (int j = 0; j < 8; ++j) { accA[r][j] = 0.f; accB[r][j] = 0.f; }
    }

    const float2* A0 = A + (size_t)row0 * WKEPT * CC + c;
    const float4* cT = (const float4*)(c7t + (size_t)wg*65*8);
    const float4* sT = (const float4*)(s7t + (size_t)wg*65*8);
    for (int wq = 0; wq < 65; ++wq) {
        float4 c0 = cT[2*wq], c1 = cT[2*wq+1];
        float4 s0 = sT[2*wq], s1 = sT[2*wq+1];
        float sg = (wq & 1) ? -1.f : 1.f;
        #pragma unroll
        for (int r = 0; r < 4; ++r) {
            float2 v = A0[(size_t)(r*WKEPT + wq) * CC];
            float P = v.x + v.y;
            float M = v.y - v.x;
            float N = v.x - v.y;
            acc128[r] = fmaf(sg, P, acc128[r]);
            accA[r][0] = fmaf(P, c0.x, fmaf(M, s0.x, accA[r][0]));
            accB[r][0] = fmaf(P, c0.x, fmaf(N, s0.x, accB[r][0]));
            accA[r][1] = fmaf(P, c0.y, fmaf(M, s0.y, accA[r][1]));
            accB[r][1] = fmaf(P, c0.y, fmaf(N, s0.y, accB[r][1]));
            accA[r][2] = fmaf(P, c0.z, fmaf(M, s0.z, accA[r][2]));
            accB[r][2] = fmaf(P, c0.z, fmaf(N, s0.z, accB[r][2]));
            accA[r][3] = fmaf(P, c0.w, fmaf(M, s0.w, accA[r][3]));
            accB[r][3] = fmaf(P, c0.w, fmaf(N, s0.w, accB[r][3]));
            accA[r][4] = fmaf(P, c1.x, fmaf(M, s1.x, accA[r][4]));
            accB[r][4] = fmaf(P, c1.x, fmaf(N, s1.x, accB[r][4]));
            accA[r][5] = fmaf(P, c1.y, fmaf(M, s1.y, accA[r][5]));
            accB[r][5] = fmaf(P, c1.y, fmaf(N, s1.y, accB[r][5]));
            accA[r][6] = fmaf(P, c1.z, fmaf(M, s1.z, accA[r][6]));
            accB[r][6] = fmaf(P, c1.z, fmaf(N, s1.z, accB[r][6]));
            accA[r][7] = fmaf(P, c1.w, fmaf(M, s1.w, accA[r][7]));
            accB[r][7] = fmaf(P, c1.w, fmaf(N, s1.w, accB[r][7]));
        }
    }

    const float scale = 1.0f / 50331648.0f;
    #pragma unroll
    for (int r = 0; r < 4; ++r) {
        size_t base = (size_t)(row0 + r) * WW * CC + c;
        #pragma unroll
        for (int j = 0; j < 8; ++j) {
            int w = wpb + j;
            size_t g = base + (size_t)w*CC;
            out[g] = fmaf(accA[r][j], scale, x[g]);
            if (w != 0) {
                size_t g2 = base + (size_t)(256 - w)*CC;
                out[g2] = fmaf(accB[r][j], scale, x[g2]);
            }
        }
        if (wg == 0) {
            size_t g = base + (size_t)128*CC;
            out[g] = fmaf(acc128[r], scale, x[g]);
        }
    }
}

// ---------------------------------------------------------------------------
// P7 fallback (unchanged).
// ---------------------------------------------------------------------------
__global__ __launch_bounds__(256) void k_p7_fb(
    const float2* __restrict__ A, const float* __restrict__ x,
    float* __restrict__ out)
{
    const int tid = threadIdx.x;
    const int ct = blockIdx.x % 3;
    const int wg = blockIdx.x / 3;
    const int h = blockIdx.y, b = blockIdx.z;
    const int c = ct*256 + tid;
    __shared__ float cm[WKEPT][8];
    __shared__ float cp[WKEPT][8];
    for (int idx = tid; idx < WKEPT*8; idx += 256) {
        int wq = idx >> 3, j = idx & 7;
        int w = wg*8 + j;
        int ai = (w * wq) & 255;
        float sn, cse; sincosf(TWOPI * (float)ai / 256.f, &sn, &cse);
        cm[wq][j] = cse - sn;
        cp[wq][j] = cse + sn;
    }
    __syncthreads();
    float acc[8] = {0,0,0,0,0,0,0,0};
    const float2* Ab = A + (size_t)((b*HH + h)*WKEPT)*CC + c;
    for (int wq = 0; wq < WKEPT; ++wq) {
        float2 v = Ab[(size_t)wq*CC];
        const float4* m4 = (const float4*)(&cm[wq][0]);
        const float4* p4 = (const float4*)(&cp[wq][0]);
        #pragma unroll
        for (int jj = 0; jj < 2; ++jj) {
            float4 qm = m4[jj], qp = p4[jj];
            acc[4*jj+0] += v.x*qm.x + v.y*qp.x;
            acc[4*jj+1] += v.x*qm.y + v.y*qp.y;
            acc[4*jj+2] += v.x*qm.z + v.y*qp.z;
            acc[4*jj+3] += v.x*qm.w + v.y*qp.w;
        }
    }
    const float scale = 1.0f / 50331648.0f;
    size_t base = (size_t)(b*HH + h)*WW*CC + c;
    #pragma unroll
    for (int j = 0; j < 8; ++j) {
        int w = wg*8 + j;
        size_t g = base + (size_t)w*CC;
        out[g] = fmaf(acc[j], scale, x[g]);
    }
}

// ---------------------------------------------------------------------------
// Launch. ws layout (floats):
//   [0 : 25,559,040)   complex buffer A (16640*768 float2)
//                      first half doubles as a_real, second half as s_real
//   [25,559,040 ...)   legacy W1P/W1M slots (unused), WKP, WKM, BEFF,
//                      then c1t/s1t (unused), c7t, s7t twiddle tables
// d_out doubles as complex buffer B.
// ---------------------------------------------------------------------------
extern "C" void kernel_launch(void* const* d_in, const int* in_sizes, int n_in,
                              void* d_out, int out_size, void* d_ws, size_t ws_size,
                              hipStream_t stream)
{
    (void)in_sizes; (void)n_in; (void)out_size;
    const float* x  = (const float*)d_in[0];
    const float* w1 = (const float*)d_in[1];
    const float* b1 = (const float*)d_in[2];
    const float* w2 = (const float*)d_in[3];
    const float* b2 = (const float*)d_in[4];

    float*  ws     = (float*)d_ws;
    float2* Abuf   = (float2*)d_ws;
    float*  a_real = ws;
    float*  s_real = ws + (size_t)NPTS*CC;
    float*  W1P    = ws + 2*(size_t)NPTS*CC;   // unused (layout keeps offsets)
    float*  W1M    = W1P + NB*BS*BS;           // unused
    float*  WKP    = W1M + NB*BS*BS;
    float*  WKM    = WKP + NB*BS*BS;
    float*  BEFF   = WKM + NB*BS*BS;
    float*  c1t    = BEFF + NB*BS;             // unused
    float*  s1t    = c1t + P1_TW;              // unused
    float*  c7t    = s1t + P1_TW;
    float*  s7t    = c7t + P7_TW;

    const size_t need_bytes =
        ((size_t)2*NPTS*CC + 4*(size_t)NB*BS*BS + NB*BS + 2*P1_TW + 2*P7_TW)
        * sizeof(float);
    const bool fast = (ws_size >= need_bytes);

    float2* Bc   = (float2*)d_out;
    float*  outf = (float*)d_out;

    k_weights<<<dim3(NB), dim3(256), 0, stream>>>(w2, b2, WKP, WKM, BEFF);
    if (fast) {
        k_tw<<<dim3(33), dim3(256), 0, stream>>>(c7t, s7t);
    }
    k_p1     <<<dim3(48, 256), dim3(256), 0, stream>>>(x, Abuf);
    k_cfft   <<<dim3(NPTS/LPB), dim3(256), 0, stream>>>(Abuf, Bc);
    k_hb_c2a <<<dim3(96, WKEPT), dim3(256), 0, stream>>>(Bc, a_real);
    k_mlp    <<<dim3(260, NB), dim3(256), 0, stream>>>(a_real, x, w1, b1,
                                                       WKP, WKM, BEFF, s_real);
    k_hb_s2c <<<dim3(48, WKEPT), dim3(256), 0, stream>>>(s_real, Bc);
    k_cfft   <<<dim3(NPTS/LPB), dim3(256), 0, stream>>>(Bc, Abuf);
    if (fast) {
        k_p7<<<dim3(48, 64), dim3(256), 0, stream>>>(Abuf, x, c7t, s7t, outf);
    } else {
        k_p7_fb<<<dim3(96, HH, BB), dim3(256), 0, stream>>>(Abuf, x, outf);
    }
}

// Round 8
// 1086.462 us; speedup vs baseline: 2.2245x; 1.0929x over previous
//
#include <hip/hip_runtime.h>

#define BB 2
#define HH 128
#define WW 256
#define CC 768
#define NB 8
#define BS 96
#define WKEPT 65
#define NPTS (BB*HH*WKEPT)        // 16640 kept (b,h,w') points
#define NTOT ((size_t)BB*HH*WW*CC) // 50331648
#define TWOPI 6.283185307179586f

#define P7_TW (16*65*8)           // 8320 entries

typedef __attribute__((ext_vector_type(8))) short bf16x8;
typedef __attribute__((ext_vector_type(4))) float f32x4;

__device__ __forceinline__ unsigned short f2bf(float f) {
    unsigned int u = __float_as_uint(f);
    u += 0x7fffu + ((u >> 16) & 1u);      // round-to-nearest-even
    return (unsigned short)(u >> 16);
}
__device__ __forceinline__ float bf2f(unsigned short s) {
    return __uint_as_float((unsigned int)s << 16);
}

// ---------------------------------------------------------------------------
// K0 (v2): precombine weights into TRANSPOSED bf16 hi/lo pairs for MFMA.
//   W10t/W11t = w1[0]/w1[1] transposed to [o][k];  hi=bf16(w), lo=bf16(w-hi)
//   WKPt/WKMt = (WK±WNK)/2 transposed (collapsed layer 2, p2/m2 form)
//   BEFF = b2[0]+b2[1]+b2[0]@m
// ---------------------------------------------------------------------------
__global__ __launch_bounds__(256) void k_weights(
    const float* __restrict__ w1, const float* __restrict__ w2,
    const float* __restrict__ b2,
    unsigned short* __restrict__ W10h, unsigned short* __restrict__ W10l,
    unsigned short* __restrict__ W11h, unsigned short* __restrict__ W11l,
    unsigned short* __restrict__ WKPh, unsigned short* __restrict__ WKPl,
    unsigned short* __restrict__ WKMh, unsigned short* __restrict__ WKMl,
    float* __restrict__ BEFF)
{
    const int n = blockIdx.x;
    const int tid = threadIdx.x;
    __shared__ float m_s[BS*BS];

    const float* w2a = w2 + (size_t)(0*NB + n)*BS*BS;
    const float* w2b = w2 + (size_t)(1*NB + n)*BS*BS;
    for (int idx = tid; idx < BS*BS; idx += 256)
        m_s[idx] = 0.5f*(w2a[idx] - w2b[idx]);

    // layer-1 weights: transpose + hi/lo split
    const float* w1a = w1 + (size_t)(0*NB + n)*BS*BS;
    const float* w1b = w1 + (size_t)(1*NB + n)*BS*BS;
    for (int idx = tid; idx < BS*BS; idx += 256) {
        int o = idx / BS, k = idx - o*BS;          // dest [o][k]
        float v0 = w1a[k*BS + o];
        unsigned short h0 = f2bf(v0);
        unsigned short l0 = f2bf(v0 - bf2f(h0));
        W10h[n*BS*BS + idx] = h0;  W10l[n*BS*BS + idx] = l0;
        float v1 = w1b[k*BS + o];
        unsigned short h1 = f2bf(v1);
        unsigned short l1 = f2bf(v1 - bf2f(h1));
        W11h[n*BS*BS + idx] = h1;  W11l[n*BS*BS + idx] = l1;
    }
    __syncthreads();

    for (int idx = tid; idx < BS*BS; idx += 256) {
        int i = idx / BS, o = idx - i*BS;
        float p_io = 0.5f*(w2a[idx] + w2b[idx]);
        float m_io = m_s[idx];
        float accK = 0.f, accN = 0.f;
        for (int j = 0; j < BS; ++j) {
            float p_ij = 0.5f*(w2a[i*BS + j] + w2b[i*BS + j]);
            float mjo  = m_s[j*BS + o];
            accK += p_ij * mjo;
            accN += m_s[i*BS + j] * mjo;
        }
        float valK = p_io + accK;
        float valN = p_io + m_io + accN;
        float wkp = 0.5f*(valK + valN);
        float wkm = 0.5f*(valK - valN);
        int d = n*BS*BS + o*BS + i;                // transposed [o][k=i]
        unsigned short hp = f2bf(wkp);
        WKPh[d] = hp;  WKPl[d] = f2bf(wkp - bf2f(hp));
        unsigned short hm = f2bf(wkm);
        WKMh[d] = hm;  WKMl[d] = f2bf(wkm - bf2f(hm));
    }
    if (tid < BS) {
        const float* b2a = b2 + (0*NB + n)*BS;
        const float* b2b = b2 + (1*NB + n)*BS;
        float acc = b2a[tid] + b2b[tid];
        for (int j = 0; j < BS; ++j) acc += b2a[j] * m_s[j*BS + tid];
        BEFF[n*BS + tid] = acc;
    }
}

// ---------------------------------------------------------------------------
// K-tw: p7 twiddle tables in GLOBAL memory (unchanged).
// ---------------------------------------------------------------------------
__global__ __launch_bounds__(256) void k_tw(
    float* __restrict__ c7t, float* __restrict__ s7t)
{
    int idx = blockIdx.x*256 + threadIdx.x;
    if (idx < P7_TW) {
        int j = idx & 7; int rest = idx >> 3;
        int wq = rest % 65; int wg = rest / 65;
        int ai = ((wg*8 + j) * wq) & 255;
        float sn, cs; sincosf(TWOPI * (float)ai / 256.0f, &sn, &cs);
        c7t[idx] = cs; s7t[idx] = sn;
    }
}

// ---------------------------------------------------------------------------
// P1: forward W-axis via 256-pt Stockham FFT, channel-pair packing
// (unchanged from round 7).
// ---------------------------------------------------------------------------
__global__ __launch_bounds__(256) void k_p1(
    const float* __restrict__ x, float2* __restrict__ out)
{
    const int tid = threadIdx.x;
    const int row = blockIdx.y;           // 0..255 = b*HH+h
    const int c0 = blockIdx.x * 16;
    __shared__ float2 tw[256];
    __shared__ float2 bufA[8*256];        // 16 KB
    __shared__ float2 bufB[8*256];        // 16 KB

    {
        float sn, cs; sincosf(TWOPI*(float)tid/256.f, &sn, &cs);
        tw[tid] = make_float2(cs, -sn);
    }
    const float* xr = x + (size_t)row * WW * CC + c0;
    for (int idx = tid; idx < 2048; idx += 256) {
        int l = idx & 7, w = idx >> 3;
        const float2 v = *(const float2*)(xr + (size_t)w*CC + 2*l);
        bufA[l*256 + w] = v;
    }
    __syncthreads();

    float2* src = bufA;
    float2* dst = bufB;
    const int t  = tid & 127;
    const int l0 = tid >> 7;
    #pragma unroll
    for (int st = 0; st < 8; ++st) {
        const int s = 1 << st;
        const int q = t & (s - 1);
        const int p = t >> st;
        const float2 w = tw[p << st];
        #pragma unroll
        for (int k = 0; k < 4; ++k) {
            int base = (l0 + 2*k) * 256;
            float2 a = src[base + q + s*p];
            float2 b = src[base + q + s*p + 128];
            float dx = a.x - b.x, dy = a.y - b.y;
            dst[base + q + 2*s*p]     = make_float2(a.x + b.x, a.y + b.y);
            dst[base + q + 2*s*p + s] = make_float2(dx*w.x - dy*w.y, dx*w.y + dy*w.x);
        }
        __syncthreads();
        float2* tmp = src; src = dst; dst = tmp;
    }
    for (int idx = tid; idx < 8*WKEPT; idx += 256) {
        int l = idx & 7, wp = idx >> 3;
        float2 Z  = src[l*256 + wp];
        float2 Zm = src[l*256 + ((256 - wp) & 255)];
        float2 U = make_float2(0.5f*(Z.x + Zm.x), 0.5f*(Z.y - Zm.y));
        float2 V = make_float2(0.5f*(Z.y + Zm.y), 0.5f*(Zm.x - Z.x));
        size_t g = (size_t)(row*WKEPT + wp)*CC + c0 + 2*l;
        out[g]     = U;
        out[g + 1] = V;
    }
}

// ---------------------------------------------------------------------------
// P2/P6: C-axis 768-pt FFT per line (unchanged).
// ---------------------------------------------------------------------------
#define LPB 4
__global__ __launch_bounds__(256) void k_cfft(
    const float2* __restrict__ in, float2* __restrict__ out)
{
    __shared__ float2 tw[CC];
    __shared__ float2 bufA[LPB*CC];
    __shared__ float2 bufB[LPB*CC];
    const int tid = threadIdx.x;
    const size_t line0 = (size_t)blockIdx.x * LPB;

    for (int t = tid; t < CC; t += 256) {
        float sn, cs; sincosf(TWOPI * (float)t / 768.0f, &sn, &cs);
        tw[t] = make_float2(cs, -sn);
    }
    for (int idx = tid; idx < LPB*CC; idx += 256) {
        int l = idx / CC, c = idx - l*CC;
        int m = c / 3, j = c - 3*m;
        bufA[l*CC + j*256 + m] = in[(line0 + l)*CC + c];
    }
    __syncthreads();

    float2* src = bufA;
    float2* dst = bufB;
    #pragma unroll
    for (int st = 0; st < 8; ++st) {
        const int s = 1 << st;
        const int h = 128 >> st;
        for (int item = tid; item < LPB*3*128; item += 256) {
            int sub = item >> 7;
            int t   = item & 127;
            int q = t & (s - 1);
            int p = t >> st;
            float2 a = src[sub*256 + q + s*p];
            float2 b = src[sub*256 + q + s*(p + h)];
            float2 w = tw[p * (3 << st)];
            float dx = a.x - b.x, dy = a.y - b.y;
            dst[sub*256 + q + s*(2*p)]     = make_float2(a.x + b.x, a.y + b.y);
            dst[sub*256 + q + s*(2*p + 1)] = make_float2(dx*w.x - dy*w.y, dx*w.y + dy*w.x);
        }
        __syncthreads();
        float2* tmp = src; src = dst; dst = tmp;
    }
    for (int idx = tid; idx < LPB*CC; idx += 256) {
        int l = idx / CC, cp = idx - l*CC;
        int r = cp & 255;
        float2 S0 = src[(l*3 + 0)*256 + r];
        float2 S1 = src[(l*3 + 1)*256 + r];
        float2 S2 = src[(l*3 + 2)*256 + r];
        float2 w1 = tw[cp];
        int i2 = 2*cp; if (i2 >= CC) i2 -= CC;
        float2 w2 = tw[i2];
        float fr = S0.x + w1.x*S1.x - w1.y*S1.y + w2.x*S2.x - w2.y*S2.y;
        float fi = S0.y + w1.x*S1.y + w1.y*S1.x + w2.x*S2.y + w2.y*S2.x;
        out[(line0 + l)*CC + cp] = make_float2(fr, fi);
    }
}

// ---------------------------------------------------------------------------
// P3: H-axis via 128-pt radix-2 Stockham FFT (unchanged).
// ---------------------------------------------------------------------------
__global__ __launch_bounds__(256) void k_hb_c2a(
    const float2* __restrict__ in, float* __restrict__ aout)
{
    const int tid = threadIdx.x;
    const int wp = blockIdx.y;
    const int c0 = blockIdx.x * 8;
    __shared__ float2 tw[128];
    __shared__ float2 bufA[16*128];
    __shared__ float2 bufB[16*128];

    if (tid < 128) {
        float sn, cs; sincosf(TWOPI*(float)tid/128.f, &sn, &cs);
        tw[tid] = make_float2(cs, -sn);
    }
    for (int idx = tid; idx < 1024; idx += 256) {
        int cl = idx & 7, h = idx >> 3;
        float2 z0 = in[(size_t)((0*HH + h)*WKEPT + wp)*CC + c0 + cl];
        float2 z1 = in[(size_t)((1*HH + h)*WKEPT + wp)*CC + c0 + cl];
        bufA[(2*cl+0)*128 + h] = make_float2(z0.x+z1.x, z0.y+z1.y);
        bufA[(2*cl+1)*128 + h] = make_float2(z0.x-z1.x, z0.y-z1.y);
    }
    __syncthreads();

    float2* src = bufA;
    float2* dst = bufB;
    const int t  = tid & 63;
    const int l0 = tid >> 6;
    #pragma unroll
    for (int st = 0; st < 7; ++st) {
        const int s = 1 << st;
        const int q = t & (s - 1);
        const int p = t >> st;
        const float2 w = tw[p << st];
        #pragma unroll
        for (int k = 0; k < 4; ++k) {
            int base = (l0 + 4*k) * 128;
            float2 a = src[base + q + s*p];
            float2 b = src[base + q + s*p + 64];
            float dx = a.x - b.x, dy = a.y - b.y;
            dst[base + q + 2*s*p]     = make_float2(a.x + b.x, a.y + b.y);
            dst[base + q + 2*s*p + s] = make_float2(dx*w.x - dy*w.y, dx*w.y + dy*w.x);
        }
        __syncthreads();
        float2* tmp = src; src = dst; dst = tmp;
    }
    for (int idx = tid; idx < 2048; idx += 256) {
        int cl = idx & 7;
        int hp = (idx >> 3) & 127;
        int uv = idx >> 10;
        float2 z = src[(2*cl + uv)*128 + hp];
        aout[(size_t)((uv*HH + hp)*WKEPT + wp)*CC + c0 + cl] = z.x + z.y;
    }
}

// ---------------------------------------------------------------------------
// P5: H-axis FFT on REAL s via complex packing (unchanged).
// ---------------------------------------------------------------------------
__global__ __launch_bounds__(256) void k_hb_s2c(
    const float* __restrict__ sreal, float2* __restrict__ out)
{
    const int tid = threadIdx.x;
    const int wp = blockIdx.y;
    const int c0 = blockIdx.x * 16;
    __shared__ float2 tw[128];
    __shared__ float2 bufA[16*128];
    __shared__ float2 bufB[16*128];

    if (tid < 128) {
        float sn, cs; sincosf(TWOPI*(float)tid/128.f, &sn, &cs);
        tw[tid] = make_float2(cs, -sn);
    }
    for (int idx = tid; idx < 2048; idx += 256) {
        int cl = idx & 15, h = idx >> 4;
        float s0 = sreal[(size_t)((0*HH + h)*WKEPT + wp)*CC + c0 + cl];
        float s1 = sreal[(size_t)((1*HH + h)*WKEPT + wp)*CC + c0 + cl];
        bufA[cl*128 + h] = make_float2(s0 + s1, s0 - s1);   // z = u + i v
    }
    __syncthreads();

    float2* src = bufA;
    float2* dst = bufB;
    const int t  = tid & 63;
    const int l0 = tid >> 6;
    #pragma unroll
    for (int st = 0; st < 7; ++st) {
        const int s = 1 << st;
        const int q = t & (s - 1);
        const int p = t >> st;
        const float2 w = tw[p << st];
        #pragma unroll
        for (int k = 0; k < 4; ++k) {
            int base = (l0 + 4*k) * 128;
            float2 a = src[base + q + s*p];
            float2 b = src[base + q + s*p + 64];
            float dx = a.x - b.x, dy = a.y - b.y;
            dst[base + q + 2*s*p]     = make_float2(a.x + b.x, a.y + b.y);
            dst[base + q + 2*s*p + s] = make_float2(dx*w.x - dy*w.y, dx*w.y + dy*w.x);
        }
        __syncthreads();
        float2* tmp = src; src = dst; dst = tmp;
    }
    for (int idx = tid; idx < 2048; idx += 256) {
        int cl = idx & 15;
        int hp = idx >> 4;
        float2 A  = src[cl*128 + hp];
        float2 Zm = src[cl*128 + ((128 - hp) & 127)];
        float2 U = make_float2(0.5f*(A.x + Zm.x), 0.5f*(A.y - Zm.y));
        float2 V = make_float2(0.5f*(A.y + Zm.y), 0.5f*(Zm.x - A.x));
        out[(size_t)((0*HH + hp)*WKEPT + wp)*CC + c0 + cl] = U;
        out[(size_t)((1*HH + hp)*WKEPT + wp)*CC + c0 + cl] = V;
    }
}

// ---------------------------------------------------------------------------
// P4 (v4, MFMA): fused MLP on matrix cores.
//   U=(a+an)/2, V=(a-an)/2 -> T1=U@W10, T2=V@W11 (mfma_f32_16x16x32_bf16,
//   hi/lo weight split: bf16 products exact in fp32, ~17-bit weights);
//   o1k=relu(T1+T2+b1k), o1nk=relu(T1-T2+b1n); p2/m2 via LDS transpose;
//   S = p2@WKP + m2@WKM + BEFF; soft-threshold.
// Tiling: block=64 points (4 waves x 16-pt M-tile), N=96 (6 tiles), K=96
// (3 chunks of 32, weights staged per chunk in LDS transposed [o][k],
// b-frag = contiguous bf16x8 = verified ladder "B^T rows" convention).
// A-frags per-lane direct from global (a-row and flipped x-row are both
// c-contiguous). C/D layout (HW-verified): col=lane&15, row=(lane>>4)*4+reg.
// LDS 62 KB -> 2 blocks/CU. grid (260, 8), 256 thr.
// ---------------------------------------------------------------------------
__global__ __launch_bounds__(256, 2) void k_mlp(
    const float* __restrict__ a, const float* __restrict__ x,
    const unsigned short* __restrict__ W10h, const unsigned short* __restrict__ W10l,
    const unsigned short* __restrict__ W11h, const unsigned short* __restrict__ W11l,
    const unsigned short* __restrict__ WKPh, const unsigned short* __restrict__ WKPl,
    const unsigned short* __restrict__ WKMh, const unsigned short* __restrict__ WKMl,
    const float* __restrict__ b1, const float* __restrict__ BEFF,
    float* __restrict__ sout)
{
    const int tid = threadIdx.x;
    const int n = blockIdx.y;
    const int P0 = blockIdx.x * 64;
    // weights for current chunk: [96 o][48 pad] (only k<32 used; 96B rows, 16B-aligned)
    __shared__ unsigned short Wh_A[96*48], Wl_A[96*48];   // 9216 B each
    __shared__ unsigned short Wh_B[96*48], Wl_B[96*48];
    // p2/m2 handoff: [64 pt][104 pad] (208B rows, 16B-aligned, 2-way banks)
    __shared__ unsigned short PMp[64*104], PMm[64*104];   // 13312 B each

    const int lane = tid & 63;
    const int wv = tid >> 6;          // wave 0..3 -> M-tile points 16*wv..+15
    const int lr = lane & 15;         // A-row / B-col / D-col
    const int lk = lane >> 4;         // k-segment 0..3 (8 elems each)

    // A-load row (this lane's point) + flipped-x base
    const int Pld = P0 + 16*wv + lr;
    int bb = Pld / (HH*WKEPT);
    int rem = Pld - bb*(HH*WKEPT);
    int h = rem / WKEPT;
    int wq = rem - h*WKEPT;
    int hh2 = (HH - h) & (HH-1);
    int ww2 = (WW - wq) & (WW-1);
    const float* aRow  = a + (size_t)Pld*CC + n*BS;
    const float* anRow = x + (size_t)((bb*HH + hh2)*WW + ww2)*CC + n*BS;

    f32x4 T1[6], T2[6];
    #pragma unroll
    for (int t = 0; t < 6; ++t) {
        T1[t] = (f32x4){0.f,0.f,0.f,0.f};
        T2[t] = (f32x4){0.f,0.f,0.f,0.f};
    }

    // ---- layer 1: 3 K-chunks ----
    for (int ks = 0; ks < 3; ++ks) {
        __syncthreads();   // prior-chunk readers done before overwrite
        for (int idx = tid; idx < 96*16; idx += 256) {
            int o = idx >> 4, kp = (idx & 15) << 1;
            int g = n*BS*BS + o*BS + ks*32 + kp;
            *(ushort2*)&Wh_A[o*48 + kp] = *(const ushort2*)&W10h[g];
            *(ushort2*)&Wl_A[o*48 + kp] = *(const ushort2*)&W10l[g];
            *(ushort2*)&Wh_B[o*48 + kp] = *(const ushort2*)&W11h[g];
            *(ushort2*)&Wl_B[o*48 + kp] = *(const ushort2*)&W11l[g];
        }
        __syncthreads();

        const int kseg = ks*32 + 8*lk;
        float4 a0 = *(const float4*)(aRow + kseg);
        float4 a1 = *(const float4*)(aRow + kseg + 4);
        float4 n0 = *(const float4*)(anRow + kseg);
        float4 n1 = *(const float4*)(anRow + kseg + 4);
        bf16x8 uF, vF;
        uF[0] = (short)f2bf(0.5f*(a0.x + n0.x));  vF[0] = (short)f2bf(0.5f*(a0.x - n0.x));
        uF[1] = (short)f2bf(0.5f*(a0.y + n0.y));  vF[1] = (short)f2bf(0.5f*(a0.y - n0.y));
        uF[2] = (short)f2bf(0.5f*(a0.z + n0.z));  vF[2] = (short)f2bf(0.5f*(a0.z - n0.z));
        uF[3] = (short)f2bf(0.5f*(a0.w + n0.w));  vF[3] = (short)f2bf(0.5f*(a0.w - n0.w));
        uF[4] = (short)f2bf(0.5f*(a1.x + n1.x));  vF[4] = (short)f2bf(0.5f*(a1.x - n1.x));
        uF[5] = (short)f2bf(0.5f*(a1.y + n1.y));  vF[5] = (short)f2bf(0.5f*(a1.y - n1.y));
        uF[6] = (short)f2bf(0.5f*(a1.z + n1.z));  vF[6] = (short)f2bf(0.5f*(a1.z - n1.z));
        uF[7] = (short)f2bf(0.5f*(a1.w + n1.w));  vF[7] = (short)f2bf(0.5f*(a1.w - n1.w));

        #pragma unroll
        for (int t = 0; t < 6; ++t) {
            int wb = (16*t + lr)*48 + 8*lk;
            bf16x8 bh = *(const bf16x8*)&Wh_A[wb];
            T1[t] = __builtin_amdgcn_mfma_f32_16x16x32_bf16(uF, bh, T1[t], 0, 0, 0);
            bf16x8 bl = *(const bf16x8*)&Wl_A[wb];
            T1[t] = __builtin_amdgcn_mfma_f32_16x16x32_bf16(uF, bl, T1[t], 0, 0, 0);
            bf16x8 ch = *(const bf16x8*)&Wh_B[wb];
            T2[t] = __builtin_amdgcn_mfma_f32_16x16x32_bf16(vF, ch, T2[t], 0, 0, 0);
            bf16x8 cl = *(const bf16x8*)&Wl_B[wb];
            T2[t] = __builtin_amdgcn_mfma_f32_16x16x32_bf16(vF, cl, T2[t], 0, 0, 0);
        }
    }

    // ---- bias + relu -> p2/m2 into LDS (transpose via D-layout) ----
    #pragma unroll
    for (int t = 0; t < 6; ++t) {
        float bk = b1[(0*NB + n)*BS + 16*t + lr];
        float bn = b1[(1*NB + n)*BS + 16*t + lr];
        #pragma unroll
        for (int r = 0; r < 4; ++r) {
            float ok = fmaxf(T1[t][r] + T2[t][r] + bk, 0.f);
            float on = fmaxf(T1[t][r] - T2[t][r] + bn, 0.f);
            int pl = 16*wv + 4*lk + r;
            PMp[pl*104 + 16*t + lr] = f2bf(ok + on);
            PMm[pl*104 + 16*t + lr] = f2bf(ok - on);
        }
    }

    // ---- layer 2: 3 K-chunks (S = p2@WKP + m2@WKM) ----
    f32x4 S[6];
    #pragma unroll
    for (int t = 0; t < 6; ++t) S[t] = (f32x4){0.f,0.f,0.f,0.f};
    for (int ks = 0; ks < 3; ++ks) {
        __syncthreads();   // PM writes visible (ks=0) / prior readers done
        for (int idx = tid; idx < 96*16; idx += 256) {
            int o = idx >> 4, kp = (idx & 15) << 1;
            int g = n*BS*BS + o*BS + ks*32 + kp;
            *(ushort2*)&Wh_A[o*48 + kp] = *(const ushort2*)&WKPh[g];
            *(ushort2*)&Wl_A[o*48 + kp] = *(const ushort2*)&WKPl[g];
            *(ushort2*)&Wh_B[o*48 + kp] = *(const ushort2*)&WKMh[g];
            *(ushort2*)&Wl_B[o*48 + kp] = *(const ushort2*)&WKMl[g];
        }
        __syncthreads();

        const int kseg = ks*32 + 8*lk;
        bf16x8 pF = *(const bf16x8*)&PMp[(16*wv + lr)*104 + kseg];
        bf16x8 mF = *(const bf16x8*)&PMm[(16*wv + lr)*104 + kseg];
        #pragma unroll
        for (int t = 0; t < 6; ++t) {
            int wb = (16*t + lr)*48 + 8*lk;
            bf16x8 bh = *(const bf16x8*)&Wh_A[wb];
            S[t] = __builtin_amdgcn_mfma_f32_16x16x32_bf16(pF, bh, S[t], 0, 0, 0);
            bf16x8 bl = *(const bf16x8*)&Wl_A[wb];
            S[t] = __builtin_amdgcn_mfma_f32_16x16x32_bf16(pF, bl, S[t], 0, 0, 0);
            bf16x8 ch = *(const bf16x8*)&Wh_B[wb];
            S[t] = __builtin_amdgcn_mfma_f32_16x16x32_bf16(mF, ch, S[t], 0, 0, 0);
            bf16x8 cl = *(const bf16x8*)&Wl_B[wb];
            S[t] = __builtin_amdgcn_mfma_f32_16x16x32_bf16(mF, cl, S[t], 0, 0, 0);
        }
    }

    // ---- epilogue: +BEFF, soft-threshold, store ----
    #pragma unroll
    for (int t = 0; t < 6; ++t) {
        float be = BEFF[n*BS + 16*t + lr];
        #pragma unroll
        for (int r = 0; r < 4; ++r) {
            float v = S[t][r] + be;
            float av2 = fabsf(v) - 0.01f;
            float sv = (av2 > 0.f) ? copysignf(av2, v) : 0.f;
            int pt = P0 + 16*wv + 4*lk + r;
            sout[(size_t)pt*CC + n*BS + 16*t + lr] = sv;
        }
    }
}

// ---------------------------------------------------------------------------
// P7: inverse W expansion with output-pair symmetry (unchanged).
// ---------------------------------------------------------------------------
__global__ __launch_bounds__(256) void k_p7(
    const float2* __restrict__ A, const float* __restrict__ x,
    const float* __restrict__ c7t, const float* __restrict__ s7t,
    float* __restrict__ out)
{
    const int tid = threadIdx.x;
    const int ct = blockIdx.x % 3;
    const int wg = blockIdx.x / 3;        // 0..15
    const int rg = blockIdx.y;            // 0..63
    const int c  = ct*256 + tid;
    const int wpb = wg*8;
    const int row0 = rg*4;

    float accA[4][8], accB[4][8], acc128[4];
    #pragma unroll
    for (int r = 0; r < 4; ++r) {
        acc128[r] = 0.f;
        #pragma unroll
        for (int j = 0; j < 8; ++j) { accA[r][j] = 0.f; accB[r][j] = 0.f; }
    }

    const float2* A0 = A + (size_t)row0 * WKEPT * CC + c;
    const float4* cT = (const float4*)(c7t + (size_t)wg*65*8);
    const float4* sT = (const float4*)(s7t + (size_t)wg*65*8);
    for (int wq = 0; wq < 65; ++wq) {
        float4 c0 = cT[2*wq], c1 = cT[2*wq+1];
        float4 s0 = sT[2*wq], s1 = sT[2*wq+1];
        float sg = (wq & 1) ? -1.f : 1.f;
        #pragma unroll
        for (int r = 0; r < 4; ++r) {
            float2 v = A0[(size_t)(r*WKEPT + wq) * CC];
            float P = v.x + v.y;
            float M = v.y - v.x;
            float N = v.x - v.y;
            acc128[r] = fmaf(sg, P, acc128[r]);
            accA[r][0] = fmaf(P, c0.x, fmaf(M, s0.x, accA[r][0]));
            accB[r][0] = fmaf(P, c0.x, fmaf(N, s0.x, accB[r][0]));
            accA[r][1] = fmaf(P, c0.y, fmaf(M, s0.y, accA[r][1]));
            accB[r][1] = fmaf(P, c0.y, fmaf(N, s0.y, accB[r][1]));
            accA[r][2] = fmaf(P, c0.z, fmaf(M, s0.z, accA[r][2]));
            accB[r][2] = fmaf(P, c0.z, fmaf(N, s0.z, accB[r][2]));
            accA[r][3] = fmaf(P, c0.w, fmaf(M, s0.w, accA[r][3]));
            accB[r][3] = fmaf(P, c0.w, fmaf(N, s0.w, accB[r][3]));
            accA[r][4] = fmaf(P, c1.x, fmaf(M, s1.x, accA[r][4]));
            accB[r][4] = fmaf(P, c1.x, fmaf(N, s1.x, accB[r][4]));
            accA[r][5] = fmaf(P, c1.y, fmaf(M, s1.y, accA[r][5]));
            accB[r][5] = fmaf(P, c1.y, fmaf(N, s1.y, accB[r][5]));
            accA[r][6] = fmaf(P, c1.z, fmaf(M, s1.z, accA[r][6]));
            accB[r][6] = fmaf(P, c1.z, fmaf(N, s1.z, accB[r][6]));
            accA[r][7] = fmaf(P, c1.w, fmaf(M, s1.w, accA[r][7]));
            accB[r][7] = fmaf(P, c1.w, fmaf(N, s1.w, accB[r][7]));
        }
    }

    const float scale = 1.0f / 50331648.0f;
    #pragma unroll
    for (int r = 0; r < 4; ++r) {
        size_t base = (size_t)(row0 + r) * WW * CC + c;
        #pragma unroll
        for (int j = 0; j < 8; ++j) {
            int w = wpb + j;
            size_t g = base + (size_t)w*CC;
            out[g] = fmaf(accA[r][j], scale, x[g]);
            if (w != 0) {
                size_t g2 = base + (size_t)(256 - w)*CC;
                out[g2] = fmaf(accB[r][j], scale, x[g2]);
            }
        }
        if (wg == 0) {
            size_t g = base + (size_t)128*CC;
            out[g] = fmaf(acc128[r], scale, x[g]);
        }
    }
}

// ---------------------------------------------------------------------------
// P7 fallback (unchanged).
// ---------------------------------------------------------------------------
__global__ __launch_bounds__(256) void k_p7_fb(
    const float2* __restrict__ A, const float* __restrict__ x,
    float* __restrict__ out)
{
    const int tid = threadIdx.x;
    const int ct = blockIdx.x % 3;
    const int wg = blockIdx.x / 3;
    const int h = blockIdx.y, b = blockIdx.z;
    const int c = ct*256 + tid;
    __shared__ float cm[WKEPT][8];
    __shared__ float cp[WKEPT][8];
    for (int idx = tid; idx < WKEPT*8; idx += 256) {
        int wq = idx >> 3, j = idx & 7;
        int w = wg*8 + j;
        int ai = (w * wq) & 255;
        float sn, cse; sincosf(TWOPI * (float)ai / 256.f, &sn, &cse);
        cm[wq][j] = cse - sn;
        cp[wq][j] = cse + sn;
    }
    __syncthreads();
    float acc[8] = {0,0,0,0,0,0,0,0};
    const float2* Ab = A + (size_t)((b*HH + h)*WKEPT)*CC + c;
    for (int wq = 0; wq < WKEPT; ++wq) {
        float2 v = Ab[(size_t)wq*CC];
        const float4* m4 = (const float4*)(&cm[wq][0]);
        const float4* p4 = (const float4*)(&cp[wq][0]);
        #pragma unroll
        for (int jj = 0; jj < 2; ++jj) {
            float4 qm = m4[jj], qp = p4[jj];
            acc[4*jj+0] += v.x*qm.x + v.y*qp.x;
            acc[4*jj+1] += v.x*qm.y + v.y*qp.y;
            acc[4*jj+2] += v.x*qm.z + v.y*qp.z;
            acc[4*jj+3] += v.x*qm.w + v.y*qp.w;
        }
    }
    const float scale = 1.0f / 50331648.0f;
    size_t base = (size_t)(b*HH + h)*WW*CC + c;
    #pragma unroll
    for (int j = 0; j < 8; ++j) {
        int w = wg*8 + j;
        size_t g = base + (size_t)w*CC;
        out[g] = fmaf(acc[j], scale, x[g]);
    }
}

// ---------------------------------------------------------------------------
// Launch. ws layout:
//   floats: Abuf (2*NPTS*CC, halves double as a_real/s_real) | BEFF | c7t | s7t
//   then ushorts: W10h,W10l,W11h,W11l,WKPh,WKPl,WKMh,WKMl (each NB*96*96)
// d_out doubles as complex buffer B.
// ---------------------------------------------------------------------------
extern "C" void kernel_launch(void* const* d_in, const int* in_sizes, int n_in,
                              void* d_out, int out_size, void* d_ws, size_t ws_size,
                              hipStream_t stream)
{
    (void)in_sizes; (void)n_in; (void)out_size;
    const float* x  = (const float*)d_in[0];
    const float* w1 = (const float*)d_in[1];
    const float* b1 = (const float*)d_in[2];
    const float* w2 = (const float*)d_in[3];
    const float* b2 = (const float*)d_in[4];

    float*  ws     = (float*)d_ws;
    float2* Abuf   = (float2*)d_ws;
    float*  a_real = ws;
    float*  s_real = ws + (size_t)NPTS*CC;
    float*  BEFF   = ws + 2*(size_t)NPTS*CC;
    float*  c7t    = BEFF + NB*BS;
    float*  s7t    = c7t + P7_TW;
    unsigned short* Wq = (unsigned short*)(s7t + P7_TW);
    const size_t WSZ = (size_t)NB*BS*BS;
    unsigned short* W10h = Wq + 0*WSZ;
    unsigned short* W10l = Wq + 1*WSZ;
    unsigned short* W11h = Wq + 2*WSZ;
    unsigned short* W11l = Wq + 3*WSZ;
    unsigned short* WKPh = Wq + 4*WSZ;
    unsigned short* WKPl = Wq + 5*WSZ;
    unsigned short* WKMh = Wq + 6*WSZ;
    unsigned short* WKMl = Wq + 7*WSZ;

    const size_t need_bytes =
        ((size_t)2*NPTS*CC + NB*BS + 2*P7_TW)*4 + 8*WSZ*2;
    const bool fast = (ws_size >= need_bytes);

    float2* Bc   = (float2*)d_out;
    float*  outf = (float*)d_out;

    k_weights<<<dim3(NB), dim3(256), 0, stream>>>(
        w1, w2, b2, W10h, W10l, W11h, W11l, WKPh, WKPl, WKMh, WKMl, BEFF);
    if (fast) {
        k_tw<<<dim3(33), dim3(256), 0, stream>>>(c7t, s7t);
    }
    k_p1     <<<dim3(48, 256), dim3(256), 0, stream>>>(x, Abuf);
    k_cfft   <<<dim3(NPTS/LPB), dim3(256), 0, stream>>>(Abuf, Bc);
    k_hb_c2a <<<dim3(96, WKEPT), dim3(256), 0, stream>>>(Bc, a_real);
    k_mlp    <<<dim3(260, NB), dim3(256), 0, stream>>>(
        a_real, x, W10h, W10l, W11h, W11l, WKPh, WKPl, WKMh, WKMl,
        b1, BEFF, s_real);
    k_hb_s2c <<<dim3(48, WKEPT), dim3(256), 0, stream>>>(s_real, Bc);
    k_cfft   <<<dim3(NPTS/LPB), dim3(256), 0, stream>>>(Bc, Abuf);
    if (fast) {
        k_p7<<<dim3(48, 64), dim3(256), 0, stream>>>(Abuf, x, c7t, s7t, outf);
    } else {
        k_p7_fb<<<dim3(96, HH, BB), dim3(256), 0, stream>>>(Abuf, x, outf);
    }
}